// Round 2
// baseline (15552.574 us; speedup 1.0000x reference)
//
#include <hip/hip_runtime.h>
#include <hip/hip_cooperative_groups.h>

namespace cg = cooperative_groups;

#define B_    64
#define Q_    16
#define MAXK_ 32
#define C_    64
#define D_    768
#define H_    512
#define G4_   2048   // 4*H
#define S_    529    // Q*(MAXK+1)+1
#define NR_   81     // 16 questions + 64 code + 1 text

// ---------------- workspace layout (bytes) ----------------
static constexpr size_t OFF_L     = 0;                      // 64 int
static constexpr size_t OFF_MAXL  = 256;
static constexpr size_t OFF_MAP   = 512;                    // 64*529*4
static constexpr size_t OFF_BIAS0 = OFF_MAP   + 135424;     // 2048 f
static constexpr size_t OFF_BIAS1 = OFF_BIAS0 + 8192;       // 2048 f
static constexpr size_t OFF_C0    = OFF_BIAS1 + 8192;       // 64*512 f
static constexpr size_t OFF_C1    = OFF_C0    + 131072;
static constexpr size_t OFF_HLAST = OFF_C1    + 131072;
static constexpr size_t OFF_H0B   = OFF_HLAST + 131072;     // 2 x 64*512 f
static constexpr size_t OFF_H1B   = OFF_H0B   + 262144;     // 2 x 64*512 f
static constexpr size_t OFF_WTIH0 = OFF_H1B   + 262144;     // 768x2048 f
static constexpr size_t OFF_XPROJ = OFF_WTIH0 + 6291456ULL; // 64*81*2048 f
static constexpr size_t WS_NEED   = OFF_XPROJ + 42467328ULL; // ~47.5 MiB

// ---------------- prep ----------------
__global__ __launch_bounds__(256) void k_prep(
    const int* __restrict__ ns, const int* __restrict__ que,
    const float* __restrict__ b_ih0, const float* __restrict__ b_hh0,
    const float* __restrict__ b_ih1, const float* __restrict__ b_hh1,
    int* __restrict__ Lp, int* __restrict__ maxLp, int* __restrict__ map,
    float* __restrict__ bias0, float* __restrict__ bias1,
    float* __restrict__ c0, float* __restrict__ c1, float* __restrict__ hlast,
    float* __restrict__ h0b, float* __restrict__ h1b)
{
  const int tid = threadIdx.x;
  for (int i = tid; i < B_*S_; i += 256) map[i] = -1;
  for (int i = tid; i < G4_; i += 256) {
    bias0[i] = b_ih0[i] + b_hh0[i];
    bias1[i] = b_ih1[i] + b_hh1[i];
  }
  for (int i = tid; i < B_*H_; i += 256) {
    c0[i]=0.f; c1[i]=0.f; hlast[i]=0.f;
    h0b[i]=0.f; h0b[B_*H_+i]=0.f; h1b[i]=0.f; h1b[B_*H_+i]=0.f;
  }
  if (tid == 0) *maxLp = 0;
  __syncthreads();
  if (tid < B_) {
    const int b = tid;
    const int qn = que[b];
    int pos = 0;
    int* m = map + b*S_;
    for (int q = 0; q < qn; ++q) {
      m[pos++] = q;
      const int n = ns[b*Q_ + q];
      for (int k = 0; k < n; ++k) {
        int j = q + k; if (j > C_-1) j = C_-1;
        m[pos++] = 16 + j;
      }
    }
    m[pos] = 80;
    Lp[b] = pos;
    atomicMax(maxLp, pos);
  }
}

// ---------------- transpose W_ih0 only: [2048][768] -> [768][2048] ----------------
__global__ __launch_bounds__(256) void k_transpose(
    const float* __restrict__ w, float* __restrict__ wT)
{
  __shared__ float tile[32][33];
  const int n0 = blockIdx.x * 32;
  const int k0 = blockIdx.y * 32;
  const int tx = threadIdx.x, ty = threadIdx.y;
  for (int i = ty; i < 32; i += 8)
    tile[i][tx] = w[(size_t)(n0+i)*D_ + k0 + tx];
  __syncthreads();
  for (int i = ty; i < 32; i += 8)
    wT[(size_t)(k0 + i)*G4_ + n0 + tx] = tile[tx][i];
}

// ---------------- xproj: project 81 distinct source rows per batch ----------------
__global__ __launch_bounds__(128, 2) void k_proj(
    const float* __restrict__ text, const float* __restrict__ ques,
    const float* __restrict__ code, const float* __restrict__ wT_ih0,
    const float* __restrict__ bias0, float* __restrict__ xproj)
{
  __shared__ float hsLds[32][64];
  const int mb = blockIdx.x, nb = blockIdx.y;
  const int n0 = nb * 128;
  const int tid = threadIdx.x;
  const int tb = tid >> 4, tn = tid & 15;
  const int b0 = tb * 8;
  const int bb = tid >> 1, hh = tid & 1;

  const int mrow = mb*64 + bb;
  const int sb = mrow / NR_, sr = mrow % NR_;
  const float* srcrow = (sr < 16) ? (ques + ((size_t)sb*Q_ + sr)*D_)
                      : (sr < 80) ? (code + ((size_t)sb*C_ + (sr-16))*D_)
                                  : (text + (size_t)sb*D_);

  float a[8][8];
  #pragma unroll
  for (int i=0;i<8;i++)
    #pragma unroll
    for (int j=0;j<8;j++) a[i][j]=0.f;

  for (int k0 = 0; k0 < D_; k0 += 32) {
    __syncthreads();
    {
      const float* p = srcrow + k0 + hh*16;
      float4 v0 = *(const float4*)(p+0);
      float4 v1 = *(const float4*)(p+4);
      float4 v2 = *(const float4*)(p+8);
      float4 v3 = *(const float4*)(p+12);
      const int kk = hh*16;
      hsLds[kk+ 0][bb]=v0.x; hsLds[kk+ 1][bb]=v0.y; hsLds[kk+ 2][bb]=v0.z; hsLds[kk+ 3][bb]=v0.w;
      hsLds[kk+ 4][bb]=v1.x; hsLds[kk+ 5][bb]=v1.y; hsLds[kk+ 6][bb]=v1.z; hsLds[kk+ 7][bb]=v1.w;
      hsLds[kk+ 8][bb]=v2.x; hsLds[kk+ 9][bb]=v2.y; hsLds[kk+10][bb]=v2.z; hsLds[kk+11][bb]=v2.w;
      hsLds[kk+12][bb]=v3.x; hsLds[kk+13][bb]=v3.y; hsLds[kk+14][bb]=v3.z; hsLds[kk+15][bb]=v3.w;
    }
    __syncthreads();
    const float* wb = wT_ih0 + (size_t)k0*G4_ + n0 + tn*8;
    #pragma unroll 4
    for (int k=0;k<32;k++){
      float4 w0 = *(const float4*)(wb + (size_t)k*G4_);
      float4 w1 = *(const float4*)(wb + (size_t)k*G4_ + 4);
      float4 hA = *(const float4*)(&hsLds[k][b0]);
      float4 hB = *(const float4*)(&hsLds[k][b0+4]);
      float hv[8]={hA.x,hA.y,hA.z,hA.w,hB.x,hB.y,hB.z,hB.w};
      float wv[8]={w0.x,w0.y,w0.z,w0.w,w1.x,w1.y,w1.z,w1.w};
      #pragma unroll
      for (int i=0;i<8;i++)
        #pragma unroll
        for (int j=0;j<8;j++)
          a[i][j] = fmaf(hv[i], wv[j], a[i][j]);
    }
  }
  float bz[8];
  #pragma unroll
  for (int j=0;j<8;j++) bz[j] = bias0[n0 + tn*8 + j];
  #pragma unroll
  for (int i=0;i<8;i++){
    const int m = mb*64 + b0 + i;
    float* pd = xproj + (size_t)m*G4_ + n0 + tn*8;
    *(float4*)(pd+0) = make_float4(a[i][0]+bz[0], a[i][1]+bz[1], a[i][2]+bz[2], a[i][3]+bz[3]);
    *(float4*)(pd+4) = make_float4(a[i][4]+bz[4], a[i][5]+bz[5], a[i][6]+bz[6], a[i][7]+bz[7]);
  }
}

// ---------------- persistent LSTM: shared device pieces ----------------
// Block (bh, us) owns batches bh*32..+31, units us*4..+3.
// LDS-resident weights: wl0[16][516] (W_hh0 rows), wl1[16][1028] ([W_ih1|W_hh1] rows).
// row r (r=g*4+ul) <-> global n = (r>>2)*512 + us*4 + (r&3).
#define WL0_LD 516
#define WL1_LD 1028
#define HS_LD  260

__device__ __forceinline__ void load_weights(int tid, int us,
    const float* __restrict__ w_hh0, const float* __restrict__ w_ih1,
    const float* __restrict__ w_hh1, float* __restrict__ wl0, float* __restrict__ wl1)
{
  #pragma unroll
  for (int p = 0; p < 8; ++p) {
    const int f4 = tid + p*256;           // 0..2047
    const int r = f4 >> 7, c4 = f4 & 127;
    const int n = (r >> 2)*H_ + us*4 + (r & 3);
    float4 v = *(const float4*)(w_hh0 + (size_t)n*H_ + c4*4);
    *(float4*)(wl0 + r*WL0_LD + c4*4) = v;
  }
  #pragma unroll
  for (int p = 0; p < 16; ++p) {
    const int f4 = tid + p*256;           // 0..4095
    const int r = f4 >> 8, c4 = f4 & 255;
    const int n = (r >> 2)*H_ + us*4 + (r & 3);
    float4 v = (c4 < 128) ? *(const float4*)(w_ih1 + (size_t)n*H_ + c4*4)
                          : *(const float4*)(w_hh1 + (size_t)n*H_ + (c4-128)*4);
    *(float4*)(wl1 + r*WL1_LD + c4*4) = v;
  }
}

__device__ __forceinline__ float sigm(float x) { return 1.f/(1.f + __expf(-x)); }

__device__ __forceinline__ void lstm_iter(int t, int maxL, int bh, int us,
    const float* __restrict__ wl0, const float* __restrict__ wl1, float* __restrict__ hs,
    const float* __restrict__ xproj, const float* __restrict__ bias1,
    const int* __restrict__ map, const int* __restrict__ Lp,
    const float* __restrict__ h0c, float* __restrict__ h0n,
    const float* __restrict__ h1c, float* __restrict__ h1n,
    float* __restrict__ c0, float* __restrict__ c1, float* __restrict__ hlast)
{
  const int tid  = threadIdx.x;
  const int slot = tid & 15, kg = tid >> 4;      // 16 slots x 16 k-groups
  const int bgrp = slot & 3, ngrp = slot >> 2;
  const int b8   = bgrp * 8;

  float acc0[8][4], acc1[8][4];
  #pragma unroll
  for (int i=0;i<8;i++)
    #pragma unroll
    for (int j=0;j<4;j++){ acc0[i][j]=0.f; acc1[i][j]=0.f; }

  // ---- GEMM over 4 chunks of 256 k (c<2: h0 -> L0 & L1-x; c>=2: h1 -> L1-h) ----
  for (int c = 0; c < 4; ++c) {
    const float* srcb = (c < 2) ? h0c : h1c;
    const int ccol = (c & 1) * 256;
    {
      const int row = tid & 31, cq = tid >> 5;
      const float* gp = srcb + (size_t)(bh*32 + row)*H_ + ccol + cq*32;
      const int sw = ((row >> 3) & 3) << 2;
      float* hrow = hs + row*HS_LD;
      #pragma unroll
      for (int q = 0; q < 8; ++q) {
        float4 v = *(const float4*)(gp + q*4);
        *(float4*)(hrow + ((cq*32 + q*4) ^ sw)) = v;
      }
    }
    __syncthreads();
    const int klb = kg * 16;
    const int swr = bgrp << 2;
    if (c < 2) {
      const float* w0b = wl0 + ngrp*WL0_LD + c*256;
      const float* w1b = wl1 + ngrp*WL1_LD + c*256;
      #pragma unroll
      for (int k4 = 0; k4 < 4; ++k4) {
        const int kl = klb + k4*4;
        float4 hv[8];
        #pragma unroll
        for (int i = 0; i < 8; ++i)
          hv[i] = *(const float4*)(hs + (b8+i)*HS_LD + (kl ^ swr));
        #pragma unroll
        for (int j = 0; j < 4; ++j) {
          const float4 w0 = *(const float4*)(w0b + j*4*WL0_LD + kl);
          const float4 w1 = *(const float4*)(w1b + j*4*WL1_LD + kl);
          #pragma unroll
          for (int i = 0; i < 8; ++i) {
            float a0 = acc0[i][j], a1 = acc1[i][j];
            a0 = fmaf(hv[i].x, w0.x, a0); a0 = fmaf(hv[i].y, w0.y, a0);
            a0 = fmaf(hv[i].z, w0.z, a0); a0 = fmaf(hv[i].w, w0.w, a0);
            a1 = fmaf(hv[i].x, w1.x, a1); a1 = fmaf(hv[i].y, w1.y, a1);
            a1 = fmaf(hv[i].z, w1.z, a1); a1 = fmaf(hv[i].w, w1.w, a1);
            acc0[i][j] = a0; acc1[i][j] = a1;
          }
        }
      }
    } else {
      const float* w1b = wl1 + ngrp*WL1_LD + 512 + (c-2)*256;
      #pragma unroll
      for (int k4 = 0; k4 < 4; ++k4) {
        const int kl = klb + k4*4;
        float4 hv[8];
        #pragma unroll
        for (int i = 0; i < 8; ++i)
          hv[i] = *(const float4*)(hs + (b8+i)*HS_LD + (kl ^ swr));
        #pragma unroll
        for (int j = 0; j < 4; ++j) {
          const float4 w1 = *(const float4*)(w1b + j*4*WL1_LD + kl);
          #pragma unroll
          for (int i = 0; i < 8; ++i) {
            float a1 = acc1[i][j];
            a1 = fmaf(hv[i].x, w1.x, a1); a1 = fmaf(hv[i].y, w1.y, a1);
            a1 = fmaf(hv[i].z, w1.z, a1); a1 = fmaf(hv[i].w, w1.w, a1);
            acc1[i][j] = a1;
          }
        }
      }
    }
    __syncthreads();
  }

  // ---- reduce 16 kg -> 4 wave-partials (shfl) -> LDS ----
  #pragma unroll
  for (int i = 0; i < 8; ++i)
    #pragma unroll
    for (int j = 0; j < 4; ++j) {
      float v0 = acc0[i][j], v1 = acc1[i][j];
      v0 += __shfl_xor(v0, 16); v0 += __shfl_xor(v0, 32);
      v1 += __shfl_xor(v1, 16); v1 += __shfl_xor(v1, 32);
      acc0[i][j] = v0; acc1[i][j] = v1;
    }
  if (((tid >> 4) & 3) == 0) {
    const int base = ((tid >> 6)*16 + slot)*32;
    #pragma unroll
    for (int i = 0; i < 8; ++i)
      #pragma unroll
      for (int j = 0; j < 4; ++j) {
        hs[base + i*4 + j]        = acc0[i][j];
        hs[2048 + base + i*4 + j] = acc1[i][j];
      }
  }
  __syncthreads();

  // ---- gates: L0 workers tid<128, L1 workers tid>=128 ----
  if (tid < 128) {
    const int bl = tid & 31, ul = tid >> 5;
    const int b = bh*32 + bl, u = us*4 + ul;
    const int idx = b*H_ + u;
    const int r = (t <= maxL) ? map[b*S_ + t] : -1;
    if (r >= 0) {
      const int slot2 = (ul << 2) | (bl >> 3);
      const int i2 = bl & 7;
      float g0=0.f, g1=0.f, g2=0.f, g3=0.f;
      #pragma unroll
      for (int wv = 0; wv < 4; ++wv) {
        const int base = (wv*16 + slot2)*32 + i2*4;
        g0 += hs[base+0]; g1 += hs[base+1]; g2 += hs[base+2]; g3 += hs[base+3];
      }
      const float* xp = xproj + ((size_t)b*NR_ + r)*G4_ + u;
      g0 += xp[0]; g1 += xp[512]; g2 += xp[1024]; g3 += xp[1536];
      const float cc = sigm(g1)*c0[idx] + sigm(g0)*tanhf(g2);
      c0[idx] = cc;
      h0n[idx] = sigm(g3)*tanhf(cc);
    } else {
      h0n[idx] = h0c[idx];
    }
  } else {
    const int w2 = tid & 127;
    const int bl = w2 & 31, ul = w2 >> 5;
    const int b = bh*32 + bl, u = us*4 + ul;
    const int idx = b*H_ + u;
    const int s = t - 1;
    const int r = (s >= 0 && s <= maxL) ? map[b*S_ + s] : -1;
    if (r >= 0) {
      const int slot2 = (ul << 2) | (bl >> 3);
      const int i2 = bl & 7;
      float g0=0.f, g1=0.f, g2=0.f, g3=0.f;
      #pragma unroll
      for (int wv = 0; wv < 4; ++wv) {
        const int base = 2048 + (wv*16 + slot2)*32 + i2*4;
        g0 += hs[base+0]; g1 += hs[base+1]; g2 += hs[base+2]; g3 += hs[base+3];
      }
      g0 += bias1[u]; g1 += bias1[512+u]; g2 += bias1[1024+u]; g3 += bias1[1536+u];
      const float cc = sigm(g1)*c1[idx] + sigm(g0)*tanhf(g2);
      c1[idx] = cc;
      const float hn = sigm(g3)*tanhf(cc);
      h1n[idx] = hn;
      if (s == Lp[b]) hlast[idx] = hn;
    } else {
      h1n[idx] = h1c[idx];
    }
  }
}

__device__ __forceinline__ void fc_epilogue(int tid,
    const float* __restrict__ hlast, const float* __restrict__ fcw,
    const float* __restrict__ fcb, float* __restrict__ out)
{
  if (tid < 128) {
    const int b = tid >> 1, half = tid & 1;
    const float* hv = hlast + (size_t)b*H_ + half*256;
    const float* fw = fcw + half*256;
    float s = 0.f;
    #pragma unroll 8
    for (int u = 0; u < 256; ++u) s = fmaf(hv[u], fw[u], s);
    s += __shfl_xor(s, 1);
    if (half == 0) out[b] = s + fcb[0];
  }
}

// ---------------- cooperative persistent kernel ----------------
__global__ __launch_bounds__(256, 1) void k_lstm_coop(
    const float* __restrict__ w_hh0, const float* __restrict__ w_ih1,
    const float* __restrict__ w_hh1, const float* __restrict__ xproj,
    const float* __restrict__ bias1, const int* __restrict__ Lp,
    const int* __restrict__ maxLp, const int* __restrict__ map,
    float* __restrict__ h0b, float* __restrict__ h1b,
    float* __restrict__ c0, float* __restrict__ c1, float* __restrict__ hlast,
    const float* __restrict__ fcw, const float* __restrict__ fcb,
    float* __restrict__ out)
{
  cg::grid_group grid = cg::this_grid();
  __shared__ float wl0[16*WL0_LD];
  __shared__ float wl1[16*WL1_LD];
  __shared__ float hs[32*HS_LD];
  const int blk = blockIdx.x;
  const int bh = blk & 1, us = blk >> 1;
  load_weights(threadIdx.x, us, w_hh0, w_ih1, w_hh1, wl0, wl1);
  __syncthreads();
  const int maxL = *maxLp;
  for (int t = 0; t <= maxL + 1; ++t) {
    const float* h0c = h0b + (size_t)(t & 1)*(B_*H_);
    float*       h0n = h0b + (size_t)((t+1) & 1)*(B_*H_);
    const float* h1c = h1b + (size_t)(t & 1)*(B_*H_);
    float*       h1n = h1b + (size_t)((t+1) & 1)*(B_*H_);
    lstm_iter(t, maxL, bh, us, wl0, wl1, hs, xproj, bias1, map, Lp,
              h0c, h0n, h1c, h1n, c0, c1, hlast);
    grid.sync();
  }
  if (blk == 0) fc_epilogue(threadIdx.x, hlast, fcw, fcb, out);
}

// ---------------- non-cooperative fallback: one iteration per launch ----------------
__global__ __launch_bounds__(256, 1) void k_step(int t,
    const float* __restrict__ w_hh0, const float* __restrict__ w_ih1,
    const float* __restrict__ w_hh1, const float* __restrict__ xproj,
    const float* __restrict__ bias1, const int* __restrict__ Lp,
    const int* __restrict__ maxLp, const int* __restrict__ map,
    float* __restrict__ h0b, float* __restrict__ h1b,
    float* __restrict__ c0, float* __restrict__ c1, float* __restrict__ hlast)
{
  __shared__ float wl0[16*WL0_LD];
  __shared__ float wl1[16*WL1_LD];
  __shared__ float hs[32*HS_LD];
  const int blk = blockIdx.x;
  const int bh = blk & 1, us = blk >> 1;
  load_weights(threadIdx.x, us, w_hh0, w_ih1, w_hh1, wl0, wl1);
  __syncthreads();
  const int maxL = *maxLp;
  const float* h0c = h0b + (size_t)(t & 1)*(B_*H_);
  float*       h0n = h0b + (size_t)((t+1) & 1)*(B_*H_);
  const float* h1c = h1b + (size_t)(t & 1)*(B_*H_);
  float*       h1n = h1b + (size_t)((t+1) & 1)*(B_*H_);
  lstm_iter(t, maxL, bh, us, wl0, wl1, hs, xproj, bias1, map, Lp,
            h0c, h0n, h1c, h1n, c0, c1, hlast);
}

__global__ __launch_bounds__(128) void k_fc(
    const float* __restrict__ hlast, const float* __restrict__ fcw,
    const float* __restrict__ fcb, float* __restrict__ out)
{
  fc_epilogue(threadIdx.x, hlast, fcw, fcb, out);
}

// ---------------- host ----------------
extern "C" void kernel_launch(void* const* d_in, const int* in_sizes, int n_in,
                              void* d_out, int out_size, void* d_ws, size_t ws_size,
                              hipStream_t stream)
{
  const float* text  = (const float*)d_in[0];
  const float* ques  = (const float*)d_in[1];
  const float* code  = (const float*)d_in[2];
  const int*   ns    = (const int*)  d_in[3];
  const int*   que   = (const int*)  d_in[4];
  const float* w_ih0 = (const float*)d_in[5];
  const float* w_hh0 = (const float*)d_in[6];
  const float* b_ih0 = (const float*)d_in[7];
  const float* b_hh0 = (const float*)d_in[8];
  const float* w_ih1 = (const float*)d_in[9];
  const float* w_hh1 = (const float*)d_in[10];
  const float* b_ih1 = (const float*)d_in[11];
  const float* b_hh1 = (const float*)d_in[12];
  const float* fcw   = (const float*)d_in[13];
  const float* fcb   = (const float*)d_in[14];
  float* out = (float*)d_out;

  char* ws = (char*)d_ws;
  int*   Lp     = (int*)  (ws + OFF_L);
  int*   maxLp  = (int*)  (ws + OFF_MAXL);
  int*   map    = (int*)  (ws + OFF_MAP);
  float* bias0  = (float*)(ws + OFF_BIAS0);
  float* bias1  = (float*)(ws + OFF_BIAS1);
  float* c0     = (float*)(ws + OFF_C0);
  float* c1     = (float*)(ws + OFF_C1);
  float* hlast  = (float*)(ws + OFF_HLAST);
  float* h0b    = (float*)(ws + OFF_H0B);
  float* h1b    = (float*)(ws + OFF_H1B);
  float* wT_ih0 = (float*)(ws + OFF_WTIH0);
  float* xproj  = (float*)(ws + OFF_XPROJ);
  (void)in_sizes; (void)n_in; (void)out_size; (void)ws_size; (void)WS_NEED;

  hipLaunchKernelGGL(k_prep, dim3(1), dim3(256), 0, stream,
                     ns, que, b_ih0, b_hh0, b_ih1, b_hh1,
                     Lp, maxLp, map, bias0, bias1, c0, c1, hlast, h0b, h1b);

  hipLaunchKernelGGL(k_transpose, dim3(64, 24), dim3(32, 8), 0, stream,
                     w_ih0, wT_ih0);

  hipLaunchKernelGGL(k_proj, dim3(81, 16), dim3(128), 0, stream,
                     text, ques, code, wT_ih0, bias0, xproj);

  const float* a_whh0 = w_hh0; const float* a_wih1 = w_ih1; const float* a_whh1 = w_hh1;
  const float* a_xp = xproj;   const float* a_b1 = bias1;
  const int* a_Lp = Lp; const int* a_maxLp = maxLp; const int* a_map = map;
  float* a_h0b = h0b; float* a_h1b = h1b; float* a_c0 = c0; float* a_c1 = c1;
  float* a_hl = hlast; const float* a_fcw = fcw; const float* a_fcb = fcb;
  float* a_out = out;
  void* args[] = { &a_whh0, &a_wih1, &a_whh1, &a_xp, &a_b1, &a_Lp, &a_maxLp, &a_map,
                   &a_h0b, &a_h1b, &a_c0, &a_c1, &a_hl, &a_fcw, &a_fcb, &a_out };

  hipError_t err = hipLaunchCooperativeKernel((const void*)k_lstm_coop,
                                              dim3(256), dim3(256), args, 0, stream);
  if (err != hipSuccess) {
    (void)hipGetLastError();  // clear error state
    for (int t = 0; t < S_ + 1; ++t) {
      hipLaunchKernelGGL(k_step, dim3(256), dim3(256), 0, stream, t,
                         w_hh0, w_ih1, w_hh1, xproj, bias1, Lp, maxLp, map,
                         h0b, h1b, c0, c1, hlast);
    }
    hipLaunchKernelGGL(k_fc, dim3(1), dim3(128), 0, stream, hlast, fcw, fcb, out);
  }
}

// Round 3
// 7061.634 us; speedup vs baseline: 2.2024x; 2.2024x over previous
//
#include <hip/hip_runtime.h>
#include <hip/hip_cooperative_groups.h>

namespace cg = cooperative_groups;

#define B_    64
#define Q_    16
#define MAXK_ 32
#define C_    64
#define D_    768
#define H_    512
#define G4_   2048   // 4*H
#define S_    529    // Q*(MAXK+1)+1
#define NR_   81     // 16 questions + 64 code + 1 text

typedef float f32x4_t __attribute__((ext_vector_type(4)));

// ---------------- workspace layout (bytes) ----------------
static constexpr size_t OFF_L     = 0;                      // 64 int
static constexpr size_t OFF_MAXL  = 256;
static constexpr size_t OFF_MAP   = 512;                    // 64*529*4
static constexpr size_t OFF_BIAS0 = OFF_MAP   + 135424;     // 2048 f
static constexpr size_t OFF_BIAS1 = OFF_BIAS0 + 8192;       // 2048 f
static constexpr size_t OFF_C0    = OFF_BIAS1 + 8192;       // 64*512 f
static constexpr size_t OFF_C1    = OFF_C0    + 131072;
static constexpr size_t OFF_HLAST = OFF_C1    + 131072;
static constexpr size_t OFF_H0B   = OFF_HLAST + 131072;     // 2 x 64*512 f
static constexpr size_t OFF_H1B   = OFF_H0B   + 262144;     // 2 x 64*512 f
static constexpr size_t OFF_WTIH0 = OFF_H1B   + 262144;     // 768x2048 f
static constexpr size_t OFF_XPROJ = OFF_WTIH0 + 6291456ULL; // 64*81*2048 f
static constexpr size_t OFF_BAR   = OFF_XPROJ + 42467328ULL; // 512 int barrier state
static constexpr size_t WS_NEED   = OFF_BAR   + 2048;

// ---------------- coherent (L2-bypass, LLC point-of-coherence) access helpers ----------------
__device__ __forceinline__ void store_f_cc(float* p, float v) {
  asm volatile("global_store_dword %0, %1, off sc0 sc1" :: "v"(p), "v"(v) : "memory");
}
__device__ __forceinline__ float load_f_cc(const float* p) {
  float v;
  asm volatile("global_load_dword %0, %1, off sc0 sc1\n\ts_waitcnt vmcnt(0)"
               : "=v"(v) : "v"(p) : "memory");
  return v;
}

// ---------------- prep ----------------
__global__ __launch_bounds__(256) void k_prep(
    const int* __restrict__ ns, const int* __restrict__ que,
    const float* __restrict__ b_ih0, const float* __restrict__ b_hh0,
    const float* __restrict__ b_ih1, const float* __restrict__ b_hh1,
    int* __restrict__ Lp, int* __restrict__ maxLp, int* __restrict__ map,
    float* __restrict__ bias0, float* __restrict__ bias1,
    float* __restrict__ c0, float* __restrict__ c1, float* __restrict__ hlast,
    float* __restrict__ h0b, float* __restrict__ h1b, int* __restrict__ bar)
{
  const int tid = threadIdx.x;
  for (int i = tid; i < B_*S_; i += 256) map[i] = -1;
  for (int i = tid; i < G4_; i += 256) {
    bias0[i] = b_ih0[i] + b_hh0[i];
    bias1[i] = b_ih1[i] + b_hh1[i];
  }
  for (int i = tid; i < B_*H_; i += 256) {
    c0[i]=0.f; c1[i]=0.f; hlast[i]=0.f;
    h0b[i]=0.f; h0b[B_*H_+i]=0.f; h1b[i]=0.f; h1b[B_*H_+i]=0.f;
  }
  for (int i = tid; i < 512; i += 256) bar[i] = 0;
  if (tid == 0) *maxLp = 0;
  __syncthreads();
  if (tid < B_) {
    const int b = tid;
    const int qn = que[b];
    int pos = 0;
    int* m = map + b*S_;
    for (int q = 0; q < qn; ++q) {
      m[pos++] = q;
      const int n = ns[b*Q_ + q];
      for (int k = 0; k < n; ++k) {
        int j = q + k; if (j > C_-1) j = C_-1;
        m[pos++] = 16 + j;
      }
    }
    m[pos] = 80;
    Lp[b] = pos;
    atomicMax(maxLp, pos);
  }
}

// ---------------- transpose W_ih0 only: [2048][768] -> [768][2048] ----------------
__global__ __launch_bounds__(256) void k_transpose(
    const float* __restrict__ w, float* __restrict__ wT)
{
  __shared__ float tile[32][33];
  const int n0 = blockIdx.x * 32;
  const int k0 = blockIdx.y * 32;
  const int tx = threadIdx.x, ty = threadIdx.y;
  for (int i = ty; i < 32; i += 8)
    tile[i][tx] = w[(size_t)(n0+i)*D_ + k0 + tx];
  __syncthreads();
  for (int i = ty; i < 32; i += 8)
    wT[(size_t)(k0 + i)*G4_ + n0 + tx] = tile[tx][i];
}

// ---------------- xproj: project 81 distinct source rows per batch ----------------
__global__ __launch_bounds__(128, 2) void k_proj(
    const float* __restrict__ text, const float* __restrict__ ques,
    const float* __restrict__ code, const float* __restrict__ wT_ih0,
    const float* __restrict__ bias0, float* __restrict__ xproj)
{
  __shared__ float hsLds[32][64];
  const int mb = blockIdx.x, nb = blockIdx.y;
  const int n0 = nb * 128;
  const int tid = threadIdx.x;
  const int tb = tid >> 4, tn = tid & 15;
  const int b0 = tb * 8;
  const int bb = tid >> 1, hh = tid & 1;

  const int mrow = mb*64 + bb;
  const int sb = mrow / NR_, sr = mrow % NR_;
  const float* srcrow = (sr < 16) ? (ques + ((size_t)sb*Q_ + sr)*D_)
                      : (sr < 80) ? (code + ((size_t)sb*C_ + (sr-16))*D_)
                                  : (text + (size_t)sb*D_);

  float a[8][8];
  #pragma unroll
  for (int i=0;i<8;i++)
    #pragma unroll
    for (int j=0;j<8;j++) a[i][j]=0.f;

  for (int k0 = 0; k0 < D_; k0 += 32) {
    __syncthreads();
    {
      const float* p = srcrow + k0 + hh*16;
      float4 v0 = *(const float4*)(p+0);
      float4 v1 = *(const float4*)(p+4);
      float4 v2 = *(const float4*)(p+8);
      float4 v3 = *(const float4*)(p+12);
      const int kk = hh*16;
      hsLds[kk+ 0][bb]=v0.x; hsLds[kk+ 1][bb]=v0.y; hsLds[kk+ 2][bb]=v0.z; hsLds[kk+ 3][bb]=v0.w;
      hsLds[kk+ 4][bb]=v1.x; hsLds[kk+ 5][bb]=v1.y; hsLds[kk+ 6][bb]=v1.z; hsLds[kk+ 7][bb]=v1.w;
      hsLds[kk+ 8][bb]=v2.x; hsLds[kk+ 9][bb]=v2.y; hsLds[kk+10][bb]=v2.z; hsLds[kk+11][bb]=v2.w;
      hsLds[kk+12][bb]=v3.x; hsLds[kk+13][bb]=v3.y; hsLds[kk+14][bb]=v3.z; hsLds[kk+15][bb]=v3.w;
    }
    __syncthreads();
    const float* wb = wT_ih0 + (size_t)k0*G4_ + n0 + tn*8;
    #pragma unroll 4
    for (int k=0;k<32;k++){
      float4 w0 = *(const float4*)(wb + (size_t)k*G4_);
      float4 w1 = *(const float4*)(wb + (size_t)k*G4_ + 4);
      float4 hA = *(const float4*)(&hsLds[k][b0]);
      float4 hB = *(const float4*)(&hsLds[k][b0+4]);
      float hv[8]={hA.x,hA.y,hA.z,hA.w,hB.x,hB.y,hB.z,hB.w};
      float wv[8]={w0.x,w0.y,w0.z,w0.w,w1.x,w1.y,w1.z,w1.w};
      #pragma unroll
      for (int i=0;i<8;i++)
        #pragma unroll
        for (int j=0;j<8;j++)
          a[i][j] = fmaf(hv[i], wv[j], a[i][j]);
    }
  }
  float bz[8];
  #pragma unroll
  for (int j=0;j<8;j++) bz[j] = bias0[n0 + tn*8 + j];
  #pragma unroll
  for (int i=0;i<8;i++){
    const int m = mb*64 + b0 + i;
    float* pd = xproj + (size_t)m*G4_ + n0 + tn*8;
    *(float4*)(pd+0) = make_float4(a[i][0]+bz[0], a[i][1]+bz[1], a[i][2]+bz[2], a[i][3]+bz[3]);
    *(float4*)(pd+4) = make_float4(a[i][4]+bz[4], a[i][5]+bz[5], a[i][6]+bz[6], a[i][7]+bz[7]);
  }
}

// ---------------- persistent LSTM pieces ----------------
#define WL0_LD 516
#define WL1_LD 1028
#define HS_LD  260

__device__ __forceinline__ void load_weights(int tid, int us,
    const float* __restrict__ w_hh0, const float* __restrict__ w_ih1,
    const float* __restrict__ w_hh1, float* __restrict__ wl0, float* __restrict__ wl1)
{
  #pragma unroll
  for (int p = 0; p < 8; ++p) {
    const int f4 = tid + p*256;
    const int r = f4 >> 7, c4 = f4 & 127;
    const int n = (r >> 2)*H_ + us*4 + (r & 3);
    float4 v = *(const float4*)(w_hh0 + (size_t)n*H_ + c4*4);
    *(float4*)(wl0 + r*WL0_LD + c4*4) = v;
  }
  #pragma unroll
  for (int p = 0; p < 16; ++p) {
    const int f4 = tid + p*256;
    const int r = f4 >> 8, c4 = f4 & 255;
    const int n = (r >> 2)*H_ + us*4 + (r & 3);
    float4 v = (c4 < 128) ? *(const float4*)(w_ih1 + (size_t)n*H_ + c4*4)
                          : *(const float4*)(w_hh1 + (size_t)n*H_ + (c4-128)*4);
    *(float4*)(wl1 + r*WL1_LD + c4*4) = v;
  }
}

__device__ __forceinline__ float sigm(float x) { return 1.f/(1.f + __expf(-x)); }

// issue 8 coherent dwordx4 loads for one 32x256 h-chunk into registers
__device__ __forceinline__ void stage_issue(const float* __restrict__ srcb,
    int bh, int row, int cq, int ccol, f32x4_t* vv)
{
  const float* gp = srcb + (size_t)(bh*32 + row)*H_ + ccol + cq*32;
  #pragma unroll
  for (int q = 0; q < 8; ++q)
    asm volatile("global_load_dwordx4 %0, %1, off sc0 sc1"
                 : "=v"(vv[q]) : "v"(gp + q*4) : "memory");
}
// drain loads and write to swizzled LDS
__device__ __forceinline__ void stage_write(float* __restrict__ hs,
    int row, int cq, const f32x4_t* vv)
{
  asm volatile("s_waitcnt vmcnt(0)" ::: "memory");
  const int sw = ((row >> 3) & 3) << 2;
  float* hrow = hs + row*HS_LD;
  #pragma unroll
  for (int q = 0; q < 8; ++q)
    *(f32x4_t*)(hrow + ((cq*32 + q*4) ^ sw)) = vv[q];
}

__device__ __forceinline__ void lstm_iter(int t, int maxL, int bh, int us,
    const float* __restrict__ wl0, const float* __restrict__ wl1, float* __restrict__ hs,
    const float* __restrict__ xproj, const float* __restrict__ bias1,
    const int* __restrict__ map, const int* __restrict__ Lp,
    const float* __restrict__ h0c, float* __restrict__ h0n,
    const float* __restrict__ h1c, float* __restrict__ h1n,
    float* __restrict__ c0, float* __restrict__ c1, float* __restrict__ hlast)
{
  const int tid  = threadIdx.x;
  const int slot = tid & 15, kg = tid >> 4;      // 16 slots x 16 k-groups
  const int bgrp = slot & 3, ngrp = slot >> 2;
  const int b8   = bgrp * 8;
  const int row  = tid & 31, cq = tid >> 5;

  float acc0[8][4], acc1[8][4];
  #pragma unroll
  for (int i=0;i<8;i++)
    #pragma unroll
    for (int j=0;j<4;j++){ acc0[i][j]=0.f; acc1[i][j]=0.f; }

  f32x4_t vv[8];
  stage_issue(h0c, bh, row, cq, 0, vv);          // prefetch chunk 0

  // ---- GEMM over 4 chunks of 256 k (c<2: h0 -> L0 & L1-x; c>=2: h1 -> L1-h) ----
  for (int c = 0; c < 4; ++c) {
    stage_write(hs, row, cq, vv);
    __syncthreads();
    if (c < 3) {                                  // prefetch next chunk (T14 split)
      const float* nsrc = (c + 1 < 2) ? h0c : h1c;
      stage_issue(nsrc, bh, row, cq, ((c+1) & 1)*256, vv);
    }
    const int klb = kg * 16;
    const int swr = bgrp << 2;
    if (c < 2) {
      const float* w0b = wl0 + ngrp*WL0_LD + c*256;
      const float* w1b = wl1 + ngrp*WL1_LD + c*256;
      #pragma unroll
      for (int k4 = 0; k4 < 4; ++k4) {
        const int kl = klb + k4*4;
        f32x4_t hv[8];
        #pragma unroll
        for (int i = 0; i < 8; ++i)
          hv[i] = *(const f32x4_t*)(hs + (b8+i)*HS_LD + (kl ^ swr));
        #pragma unroll
        for (int j = 0; j < 4; ++j) {
          const f32x4_t w0 = *(const f32x4_t*)(w0b + j*4*WL0_LD + kl);
          const f32x4_t w1 = *(const f32x4_t*)(w1b + j*4*WL1_LD + kl);
          #pragma unroll
          for (int i = 0; i < 8; ++i) {
            float a0 = acc0[i][j], a1 = acc1[i][j];
            a0 = fmaf(hv[i].x, w0.x, a0); a0 = fmaf(hv[i].y, w0.y, a0);
            a0 = fmaf(hv[i].z, w0.z, a0); a0 = fmaf(hv[i].w, w0.w, a0);
            a1 = fmaf(hv[i].x, w1.x, a1); a1 = fmaf(hv[i].y, w1.y, a1);
            a1 = fmaf(hv[i].z, w1.z, a1); a1 = fmaf(hv[i].w, w1.w, a1);
            acc0[i][j] = a0; acc1[i][j] = a1;
          }
        }
      }
    } else {
      const float* w1b = wl1 + ngrp*WL1_LD + 512 + (c-2)*256;
      #pragma unroll
      for (int k4 = 0; k4 < 4; ++k4) {
        const int kl = klb + k4*4;
        f32x4_t hv[8];
        #pragma unroll
        for (int i = 0; i < 8; ++i)
          hv[i] = *(const f32x4_t*)(hs + (b8+i)*HS_LD + (kl ^ swr));
        #pragma unroll
        for (int j = 0; j < 4; ++j) {
          const f32x4_t w1 = *(const f32x4_t*)(w1b + j*4*WL1_LD + kl);
          #pragma unroll
          for (int i = 0; i < 8; ++i) {
            float a1 = acc1[i][j];
            a1 = fmaf(hv[i].x, w1.x, a1); a1 = fmaf(hv[i].y, w1.y, a1);
            a1 = fmaf(hv[i].z, w1.z, a1); a1 = fmaf(hv[i].w, w1.w, a1);
            acc1[i][j] = a1;
          }
        }
      }
    }
    __syncthreads();
  }

  // ---- reduce 16 kg -> 4 wave-partials (shfl) -> LDS ----
  #pragma unroll
  for (int i = 0; i < 8; ++i)
    #pragma unroll
    for (int j = 0; j < 4; ++j) {
      float v0 = acc0[i][j], v1 = acc1[i][j];
      v0 += __shfl_xor(v0, 16); v0 += __shfl_xor(v0, 32);
      v1 += __shfl_xor(v1, 16); v1 += __shfl_xor(v1, 32);
      acc0[i][j] = v0; acc1[i][j] = v1;
    }
  if (((tid >> 4) & 3) == 0) {
    const int base = ((tid >> 6)*16 + slot)*32;
    #pragma unroll
    for (int i = 0; i < 8; ++i)
      #pragma unroll
      for (int j = 0; j < 4; ++j) {
        hs[base + i*4 + j]        = acc0[i][j];
        hs[2048 + base + i*4 + j] = acc1[i][j];
      }
  }
  __syncthreads();

  // ---- gates: L0 workers tid<128, L1 workers tid>=128 ----
  if (tid < 128) {
    const int bl = tid & 31, ul = tid >> 5;
    const int b = bh*32 + bl, u = us*4 + ul;
    const int idx = b*H_ + u;
    const int r = (t <= maxL) ? map[b*S_ + t] : -1;
    if (r >= 0) {
      const int slot2 = (ul << 2) | (bl >> 3);
      const int i2 = bl & 7;
      float g0=0.f, g1=0.f, g2=0.f, g3=0.f;
      #pragma unroll
      for (int wv = 0; wv < 4; ++wv) {
        const int base = (wv*16 + slot2)*32 + i2*4;
        g0 += hs[base+0]; g1 += hs[base+1]; g2 += hs[base+2]; g3 += hs[base+3];
      }
      const float* xp = xproj + ((size_t)b*NR_ + r)*G4_ + u;
      g0 += xp[0]; g1 += xp[512]; g2 += xp[1024]; g3 += xp[1536];
      const float cc = sigm(g1)*c0[idx] + sigm(g0)*tanhf(g2);
      c0[idx] = cc;
      store_f_cc(h0n + idx, sigm(g3)*tanhf(cc));
    } else {
      store_f_cc(h0n + idx, load_f_cc(h0c + idx));
    }
  } else {
    const int w2 = tid & 127;
    const int bl = w2 & 31, ul = w2 >> 5;
    const int b = bh*32 + bl, u = us*4 + ul;
    const int idx = b*H_ + u;
    const int s = t - 1;
    const int r = (s >= 0 && s <= maxL) ? map[b*S_ + s] : -1;
    if (r >= 0) {
      const int slot2 = (ul << 2) | (bl >> 3);
      const int i2 = bl & 7;
      float g0=0.f, g1=0.f, g2=0.f, g3=0.f;
      #pragma unroll
      for (int wv = 0; wv < 4; ++wv) {
        const int base = 2048 + (wv*16 + slot2)*32 + i2*4;
        g0 += hs[base+0]; g1 += hs[base+1]; g2 += hs[base+2]; g3 += hs[base+3];
      }
      g0 += bias1[u]; g1 += bias1[512+u]; g2 += bias1[1024+u]; g3 += bias1[1536+u];
      const float cc = sigm(g1)*c1[idx] + sigm(g0)*tanhf(g2);
      c1[idx] = cc;
      const float hn = sigm(g3)*tanhf(cc);
      store_f_cc(h1n + idx, hn);
      if (s == Lp[b]) store_f_cc(hlast + idx, hn);
    } else {
      store_f_cc(h1n + idx, load_f_cc(h1c + idx));
    }
  }
}

__device__ __forceinline__ void fc_epilogue(int tid,
    const float* __restrict__ hlast, const float* __restrict__ fcw,
    const float* __restrict__ fcb, float* __restrict__ out)
{
  // hlast was only ever written write-through (sc0 sc1): plain reads are safe.
  if (tid < 128) {
    const int b = tid >> 1, half = tid & 1;
    const float* hv = hlast + (size_t)b*H_ + half*256;
    const float* fw = fcw + half*256;
    float s = 0.f;
    #pragma unroll 8
    for (int u = 0; u < 256; ++u) s = fmaf(hv[u], fw[u], s);
    s += __shfl_xor(s, 1);
    if (half == 0) out[b] = s + fcb[0];
  }
}

// ---------------- custom two-level grid barrier (no cache flushes) ----------------
// bar layout (ints): leaf[i] at bar[i*16] (i<16), root at bar[256], gen at bar[272].
// Monotonic counters: no resets, zeroed each launch by k_prep.
__device__ __forceinline__ void grid_barrier(int* __restrict__ bar, int blk, int g)
{
  asm volatile("s_waitcnt vmcnt(0)" ::: "memory");  // drain this thread's sc stores
  __syncthreads();                                   // all threads' stores drained
  if (threadIdx.x == 0) {
    int* lp = bar + (blk >> 4) * 16;
    int* rp = bar + 256;
    int* gp = bar + 272;
    bool last = false;
    if (atomicAdd(lp, 1) == g*16 - 1) {
      if (atomicAdd(rp, 1) == g*16 - 1) {
        __hip_atomic_store(gp, g, __ATOMIC_RELAXED, __HIP_MEMORY_SCOPE_AGENT);
        last = true;
      }
    }
    if (!last) {
      while (__hip_atomic_load(gp, __ATOMIC_RELAXED, __HIP_MEMORY_SCOPE_AGENT) < g)
        __builtin_amdgcn_s_sleep(2);
    }
  }
  __syncthreads();
}

// ---------------- cooperative persistent kernel ----------------
__global__ __launch_bounds__(256, 1) void k_lstm_coop(
    const float* __restrict__ w_hh0, const float* __restrict__ w_ih1,
    const float* __restrict__ w_hh1, const float* __restrict__ xproj,
    const float* __restrict__ bias1, const int* __restrict__ Lp,
    const int* __restrict__ maxLp, const int* __restrict__ map,
    float* __restrict__ h0b, float* __restrict__ h1b,
    float* __restrict__ c0, float* __restrict__ c1, float* __restrict__ hlast,
    const float* __restrict__ fcw, const float* __restrict__ fcb,
    float* __restrict__ out, int* __restrict__ bar)
{
  __shared__ float wl0[16*WL0_LD];
  __shared__ float wl1[16*WL1_LD];
  __shared__ float hs[32*HS_LD];
  const int blk = blockIdx.x;
  const int bh = blk & 1, us = blk >> 1;
  load_weights(threadIdx.x, us, w_hh0, w_ih1, w_hh1, wl0, wl1);
  __syncthreads();
  const int maxL = *maxLp;
  for (int t = 0; t <= maxL + 1; ++t) {
    const float* h0c = h0b + (size_t)(t & 1)*(B_*H_);
    float*       h0n = h0b + (size_t)((t+1) & 1)*(B_*H_);
    const float* h1c = h1b + (size_t)(t & 1)*(B_*H_);
    float*       h1n = h1b + (size_t)((t+1) & 1)*(B_*H_);
    lstm_iter(t, maxL, bh, us, wl0, wl1, hs, xproj, bias1, map, Lp,
              h0c, h0n, h1c, h1n, c0, c1, hlast);
    grid_barrier(bar, blk, t + 1);
  }
  if (blk == 0) fc_epilogue(threadIdx.x, hlast, fcw, fcb, out);
}

// ---------------- non-cooperative fallback: one iteration per launch ----------------
__global__ __launch_bounds__(256, 1) void k_step(int t,
    const float* __restrict__ w_hh0, const float* __restrict__ w_ih1,
    const float* __restrict__ w_hh1, const float* __restrict__ xproj,
    const float* __restrict__ bias1, const int* __restrict__ Lp,
    const int* __restrict__ maxLp, const int* __restrict__ map,
    float* __restrict__ h0b, float* __restrict__ h1b,
    float* __restrict__ c0, float* __restrict__ c1, float* __restrict__ hlast)
{
  __shared__ float wl0[16*WL0_LD];
  __shared__ float wl1[16*WL1_LD];
  __shared__ float hs[32*HS_LD];
  const int blk = blockIdx.x;
  const int bh = blk & 1, us = blk >> 1;
  load_weights(threadIdx.x, us, w_hh0, w_ih1, w_hh1, wl0, wl1);
  __syncthreads();
  const int maxL = *maxLp;
  if (t > maxL + 1) return;
  const float* h0c = h0b + (size_t)(t & 1)*(B_*H_);
  float*       h0n = h0b + (size_t)((t+1) & 1)*(B_*H_);
  const float* h1c = h1b + (size_t)(t & 1)*(B_*H_);
  float*       h1n = h1b + (size_t)((t+1) & 1)*(B_*H_);
  lstm_iter(t, maxL, bh, us, wl0, wl1, hs, xproj, bias1, map, Lp,
            h0c, h0n, h1c, h1n, c0, c1, hlast);
}

__global__ __launch_bounds__(128) void k_fc(
    const float* __restrict__ hlast, const float* __restrict__ fcw,
    const float* __restrict__ fcb, float* __restrict__ out)
{
  fc_epilogue(threadIdx.x, hlast, fcw, fcb, out);
}

// ---------------- host ----------------
extern "C" void kernel_launch(void* const* d_in, const int* in_sizes, int n_in,
                              void* d_out, int out_size, void* d_ws, size_t ws_size,
                              hipStream_t stream)
{
  const float* text  = (const float*)d_in[0];
  const float* ques  = (const float*)d_in[1];
  const float* code  = (const float*)d_in[2];
  const int*   ns    = (const int*)  d_in[3];
  const int*   que   = (const int*)  d_in[4];
  const float* w_ih0 = (const float*)d_in[5];
  const float* w_hh0 = (const float*)d_in[6];
  const float* b_ih0 = (const float*)d_in[7];
  const float* b_hh0 = (const float*)d_in[8];
  const float* w_ih1 = (const float*)d_in[9];
  const float* w_hh1 = (const float*)d_in[10];
  const float* b_ih1 = (const float*)d_in[11];
  const float* b_hh1 = (const float*)d_in[12];
  const float* fcw   = (const float*)d_in[13];
  const float* fcb   = (const float*)d_in[14];
  float* out = (float*)d_out;

  char* ws = (char*)d_ws;
  int*   Lp     = (int*)  (ws + OFF_L);
  int*   maxLp  = (int*)  (ws + OFF_MAXL);
  int*   map    = (int*)  (ws + OFF_MAP);
  float* bias0  = (float*)(ws + OFF_BIAS0);
  float* bias1  = (float*)(ws + OFF_BIAS1);
  float* c0     = (float*)(ws + OFF_C0);
  float* c1     = (float*)(ws + OFF_C1);
  float* hlast  = (float*)(ws + OFF_HLAST);
  float* h0b    = (float*)(ws + OFF_H0B);
  float* h1b    = (float*)(ws + OFF_H1B);
  float* wT_ih0 = (float*)(ws + OFF_WTIH0);
  float* xproj  = (float*)(ws + OFF_XPROJ);
  int*   bar    = (int*)  (ws + OFF_BAR);
  (void)in_sizes; (void)n_in; (void)out_size; (void)ws_size; (void)WS_NEED;

  hipLaunchKernelGGL(k_prep, dim3(1), dim3(256), 0, stream,
                     ns, que, b_ih0, b_hh0, b_ih1, b_hh1,
                     Lp, maxLp, map, bias0, bias1, c0, c1, hlast, h0b, h1b, bar);

  hipLaunchKernelGGL(k_transpose, dim3(64, 24), dim3(32, 8), 0, stream,
                     w_ih0, wT_ih0);

  hipLaunchKernelGGL(k_proj, dim3(81, 16), dim3(128), 0, stream,
                     text, ques, code, wT_ih0, bias0, xproj);

  const float* a_whh0 = w_hh0; const float* a_wih1 = w_ih1; const float* a_whh1 = w_hh1;
  const float* a_xp = xproj;   const float* a_b1 = bias1;
  const int* a_Lp = Lp; const int* a_maxLp = maxLp; const int* a_map = map;
  float* a_h0b = h0b; float* a_h1b = h1b; float* a_c0 = c0; float* a_c1 = c1;
  float* a_hl = hlast; const float* a_fcw = fcw; const float* a_fcb = fcb;
  float* a_out = out; int* a_bar = bar;
  void* args[] = { &a_whh0, &a_wih1, &a_whh1, &a_xp, &a_b1, &a_Lp, &a_maxLp, &a_map,
                   &a_h0b, &a_h1b, &a_c0, &a_c1, &a_hl, &a_fcw, &a_fcb, &a_out, &a_bar };

  hipError_t err = hipLaunchCooperativeKernel((const void*)k_lstm_coop,
                                              dim3(256), dim3(256), args, 0, stream);
  if (err != hipSuccess) {
    (void)hipGetLastError();  // clear error state
    for (int t = 0; t < S_ + 1; ++t) {
      hipLaunchKernelGGL(k_step, dim3(256), dim3(256), 0, stream, t,
                         w_hh0, w_ih1, w_hh1, xproj, bias1, Lp, maxLp, map,
                         h0b, h1b, c0, c1, hlast);
    }
    hipLaunchKernelGGL(k_fc, dim3(1), dim3(128), 0, stream, hlast, fcw, fcb, out);
  }
}

// Round 5
// 7047.153 us; speedup vs baseline: 2.2069x; 1.0021x over previous
//
#include <hip/hip_runtime.h>
#include <hip/hip_cooperative_groups.h>

namespace cg = cooperative_groups;

#define B_    64
#define Q_    16
#define MAXK_ 32
#define C_    64
#define D_    768
#define H_    512
#define G4_   2048   // 4*H
#define S_    529    // Q*(MAXK+1)+1
#define NR_   81     // 16 questions + 64 code + 1 text

typedef float f32x4_t __attribute__((ext_vector_type(4)));
typedef unsigned int u32x2_t __attribute__((ext_vector_type(2)));
typedef unsigned int u32x4_t __attribute__((ext_vector_type(4)));

// LDS geometry (bytes)
#define WL0_RB 1040   // 16 rows x (512 halves + 8 pad) : W_hh0 slice
#define WL1_RB 2064   // 16 rows x (1024 halves + 8 pad): [W_ih1|W_hh1] slice
#define HS_RB  512    // 32 rows x 256 halves (one 256-k chunk)

// ---------------- workspace layout (bytes) ----------------
static constexpr size_t OFF_L     = 0;                      // 64 int
static constexpr size_t OFF_MAXL  = 256;
static constexpr size_t OFF_MAP   = 512;                    // 64*529*4
static constexpr size_t OFF_BIAS0 = OFF_MAP   + 135424;     // 2048 f
static constexpr size_t OFF_BIAS1 = OFF_BIAS0 + 8192;       // 2048 f
static constexpr size_t OFF_C0    = OFF_BIAS1 + 8192;       // 64*512 f
static constexpr size_t OFF_C1    = OFF_C0    + 131072;
static constexpr size_t OFF_HLAST = OFF_C1    + 131072;
static constexpr size_t OFF_H0B   = OFF_HLAST + 131072;     // 2 x 64*512 f
static constexpr size_t OFF_H1B   = OFF_H0B   + 262144;     // 2 x 64*512 f
static constexpr size_t OFF_WTIH0 = OFF_H1B   + 262144;     // 768x2048 f
static constexpr size_t OFF_XPROJ = OFF_WTIH0 + 6291456ULL; // 64*81*2048 f
static constexpr size_t OFF_BAR   = OFF_XPROJ + 42467328ULL; // 512 int barrier state
static constexpr size_t WS_NEED   = OFF_BAR   + 2048;

// ---------------- coherent (L2-bypass) access helpers ----------------
__device__ __forceinline__ void store_f_cc(float* p, float v) {
  asm volatile("global_store_dword %0, %1, off sc0 sc1" :: "v"(p), "v"(v) : "memory");
}
__device__ __forceinline__ float load_f_cc(const float* p) {
  float v;
  asm volatile("global_load_dword %0, %1, off sc0 sc1\n\ts_waitcnt vmcnt(0)"
               : "=v"(v) : "v"(p) : "memory");
  return v;
}

__device__ __forceinline__ void dot2(float& acc, unsigned int a, unsigned int b) {
  asm("v_dot2_f32_f16 %0, %1, %2, %0" : "+v"(acc) : "v"(a), "v"(b));
}
__device__ __forceinline__ unsigned int pkrtz(float a, float b) {
  auto r = __builtin_amdgcn_cvt_pkrtz(a, b);   // __fp16 ext_vector_type(2)
  unsigned int u;
  __builtin_memcpy(&u, &r, 4);
  return u;
}

// ---------------- prep ----------------
__global__ __launch_bounds__(256) void k_prep(
    const int* __restrict__ ns, const int* __restrict__ que,
    const float* __restrict__ b_ih0, const float* __restrict__ b_hh0,
    const float* __restrict__ b_ih1, const float* __restrict__ b_hh1,
    int* __restrict__ Lp, int* __restrict__ maxLp, int* __restrict__ map,
    float* __restrict__ bias0, float* __restrict__ bias1,
    float* __restrict__ c0, float* __restrict__ c1, float* __restrict__ hlast,
    float* __restrict__ h0b, float* __restrict__ h1b, int* __restrict__ bar)
{
  const int tid = threadIdx.x;
  for (int i = tid; i < B_*S_; i += 256) map[i] = -1;
  for (int i = tid; i < G4_; i += 256) {
    bias0[i] = b_ih0[i] + b_hh0[i];
    bias1[i] = b_ih1[i] + b_hh1[i];
  }
  for (int i = tid; i < B_*H_; i += 256) {
    c0[i]=0.f; c1[i]=0.f; hlast[i]=0.f;
    h0b[i]=0.f; h0b[B_*H_+i]=0.f; h1b[i]=0.f; h1b[B_*H_+i]=0.f;
  }
  for (int i = tid; i < 512; i += 256) bar[i] = 0;
  if (tid == 0) *maxLp = 0;
  __syncthreads();
  if (tid < B_) {
    const int b = tid;
    const int qn = que[b];
    int pos = 0;
    int* m = map + b*S_;
    for (int q = 0; q < qn; ++q) {
      m[pos++] = q;
      const int n = ns[b*Q_ + q];
      for (int k = 0; k < n; ++k) {
        int j = q + k; if (j > C_-1) j = C_-1;
        m[pos++] = 16 + j;
      }
    }
    m[pos] = 80;
    Lp[b] = pos;
    atomicMax(maxLp, pos);
  }
}

// ---------------- transpose W_ih0 only: [2048][768] -> [768][2048] ----------------
__global__ __launch_bounds__(256) void k_transpose(
    const float* __restrict__ w, float* __restrict__ wT)
{
  __shared__ float tile[32][33];
  const int n0 = blockIdx.x * 32;
  const int k0 = blockIdx.y * 32;
  const int tx = threadIdx.x, ty = threadIdx.y;
  for (int i = ty; i < 32; i += 8)
    tile[i][tx] = w[(size_t)(n0+i)*D_ + k0 + tx];
  __syncthreads();
  for (int i = ty; i < 32; i += 8)
    wT[(size_t)(k0 + i)*G4_ + n0 + tx] = tile[tx][i];
}

// ---------------- xproj: project 81 distinct source rows per batch (fp32) ----------------
__global__ __launch_bounds__(128, 2) void k_proj(
    const float* __restrict__ text, const float* __restrict__ ques,
    const float* __restrict__ code, const float* __restrict__ wT_ih0,
    const float* __restrict__ bias0, float* __restrict__ xproj)
{
  __shared__ float hsLds[32][64];
  const int mb = blockIdx.x, nb = blockIdx.y;
  const int n0 = nb * 128;
  const int tid = threadIdx.x;
  const int tb = tid >> 4, tn = tid & 15;
  const int b0 = tb * 8;
  const int bb = tid >> 1, hh = tid & 1;

  const int mrow = mb*64 + bb;
  const int sb = mrow / NR_, sr = mrow % NR_;
  const float* srcrow = (sr < 16) ? (ques + ((size_t)sb*Q_ + sr)*D_)
                      : (sr < 80) ? (code + ((size_t)sb*C_ + (sr-16))*D_)
                                  : (text + (size_t)sb*D_);

  float a[8][8];
  #pragma unroll
  for (int i=0;i<8;i++)
    #pragma unroll
    for (int j=0;j<8;j++) a[i][j]=0.f;

  for (int k0 = 0; k0 < D_; k0 += 32) {
    __syncthreads();
    {
      const float* p = srcrow + k0 + hh*16;
      float4 v0 = *(const float4*)(p+0);
      float4 v1 = *(const float4*)(p+4);
      float4 v2 = *(const float4*)(p+8);
      float4 v3 = *(const float4*)(p+12);
      const int kk = hh*16;
      hsLds[kk+ 0][bb]=v0.x; hsLds[kk+ 1][bb]=v0.y; hsLds[kk+ 2][bb]=v0.z; hsLds[kk+ 3][bb]=v0.w;
      hsLds[kk+ 4][bb]=v1.x; hsLds[kk+ 5][bb]=v1.y; hsLds[kk+ 6][bb]=v1.z; hsLds[kk+ 7][bb]=v1.w;
      hsLds[kk+ 8][bb]=v2.x; hsLds[kk+ 9][bb]=v2.y; hsLds[kk+10][bb]=v2.z; hsLds[kk+11][bb]=v2.w;
      hsLds[kk+12][bb]=v3.x; hsLds[kk+13][bb]=v3.y; hsLds[kk+14][bb]=v3.z; hsLds[kk+15][bb]=v3.w;
    }
    __syncthreads();
    const float* wb = wT_ih0 + (size_t)k0*G4_ + n0 + tn*8;
    #pragma unroll 4
    for (int k=0;k<32;k++){
      float4 w0 = *(const float4*)(wb + (size_t)k*G4_);
      float4 w1 = *(const float4*)(wb + (size_t)k*G4_ + 4);
      float4 hA = *(const float4*)(&hsLds[k][b0]);
      float4 hB = *(const float4*)(&hsLds[k][b0+4]);
      float hv[8]={hA.x,hA.y,hA.z,hA.w,hB.x,hB.y,hB.z,hB.w};
      float wv[8]={w0.x,w0.y,w0.z,w0.w,w1.x,w1.y,w1.z,w1.w};
      #pragma unroll
      for (int i=0;i<8;i++)
        #pragma unroll
        for (int j=0;j<8;j++)
          a[i][j] = fmaf(hv[i], wv[j], a[i][j]);
    }
  }
  float bz[8];
  #pragma unroll
  for (int j=0;j<8;j++) bz[j] = bias0[n0 + tn*8 + j];
  #pragma unroll
  for (int i=0;i<8;i++){
    const int m = mb*64 + b0 + i;
    float* pd = xproj + (size_t)m*G4_ + n0 + tn*8;
    *(float4*)(pd+0) = make_float4(a[i][0]+bz[0], a[i][1]+bz[1], a[i][2]+bz[2], a[i][3]+bz[3]);
    *(float4*)(pd+4) = make_float4(a[i][4]+bz[4], a[i][5]+bz[5], a[i][6]+bz[6], a[i][7]+bz[7]);
  }
}

// ---------------- persistent LSTM pieces (fp16 weights/h in LDS) ----------------
__device__ __forceinline__ void load_weights(int tid, int us,
    const float* __restrict__ w_hh0, const float* __restrict__ w_ih1,
    const float* __restrict__ w_hh1, ushort* __restrict__ wl0h, ushort* __restrict__ wl1h)
{
  char* w0b = (char*)wl0h;
  char* w1b = (char*)wl1h;
  #pragma unroll
  for (int p = 0; p < 8; ++p) {
    const int f4 = tid + p*256;           // 0..2047 = 16 rows x 128 float4
    const int r = f4 >> 7, c4 = f4 & 127;
    const int n = (r >> 2)*H_ + us*4 + (r & 3);
    float4 v = *(const float4*)(w_hh0 + (size_t)n*H_ + c4*4);
    u32x2_t o; o.x = pkrtz(v.x, v.y); o.y = pkrtz(v.z, v.w);
    *(u32x2_t*)(w0b + r*WL0_RB + c4*8) = o;
  }
  #pragma unroll
  for (int p = 0; p < 16; ++p) {
    const int f4 = tid + p*256;           // 0..4095 = 16 rows x 256 float4
    const int r = f4 >> 8, c4 = f4 & 255;
    const int n = (r >> 2)*H_ + us*4 + (r & 3);
    float4 v = (c4 < 128) ? *(const float4*)(w_ih1 + (size_t)n*H_ + c4*4)
                          : *(const float4*)(w_hh1 + (size_t)n*H_ + (c4-128)*4);
    u32x2_t o; o.x = pkrtz(v.x, v.y); o.y = pkrtz(v.z, v.w);
    *(u32x2_t*)(w1b + r*WL1_RB + c4*8) = o;
  }
}

__device__ __forceinline__ float sigm(float x) { return 1.f/(1.f + __expf(-x)); }

// issue 8 coherent dwordx4 loads for one 32x256 f32 h-chunk into registers
__device__ __forceinline__ void stage_issue(const float* __restrict__ srcb,
    int bh, int row, int cq, int ccol, f32x4_t* vv)
{
  const float* gp = srcb + (size_t)(bh*32 + row)*H_ + ccol + cq*32;
  #pragma unroll
  for (int q = 0; q < 8; ++q)
    asm volatile("global_load_dwordx4 %0, %1, off sc0 sc1"
                 : "=v"(vv[q]) : "v"(gp + q*4) : "memory");
}
// drain loads, convert to f16, write swizzled LDS chunk [32 rows][256 halves]
__device__ __forceinline__ void stage_write_f16(char* __restrict__ hsb,
    int row, int cq, const f32x4_t* vv)
{
  asm volatile("s_waitcnt vmcnt(0)" ::: "memory");
  __builtin_amdgcn_sched_barrier(0);   // keep pkrtz below the wait (rule #18)
  const int swz = (row & 7) << 4;
  char* hrow = hsb + row*HS_RB;
  #pragma unroll
  for (int q = 0; q < 4; ++q) {
    u32x4_t o;
    o.x = pkrtz(vv[2*q].x,   vv[2*q].y);
    o.y = pkrtz(vv[2*q].z,   vv[2*q].w);
    o.z = pkrtz(vv[2*q+1].x, vv[2*q+1].y);
    o.w = pkrtz(vv[2*q+1].z, vv[2*q+1].w);
    *(u32x4_t*)(hrow + ((cq*64 + q*16) ^ swz)) = o;
  }
}

__device__ __forceinline__ void lstm_iter(int t, int maxL, int bh, int us,
    const ushort* __restrict__ wl0h, const ushort* __restrict__ wl1h,
    float* __restrict__ hsf,
    const float* __restrict__ xproj, const float* __restrict__ bias1,
    const int* __restrict__ map, const int* __restrict__ Lp,
    const float* __restrict__ h0c, float* __restrict__ h0n,
    const float* __restrict__ h1c, float* __restrict__ h1n,
    float* __restrict__ c0, float* __restrict__ c1, float* __restrict__ hlast)
{
  const int tid  = threadIdx.x;
  const int slot = tid & 15, kg = tid >> 4;      // 16 slots x 16 k-groups
  const int bgrp = slot & 3, ngrp = slot >> 2;
  const int b8   = bgrp * 8;
  const int row  = tid & 31, cq = tid >> 5;
  char* hsb = (char*)hsf;
  const char* w0base = (const char*)wl0h + ngrp*WL0_RB;
  const char* w1base = (const char*)wl1h + ngrp*WL1_RB;

  // ---- prefetch this step's xproj gate inputs (L0 gate threads) ----
  float xg0=0.f, xg1=0.f, xg2=0.f, xg3=0.f;
  int rpre = -1;
  if (tid < 128) {
    const int b = bh*32 + (tid & 31);
    if (t <= maxL) rpre = map[b*S_ + t];
    const int rr = rpre < 0 ? 0 : rpre;
    const float* xp = xproj + ((size_t)b*NR_ + rr)*G4_ + (us*4 + (tid>>5));
    xg0 = xp[0]; xg1 = xp[512]; xg2 = xp[1024]; xg3 = xp[1536];
  }

  float acc0[8][4], acc1[8][4];
  #pragma unroll
  for (int i=0;i<8;i++)
    #pragma unroll
    for (int j=0;j<4;j++){ acc0[i][j]=0.f; acc1[i][j]=0.f; }

  f32x4_t vv[8];
  stage_issue(h0c, bh, row, cq, 0, vv);          // prefetch chunk 0

  // ---- GEMM over 4 chunks of 256 k (c<2: h0 -> L0 & L1-x; c>=2: h1 -> L1-h) ----
  for (int c = 0; c < 4; ++c) {
    stage_write_f16(hsb, row, cq, vv);
    __syncthreads();
    if (c < 3) {                                  // prefetch next chunk
      const float* nsrc = (c + 1 < 2) ? h0c : h1c;
      stage_issue(nsrc, bh, row, cq, ((c+1) & 1)*256, vv);
    }
    const int kb0 = kg * 32;                      // byte base of this kg's k-slice
    if (c < 2) {
      const char* w0r = w0base + c*512;
      const char* w1r = w1base + c*512;
      #pragma unroll
      for (int k4 = 0; k4 < 4; ++k4) {
        const int kb = kb0 + ((((k4 + bgrp) & 3)) << 3);   // bgrp-rotated: conflict-free
        u32x2_t hv[8];
        #pragma unroll
        for (int i = 0; i < 8; ++i)
          hv[i] = *(const u32x2_t*)(hsb + (b8+i)*HS_RB + (kb ^ (i<<4)));
        #pragma unroll
        for (int j = 0; j < 4; ++j) {
          const u32x2_t w0 = *(const u32x2_t*)(w0r + j*4*WL0_RB + kb);
          const u32x2_t w1 = *(const u32x2_t*)(w1r + j*4*WL1_RB + kb);
          #pragma unroll
          for (int i = 0; i < 8; ++i) {
            dot2(acc0[i][j], hv[i].x, w0.x);
            dot2(acc0[i][j], hv[i].y, w0.y);
            dot2(acc1[i][j], hv[i].x, w1.x);
            dot2(acc1[i][j], hv[i].y, w1.y);
          }
        }
      }
    } else {
      const char* w1r = w1base + 1024 + (c-2)*512;
      #pragma unroll
      for (int k4 = 0; k4 < 4; ++k4) {
        const int kb = kb0 + ((((k4 + bgrp) & 3)) << 3);
        u32x2_t hv[8];
        #pragma unroll
        for (int i = 0; i < 8; ++i)
          hv[i] = *(const u32x2_t*)(hsb + (b8+i)*HS_RB + (kb ^ (i<<4)));
        #pragma unroll
        for (int j = 0; j < 4; ++j) {
          const u32x2_t w1 = *(const u32x2_t*)(w1r + j*4*WL1_RB + kb);
          #pragma unroll
          for (int i = 0; i < 8; ++i) {
            dot2(acc1[i][j], hv[i].x, w1.x);
            dot2(acc1[i][j], hv[i].y, w1.y);
          }
        }
      }
    }
    __syncthreads();
  }

  // ---- reduce 16 kg -> 4 wave-partials (shfl) -> LDS ----
  #pragma unroll
  for (int i = 0; i < 8; ++i)
    #pragma unroll
    for (int j = 0; j < 4; ++j) {
      float v0 = acc0[i][j], v1 = acc1[i][j];
      v0 += __shfl_xor(v0, 16); v0 += __shfl_xor(v0, 32);
      v1 += __shfl_xor(v1, 16); v1 += __shfl_xor(v1, 32);
      acc0[i][j] = v0; acc1[i][j] = v1;
    }
  if (((tid >> 4) & 3) == 0) {
    const int base = ((tid >> 6)*16 + slot)*32;
    #pragma unroll
    for (int i = 0; i < 8; ++i)
      #pragma unroll
      for (int j = 0; j < 4; ++j) {
        hsf[base + i*4 + j]        = acc0[i][j];
        hsf[2048 + base + i*4 + j] = acc1[i][j];
      }
  }
  __syncthreads();

  // ---- gates: L0 workers tid<128, L1 workers tid>=128 ----
  if (tid < 128) {
    const int bl = tid & 31, ul = tid >> 5;
    const int b = bh*32 + bl, u = us*4 + ul;
    const int idx = b*H_ + u;
    if (rpre >= 0) {
      const int slot2 = (ul << 2) | (bl >> 3);
      const int i2 = bl & 7;
      float g0=xg0, g1=xg1, g2=xg2, g3=xg3;
      #pragma unroll
      for (int wv = 0; wv < 4; ++wv) {
        const int base = (wv*16 + slot2)*32 + i2*4;
        g0 += hsf[base+0]; g1 += hsf[base+1]; g2 += hsf[base+2]; g3 += hsf[base+3];
      }
      const float cc = sigm(g1)*c0[idx] + sigm(g0)*tanhf(g2);
      c0[idx] = cc;
      store_f_cc(h0n + idx, sigm(g3)*tanhf(cc));
    } else {
      store_f_cc(h0n + idx, load_f_cc(h0c + idx));
    }
  } else {
    const int w2 = tid & 127;
    const int bl = w2 & 31, ul = w2 >> 5;
    const int b = bh*32 + bl, u = us*4 + ul;
    const int idx = b*H_ + u;
    const int s = t - 1;
    const int r = (s >= 0 && s <= maxL) ? map[b*S_ + s] : -1;
    if (r >= 0) {
      const int slot2 = (ul << 2) | (bl >> 3);
      const int i2 = bl & 7;
      float g0=0.f, g1=0.f, g2=0.f, g3=0.f;
      #pragma unroll
      for (int wv = 0; wv < 4; ++wv) {
        const int base = 2048 + (wv*16 + slot2)*32 + i2*4;
        g0 += hsf[base+0]; g1 += hsf[base+1]; g2 += hsf[base+2]; g3 += hsf[base+3];
      }
      g0 += bias1[u]; g1 += bias1[512+u]; g2 += bias1[1024+u]; g3 += bias1[1536+u];
      const float cc = sigm(g1)*c1[idx] + sigm(g0)*tanhf(g2);
      c1[idx] = cc;
      const float hn = sigm(g3)*tanhf(cc);
      store_f_cc(h1n + idx, hn);
      if (s == Lp[b]) store_f_cc(hlast + idx, hn);
    } else {
      store_f_cc(h1n + idx, load_f_cc(h1c + idx));
    }
  }
}

__device__ __forceinline__ void fc_epilogue(int tid,
    const float* __restrict__ hlast, const float* __restrict__ fcw,
    const float* __restrict__ fcb, float* __restrict__ out)
{
  if (tid < 128) {
    const int b = tid >> 1, half = tid & 1;
    const float* hv = hlast + (size_t)b*H_ + half*256;
    const float* fw = fcw + half*256;
    float s = 0.f;
    #pragma unroll 8
    for (int u = 0; u < 256; ++u) s = fmaf(hv[u], fw[u], s);
    s += __shfl_xor(s, 1);
    if (half == 0) out[b] = s + fcb[0];
  }
}

// ---------------- custom two-level grid barrier (no cache flushes) ----------------
__device__ __forceinline__ void grid_barrier(int* __restrict__ bar, int blk, int g)
{
  asm volatile("s_waitcnt vmcnt(0)" ::: "memory");  // drain this thread's sc stores
  __syncthreads();                                   // all threads' stores drained
  if (threadIdx.x == 0) {
    int* lp = bar + (blk >> 4) * 16;
    int* rp = bar + 256;
    int* gp = bar + 272;
    bool last = false;
    if (atomicAdd(lp, 1) == g*16 - 1) {
      if (atomicAdd(rp, 1) == g*16 - 1) {
        __hip_atomic_store(gp, g, __ATOMIC_RELAXED, __HIP_MEMORY_SCOPE_AGENT);
        last = true;
      }
    }
    if (!last) {
      while (__hip_atomic_load(gp, __ATOMIC_RELAXED, __HIP_MEMORY_SCOPE_AGENT) < g)
        __builtin_amdgcn_s_sleep(1);
    }
  }
  __syncthreads();
}

// ---------------- cooperative persistent kernel ----------------
__global__ __launch_bounds__(256, 1) void k_lstm_coop(
    const float* __restrict__ w_hh0, const float* __restrict__ w_ih1,
    const float* __restrict__ w_hh1, const float* __restrict__ xproj,
    const float* __restrict__ bias1, const int* __restrict__ Lp,
    const int* __restrict__ maxLp, const int* __restrict__ map,
    float* __restrict__ h0b, float* __restrict__ h1b,
    float* __restrict__ c0, float* __restrict__ c1, float* __restrict__ hlast,
    const float* __restrict__ fcw, const float* __restrict__ fcb,
    float* __restrict__ out, int* __restrict__ bar)
{
  __shared__ __align__(16) ushort wl0h[16*520];
  __shared__ __align__(16) ushort wl1h[16*1032];
  __shared__ __align__(16) float  hsf[4096];
  const int blk = blockIdx.x;
  const int bh = blk & 1, us = blk >> 1;
  load_weights(threadIdx.x, us, w_hh0, w_ih1, w_hh1, wl0h, wl1h);
  __syncthreads();
  const int maxL = *maxLp;
  for (int t = 0; t <= maxL + 1; ++t) {
    const float* h0c = h0b + (size_t)(t & 1)*(B_*H_);
    float*       h0n = h0b + (size_t)((t+1) & 1)*(B_*H_);
    const float* h1c = h1b + (size_t)(t & 1)*(B_*H_);
    float*       h1n = h1b + (size_t)((t+1) & 1)*(B_*H_);
    lstm_iter(t, maxL, bh, us, wl0h, wl1h, hsf, xproj, bias1, map, Lp,
              h0c, h0n, h1c, h1n, c0, c1, hlast);
    grid_barrier(bar, blk, t + 1);
  }
  if (blk == 0) fc_epilogue(threadIdx.x, hlast, fcw, fcb, out);
}

// ---------------- non-cooperative fallback: one iteration per launch ----------------
__global__ __launch_bounds__(256, 1) void k_step(int t,
    const float* __restrict__ w_hh0, const float* __restrict__ w_ih1,
    const float* __restrict__ w_hh1, const float* __restrict__ xproj,
    const float* __restrict__ bias1, const int* __restrict__ Lp,
    const int* __restrict__ maxLp, const int* __restrict__ map,
    float* __restrict__ h0b, float* __restrict__ h1b,
    float* __restrict__ c0, float* __restrict__ c1, float* __restrict__ hlast)
{
  __shared__ __align__(16) ushort wl0h[16*520];
  __shared__ __align__(16) ushort wl1h[16*1032];
  __shared__ __align__(16) float  hsf[4096];
  const int blk = blockIdx.x;
  const int bh = blk & 1, us = blk >> 1;
  load_weights(threadIdx.x, us, w_hh0, w_ih1, w_hh1, wl0h, wl1h);
  __syncthreads();
  const int maxL = *maxLp;
  if (t > maxL + 1) return;
  const float* h0c = h0b + (size_t)(t & 1)*(B_*H_);
  float*       h0n = h0b + (size_t)((t+1) & 1)*(B_*H_);
  const float* h1c = h1b + (size_t)(t & 1)*(B_*H_);
  float*       h1n = h1b + (size_t)((t+1) & 1)*(B_*H_);
  lstm_iter(t, maxL, bh, us, wl0h, wl1h, hsf, xproj, bias1, map, Lp,
            h0c, h0n, h1c, h1n, c0, c1, hlast);
}

__global__ __launch_bounds__(128) void k_fc(
    const float* __restrict__ hlast, const float* __restrict__ fcw,
    const float* __restrict__ fcb, float* __restrict__ out)
{
  fc_epilogue(threadIdx.x, hlast, fcw, fcb, out);
}

// ---------------- host ----------------
extern "C" void kernel_launch(void* const* d_in, const int* in_sizes, int n_in,
                              void* d_out, int out_size, void* d_ws, size_t ws_size,
                              hipStream_t stream)
{
  const float* text  = (const float*)d_in[0];
  const float* ques  = (const float*)d_in[1];
  const float* code  = (const float*)d_in[2];
  const int*   ns    = (const int*)  d_in[3];
  const int*   que   = (const int*)  d_in[4];
  const float* w_ih0 = (const float*)d_in[5];
  const float* w_hh0 = (const float*)d_in[6];
  const float* b_ih0 = (const float*)d_in[7];
  const float* b_hh0 = (const float*)d_in[8];
  const float* w_ih1 = (const float*)d_in[9];
  const float* w_hh1 = (const float*)d_in[10];
  const float* b_ih1 = (const float*)d_in[11];
  const float* b_hh1 = (const float*)d_in[12];
  const float* fcw   = (const float*)d_in[13];
  const float* fcb   = (const float*)d_in[14];
  float* out = (float*)d_out;

  char* ws = (char*)d_ws;
  int*   Lp     = (int*)  (ws + OFF_L);
  int*   maxLp  = (int*)  (ws + OFF_MAXL);
  int*   map    = (int*)  (ws + OFF_MAP);
  float* bias0  = (float*)(ws + OFF_BIAS0);
  float* bias1  = (float*)(ws + OFF_BIAS1);
  float* c0     = (float*)(ws + OFF_C0);
  float* c1     = (float*)(ws + OFF_C1);
  float* hlast  = (float*)(ws + OFF_HLAST);
  float* h0b    = (float*)(ws + OFF_H0B);
  float* h1b    = (float*)(ws + OFF_H1B);
  float* wT_ih0 = (float*)(ws + OFF_WTIH0);
  float* xproj  = (float*)(ws + OFF_XPROJ);
  int*   bar    = (int*)  (ws + OFF_BAR);
  (void)in_sizes; (void)n_in; (void)out_size; (void)ws_size; (void)WS_NEED;

  hipLaunchKernelGGL(k_prep, dim3(1), dim3(256), 0, stream,
                     ns, que, b_ih0, b_hh0, b_ih1, b_hh1,
                     Lp, maxLp, map, bias0, bias1, c0, c1, hlast, h0b, h1b, bar);

  hipLaunchKernelGGL(k_transpose, dim3(64, 24), dim3(32, 8), 0, stream,
                     w_ih0, wT_ih0);

  hipLaunchKernelGGL(k_proj, dim3(81, 16), dim3(128), 0, stream,
                     text, ques, code, wT_ih0, bias0, xproj);

  const float* a_whh0 = w_hh0; const float* a_wih1 = w_ih1; const float* a_whh1 = w_hh1;
  const float* a_xp = xproj;   const float* a_b1 = bias1;
  const int* a_Lp = Lp; const int* a_maxLp = maxLp; const int* a_map = map;
  float* a_h0b = h0b; float* a_h1b = h1b; float* a_c0 = c0; float* a_c1 = c1;
  float* a_hl = hlast; const float* a_fcw = fcw; const float* a_fcb = fcb;
  float* a_out = out; int* a_bar = bar;
  void* args[] = { &a_whh0, &a_wih1, &a_whh1, &a_xp, &a_b1, &a_Lp, &a_maxLp, &a_map,
                   &a_h0b, &a_h1b, &a_c0, &a_c1, &a_hl, &a_fcw, &a_fcb, &a_out, &a_bar };

  hipError_t err = hipLaunchCooperativeKernel((const void*)k_lstm_coop,
                                              dim3(256), dim3(256), args, 0, stream);
  if (err != hipSuccess) {
    (void)hipGetLastError();  // clear error state
    for (int t = 0; t < S_ + 1; ++t) {
      hipLaunchKernelGGL(k_step, dim3(256), dim3(256), 0, stream, t,
                         w_hh0, w_ih1, w_hh1, xproj, bias1, Lp, maxLp, map,
                         h0b, h1b, c0, c1, hlast);
    }
    hipLaunchKernelGGL(k_fc, dim3(1), dim3(128), 0, stream, hlast, fcw, fcb, out);
  }
}

// Round 7
// 5254.506 us; speedup vs baseline: 2.9599x; 1.3412x over previous
//
#include <hip/hip_runtime.h>
#include <hip/hip_cooperative_groups.h>

namespace cg = cooperative_groups;

#define B_    64
#define Q_    16
#define MAXK_ 32
#define C_    64
#define D_    768
#define H_    512
#define G4_   2048   // 4*H
#define S_    529    // Q*(MAXK+1)+1
#define NR_   81     // 16 questions + 64 code + 1 text

typedef float f32x4_t __attribute__((ext_vector_type(4)));
typedef unsigned int u32x2_t __attribute__((ext_vector_type(2)));
typedef unsigned int u32x4_t __attribute__((ext_vector_type(4)));

// LDS geometry (bytes)
#define WL0_RB 1040   // 16 rows x (512 halves + 8 pad) : W_hh0 slice
#define WL1_RB 2064   // 16 rows x (1024 halves + 8 pad): [W_ih1|W_hh1] slice
#define HS_RB  1024   // 16 rows x 512 halves (one k-chunk)

// ---------------- workspace layout (bytes) ----------------
static constexpr size_t OFF_L     = 0;                      // 64 int
static constexpr size_t OFF_MAXL  = 256;
static constexpr size_t OFF_MAP   = 512;                    // 64*529*4
static constexpr size_t OFF_BIAS0 = OFF_MAP   + 135424;     // 2048 f
static constexpr size_t OFF_BIAS1 = OFF_BIAS0 + 8192;       // 2048 f
static constexpr size_t OFF_C0    = OFF_BIAS1 + 8192;       // 64*512 f
static constexpr size_t OFF_C1    = OFF_C0    + 131072;
static constexpr size_t OFF_HLAST = OFF_C1    + 131072;     // 64*512 f (fp32)
static constexpr size_t OFF_H0B   = OFF_HLAST + 131072;     // 2 x 64*512 half
static constexpr size_t OFF_H1B   = OFF_H0B   + 262144;
static constexpr size_t OFF_WTIH0 = OFF_H1B   + 262144;     // 768x2048 f
static constexpr size_t OFF_XPROJ = OFF_WTIH0 + 6291456ULL; // 64*81*2048 f
static constexpr size_t OFF_BAR   = OFF_XPROJ + 42467328ULL; // 1024 int barrier state
static constexpr size_t WS_NEED   = OFF_BAR   + 4096;

// ---------------- coherent (L2-bypass) access helpers ----------------
__device__ __forceinline__ void store_us_cc(ushort* p, unsigned int v) {
  asm volatile("global_store_short %0, %1, off sc0 sc1" :: "v"(p), "v"(v) : "memory");
}
__device__ __forceinline__ unsigned int load_us_cc(const ushort* p) {
  unsigned int v;
  asm volatile("global_load_ushort %0, %1, off sc0 sc1\n\ts_waitcnt vmcnt(0)"
               : "=v"(v) : "v"(p) : "memory");
  return v;
}
__device__ __forceinline__ void store_f_cc(float* p, float v) {
  asm volatile("global_store_dword %0, %1, off sc0 sc1" :: "v"(p), "v"(v) : "memory");
}

__device__ __forceinline__ void dot2(float& acc, unsigned int a, unsigned int b) {
  asm("v_dot2_f32_f16 %0, %1, %2, %0" : "+v"(acc) : "v"(a), "v"(b));
}
__device__ __forceinline__ unsigned int pkrtz(float a, float b) {
  auto r = __builtin_amdgcn_cvt_pkrtz(a, b);   // __fp16 ext_vector_type(2)
  unsigned int u;
  __builtin_memcpy(&u, &r, 4);
  return u;
}
__device__ __forceinline__ unsigned int f2h(float a) {
  return pkrtz(a, 0.f) & 0xffffu;              // low half = RTZ f32->f16 of a
}

// ---------------- prep ----------------
__global__ __launch_bounds__(256) void k_prep(
    const int* __restrict__ ns, const int* __restrict__ que,
    const float* __restrict__ b_ih0, const float* __restrict__ b_hh0,
    const float* __restrict__ b_ih1, const float* __restrict__ b_hh1,
    int* __restrict__ Lp, int* __restrict__ maxLp, int* __restrict__ map,
    float* __restrict__ bias0, float* __restrict__ bias1,
    float* __restrict__ c0, float* __restrict__ c1, float* __restrict__ hlast,
    ushort* __restrict__ h0b, ushort* __restrict__ h1b, int* __restrict__ bar)
{
  const int tid = threadIdx.x;
  for (int i = tid; i < B_*S_; i += 256) map[i] = -1;
  for (int i = tid; i < G4_; i += 256) {
    bias0[i] = b_ih0[i] + b_hh0[i];
    bias1[i] = b_ih1[i] + b_hh1[i];
  }
  int* h0i = (int*)h0b;  // 2 bufs x 64*512 halves = 32768 ints
  int* h1i = (int*)h1b;
  for (int i = tid; i < B_*H_; i += 256) {
    c0[i]=0.f; c1[i]=0.f; hlast[i]=0.f;
    h0i[i]=0; h1i[i]=0;
  }
  for (int i = tid; i < 1024; i += 256) bar[i] = 0;
  if (tid == 0) *maxLp = 0;
  __syncthreads();
  if (tid < B_) {
    const int b = tid;
    const int qn = que[b];
    int pos = 0;
    int* m = map + b*S_;
    for (int q = 0; q < qn; ++q) {
      m[pos++] = q;
      const int n = ns[b*Q_ + q];
      for (int k = 0; k < n; ++k) {
        int j = q + k; if (j > C_-1) j = C_-1;
        m[pos++] = 16 + j;
      }
    }
    m[pos] = 80;
    Lp[b] = pos;
    atomicMax(maxLp, pos);
  }
}

// ---------------- transpose W_ih0 only: [2048][768] -> [768][2048] ----------------
__global__ __launch_bounds__(256) void k_transpose(
    const float* __restrict__ w, float* __restrict__ wT)
{
  __shared__ float tile[32][33];
  const int n0 = blockIdx.x * 32;
  const int k0 = blockIdx.y * 32;
  const int tx = threadIdx.x, ty = threadIdx.y;
  for (int i = ty; i < 32; i += 8)
    tile[i][tx] = w[(size_t)(n0+i)*D_ + k0 + tx];
  __syncthreads();
  for (int i = ty; i < 32; i += 8)
    wT[(size_t)(k0 + i)*G4_ + n0 + tx] = tile[tx][i];
}

// ---------------- xproj: project 81 distinct source rows per batch (fp32) ----------------
__global__ __launch_bounds__(128, 2) void k_proj(
    const float* __restrict__ text, const float* __restrict__ ques,
    const float* __restrict__ code, const float* __restrict__ wT_ih0,
    const float* __restrict__ bias0, float* __restrict__ xproj)
{
  __shared__ float hsLds[32][64];
  const int mb = blockIdx.x, nb = blockIdx.y;
  const int n0 = nb * 128;
  const int tid = threadIdx.x;
  const int tb = tid >> 4, tn = tid & 15;
  const int b0 = tb * 8;
  const int bb = tid >> 1, hh = tid & 1;

  const int mrow = mb*64 + bb;
  const int sb = mrow / NR_, sr = mrow % NR_;
  const float* srcrow = (sr < 16) ? (ques + ((size_t)sb*Q_ + sr)*D_)
                      : (sr < 80) ? (code + ((size_t)sb*C_ + (sr-16))*D_)
                                  : (text + (size_t)sb*D_);

  float a[8][8];
  #pragma unroll
  for (int i=0;i<8;i++)
    #pragma unroll
    for (int j=0;j<8;j++) a[i][j]=0.f;

  for (int k0 = 0; k0 < D_; k0 += 32) {
    __syncthreads();
    {
      const float* p = srcrow + k0 + hh*16;
      float4 v0 = *(const float4*)(p+0);
      float4 v1 = *(const float4*)(p+4);
      float4 v2 = *(const float4*)(p+8);
      float4 v3 = *(const float4*)(p+12);
      const int kk = hh*16;
      hsLds[kk+ 0][bb]=v0.x; hsLds[kk+ 1][bb]=v0.y; hsLds[kk+ 2][bb]=v0.z; hsLds[kk+ 3][bb]=v0.w;
      hsLds[kk+ 4][bb]=v1.x; hsLds[kk+ 5][bb]=v1.y; hsLds[kk+ 6][bb]=v1.z; hsLds[kk+ 7][bb]=v1.w;
      hsLds[kk+ 8][bb]=v2.x; hsLds[kk+ 9][bb]=v2.y; hsLds[kk+10][bb]=v2.z; hsLds[kk+11][bb]=v2.w;
      hsLds[kk+12][bb]=v3.x; hsLds[kk+13][bb]=v3.y; hsLds[kk+14][bb]=v3.z; hsLds[kk+15][bb]=v3.w;
    }
    __syncthreads();
    const float* wb = wT_ih0 + (size_t)k0*G4_ + n0 + tn*8;
    #pragma unroll 4
    for (int k=0;k<32;k++){
      float4 w0 = *(const float4*)(wb + (size_t)k*G4_);
      float4 w1 = *(const float4*)(wb + (size_t)k*G4_ + 4);
      float4 hA = *(const float4*)(&hsLds[k][b0]);
      float4 hB = *(const float4*)(&hsLds[k][b0+4]);
      float hv[8]={hA.x,hA.y,hA.z,hA.w,hB.x,hB.y,hB.z,hB.w};
      float wv[8]={w0.x,w0.y,w0.z,w0.w,w1.x,w1.y,w1.z,w1.w};
      #pragma unroll
      for (int i=0;i<8;i++)
        #pragma unroll
        for (int j=0;j<8;j++)
          a[i][j] = fmaf(hv[i], wv[j], a[i][j]);
    }
  }
  float bz[8];
  #pragma unroll
  for (int j=0;j<8;j++) bz[j] = bias0[n0 + tn*8 + j];
  #pragma unroll
  for (int i=0;i<8;i++){
    const int m = mb*64 + b0 + i;
    float* pd = xproj + (size_t)m*G4_ + n0 + tn*8;
    *(float4*)(pd+0) = make_float4(a[i][0]+bz[0], a[i][1]+bz[1], a[i][2]+bz[2], a[i][3]+bz[3]);
    *(float4*)(pd+4) = make_float4(a[i][4]+bz[4], a[i][5]+bz[5], a[i][6]+bz[6], a[i][7]+bz[7]);
  }
}

// ---------------- persistent LSTM pieces ----------------
// 512 blocks: bh = blk & 3 (16 batches), us = blk >> 2 (4 units).
// Weights f16 in LDS (16 rows each matrix); h exchanged as f16 via LLC.
__device__ __forceinline__ void load_weights(int tid, int us,
    const float* __restrict__ w_hh0, const float* __restrict__ w_ih1,
    const float* __restrict__ w_hh1, ushort* __restrict__ wl0h, ushort* __restrict__ wl1h)
{
  char* w0b = (char*)wl0h;
  char* w1b = (char*)wl1h;
  #pragma unroll
  for (int p = 0; p < 8; ++p) {
    const int f4 = tid + p*256;           // 0..2047 = 16 rows x 128 float4
    const int r = f4 >> 7, c4 = f4 & 127;
    const int n = (r >> 2)*H_ + us*4 + (r & 3);
    float4 v = *(const float4*)(w_hh0 + (size_t)n*H_ + c4*4);
    u32x2_t o; o.x = pkrtz(v.x, v.y); o.y = pkrtz(v.z, v.w);
    *(u32x2_t*)(w0b + r*WL0_RB + c4*8) = o;
  }
  #pragma unroll
  for (int p = 0; p < 16; ++p) {
    const int f4 = tid + p*256;           // 0..4095 = 16 rows x 256 float4
    const int r = f4 >> 8, c4 = f4 & 255;
    const int n = (r >> 2)*H_ + us*4 + (r & 3);
    float4 v = (c4 < 128) ? *(const float4*)(w_ih1 + (size_t)n*H_ + c4*4)
                          : *(const float4*)(w_hh1 + (size_t)n*H_ + (c4-128)*4);
    u32x2_t o; o.x = pkrtz(v.x, v.y); o.y = pkrtz(v.z, v.w);
    *(u32x2_t*)(w1b + r*WL1_RB + c4*8) = o;
  }
}

__device__ __forceinline__ float sigm(float x) { return 1.f/(1.f + __expf(-x)); }

// issue 4 coherent dwordx4 loads for one 16x512-half chunk
__device__ __forceinline__ void stage_issue(const ushort* __restrict__ srcb,
    int bh, int row, int cq, u32x4_t* vvh)
{
  const ushort* gp = srcb + (size_t)(bh*16 + row)*H_ + cq*32;
  #pragma unroll
  for (int q = 0; q < 4; ++q)
    asm volatile("global_load_dwordx4 %0, %1, off sc0 sc1"
                 : "=v"(vvh[q]) : "v"(gp + q*8) : "memory");
}
// drain loads, write swizzled LDS chunk [16 rows][512 halves]
__device__ __forceinline__ void stage_write(char* __restrict__ hsb,
    int row, int cq, const u32x4_t* vvh)
{
  asm volatile("s_waitcnt vmcnt(0)" ::: "memory");
  __builtin_amdgcn_sched_barrier(0);   // rule #18
  const int swz = (row & 7) << 4;
  char* hrow = hsb + row*HS_RB;
  #pragma unroll
  for (int q = 0; q < 4; ++q)
    *(u32x4_t*)(hrow + ((cq*64 + q*16) ^ swz)) = vvh[q];
}

__device__ __forceinline__ void lstm_iter(int t, int maxL, int bh, int us,
    const ushort* __restrict__ wl0h, const ushort* __restrict__ wl1h,
    float* __restrict__ hsf,
    const float* __restrict__ xproj, const float* __restrict__ bias1,
    const int* __restrict__ map, const int* __restrict__ Lp,
    const ushort* __restrict__ h0c, ushort* __restrict__ h0n,
    const ushort* __restrict__ h1c, ushort* __restrict__ h1n,
    float* __restrict__ c0, float* __restrict__ c1, float* __restrict__ hlast)
{
  const int tid  = threadIdx.x;
  const int slot = tid & 15, kg = tid >> 4;      // 16 slots x 16 k-groups
  const int bgrp = slot & 3, ngrp = slot >> 2;
  const int b4   = bgrp * 4;
  const int row  = tid & 15, cq = tid >> 4;      // staging map
  char* hsb = (char*)hsf;
  const char* w0base = (const char*)wl0h + ngrp*WL0_RB;
  const char* w1base = (const char*)wl1h + ngrp*WL1_RB;

  // ---- prefetch this step's xproj gate inputs (L0 gate threads) ----
  float xg0=0.f, xg1=0.f, xg2=0.f, xg3=0.f;
  int rpre = -1;
  if (tid < 64) {
    const int b = bh*16 + (tid & 15);
    if (t <= maxL) rpre = map[b*S_ + t];
    const int rr = rpre < 0 ? 0 : rpre;
    const float* xp = xproj + ((size_t)b*NR_ + rr)*G4_ + (us*4 + (tid>>4));
    xg0 = xp[0]; xg1 = xp[512]; xg2 = xp[1024]; xg3 = xp[1536];
  }

  float acc0[4][4], acc1[4][4];
  #pragma unroll
  for (int i=0;i<4;i++)
    #pragma unroll
    for (int j=0;j<4;j++){ acc0[i][j]=0.f; acc1[i][j]=0.f; }

  u32x4_t vvh[4];
  stage_issue(h0c, bh, row, cq, vvh);            // chunk A = h0

  // ---- chunk A: h0 (512 halves) -> acc0 (L0) + acc1 (L1-x) ----
  stage_write(hsb, row, cq, vvh);
  __syncthreads();
  stage_issue(h1c, bh, row, cq, vvh);            // prefetch chunk B = h1
  #pragma unroll
  for (int k4 = 0; k4 < 8; ++k4) {
    const int rot = (k4 + bgrp) & 7;
    const int kb = kg*64 + rot*8;
    u32x2_t hv[4];
    #pragma unroll
    for (int i = 0; i < 4; ++i)
      hv[i] = *(const u32x2_t*)(hsb + (b4+i)*HS_RB + (kb ^ (((b4+i)&7)<<4)));
    #pragma unroll
    for (int j = 0; j < 4; ++j) {
      const u32x2_t w0 = *(const u32x2_t*)(w0base + j*4*WL0_RB + kb);
      const u32x2_t w1 = *(const u32x2_t*)(w1base + j*4*WL1_RB + kb);
      #pragma unroll
      for (int i = 0; i < 4; ++i) {
        dot2(acc0[i][j], hv[i].x, w0.x);
        dot2(acc0[i][j], hv[i].y, w0.y);
        dot2(acc1[i][j], hv[i].x, w1.x);
        dot2(acc1[i][j], hv[i].y, w1.y);
      }
    }
  }
  __syncthreads();                               // done reading chunk A

  // ---- chunk B: h1 (512 halves) -> acc1 (L1-h) ----
  stage_write(hsb, row, cq, vvh);
  __syncthreads();
  #pragma unroll
  for (int k4 = 0; k4 < 8; ++k4) {
    const int rot = (k4 + bgrp) & 7;
    const int kb = kg*64 + rot*8;
    u32x2_t hv[4];
    #pragma unroll
    for (int i = 0; i < 4; ++i)
      hv[i] = *(const u32x2_t*)(hsb + (b4+i)*HS_RB + (kb ^ (((b4+i)&7)<<4)));
    #pragma unroll
    for (int j = 0; j < 4; ++j) {
      const u32x2_t w1 = *(const u32x2_t*)(w1base + 1024 + j*4*WL1_RB + kb);
      #pragma unroll
      for (int i = 0; i < 4; ++i) {
        dot2(acc1[i][j], hv[i].x, w1.x);
        dot2(acc1[i][j], hv[i].y, w1.y);
      }
    }
  }
  __syncthreads();                               // before reduce reuses hs

  // ---- reduce 16 kg -> 4 wave-partials (shfl) -> LDS ----
  #pragma unroll
  for (int i = 0; i < 4; ++i)
    #pragma unroll
    for (int j = 0; j < 4; ++j) {
      float v0 = acc0[i][j], v1 = acc1[i][j];
      v0 += __shfl_xor(v0, 16); v0 += __shfl_xor(v0, 32);
      v1 += __shfl_xor(v1, 16); v1 += __shfl_xor(v1, 32);
      acc0[i][j] = v0; acc1[i][j] = v1;
    }
  if (((tid >> 4) & 3) == 0) {
    const int base = (tid >> 6)*256 + slot*16;
    #pragma unroll
    for (int i = 0; i < 4; ++i)
      #pragma unroll
      for (int j = 0; j < 4; ++j) {
        hsf[base + i*4 + j]        = acc0[i][j];
        hsf[1024 + base + i*4 + j] = acc1[i][j];
      }
  }
  __syncthreads();

  // ---- gates: L0 threads 0..63, L1 threads 64..127 ----
  if (tid < 64) {
    const int bl = tid & 15, ul = tid >> 4;
    const int b = bh*16 + bl, u = us*4 + ul;
    const int idx = b*H_ + u;
    if (rpre >= 0) {
      const int sbase = (ul*4 + (bl>>2))*16 + (bl&3)*4;
      float g0=xg0, g1=xg1, g2=xg2, g3=xg3;
      #pragma unroll
      for (int wv = 0; wv < 4; ++wv) {
        const int base = wv*256 + sbase;
        g0 += hsf[base+0]; g1 += hsf[base+1]; g2 += hsf[base+2]; g3 += hsf[base+3];
      }
      const float cc = sigm(g1)*c0[idx] + sigm(g0)*tanhf(g2);
      c0[idx] = cc;
      store_us_cc(h0n + idx, f2h(sigm(g3)*tanhf(cc)));
    } else {
      store_us_cc(h0n + idx, load_us_cc(h0c + idx));
    }
  } else if (tid < 128) {
    const int w2 = tid - 64;
    const int bl = w2 & 15, ul = w2 >> 4;
    const int b = bh*16 + bl, u = us*4 + ul;
    const int idx = b*H_ + u;
    const int s = t - 1;
    const int r = (s >= 0 && s <= maxL) ? map[b*S_ + s] : -1;
    if (r >= 0) {
      const int sbase = (ul*4 + (bl>>2))*16 + (bl&3)*4;
      float g0=0.f, g1=0.f, g2=0.f, g3=0.f;
      #pragma unroll
      for (int wv = 0; wv < 4; ++wv) {
        const int base = 1024 + wv*256 + sbase;
        g0 += hsf[base+0]; g1 += hsf[base+1]; g2 += hsf[base+2]; g3 += hsf[base+3];
      }
      g0 += bias1[u]; g1 += bias1[512+u]; g2 += bias1[1024+u]; g3 += bias1[1536+u];
      const float cc = sigm(g1)*c1[idx] + sigm(g0)*tanhf(g2);
      c1[idx] = cc;
      const float hn = sigm(g3)*tanhf(cc);
      store_us_cc(h1n + idx, f2h(hn));
      if (s == Lp[b]) store_f_cc(hlast + idx, hn);
    } else {
      store_us_cc(h1n + idx, load_us_cc(h1c + idx));
    }
  }
}

__device__ __forceinline__ void fc_epilogue(int tid,
    const float* __restrict__ hlast, const float* __restrict__ fcw,
    const float* __restrict__ fcb, float* __restrict__ out)
{
  if (tid < 128) {
    const int b = tid >> 1, half = tid & 1;
    const float* hv = hlast + (size_t)b*H_ + half*256;
    const float* fw = fcw + half*256;
    float s = 0.f;
    #pragma unroll 8
    for (int u = 0; u < 256; ++u) s = fmaf(hv[u], fw[u], s);
    s += __shfl_xor(s, 1);
    if (half == 0) out[b] = s + fcb[0];
  }
}

// ---------------- custom two-level grid barrier (512 blocks) ----------------
// leaves: 32 x (16 blocks), at bar[i*16]; root at bar[512]; gen at bar[528].
__device__ __forceinline__ void grid_barrier(int* __restrict__ bar, int blk, int g)
{
  asm volatile("s_waitcnt vmcnt(0)" ::: "memory");  // drain this thread's sc stores
  __syncthreads();                                   // all threads' stores drained
  if (threadIdx.x == 0) {
    int* lp = bar + (blk >> 4) * 16;
    int* rp = bar + 512;
    int* gp = bar + 528;
    bool last = false;
    if (atomicAdd(lp, 1) == g*16 - 1) {
      if (atomicAdd(rp, 1) == g*32 - 1) {
        __hip_atomic_store(gp, g, __ATOMIC_RELAXED, __HIP_MEMORY_SCOPE_AGENT);
        last = true;
      }
    }
    if (!last) {
      while (__hip_atomic_load(gp, __ATOMIC_RELAXED, __HIP_MEMORY_SCOPE_AGENT) < g)
        __builtin_amdgcn_s_sleep(1);
    }
  }
  __syncthreads();
}

// ---------------- cooperative persistent kernel ----------------
__global__ __launch_bounds__(256, 2) void k_lstm_coop(
    const float* __restrict__ w_hh0, const float* __restrict__ w_ih1,
    const float* __restrict__ w_hh1, const float* __restrict__ xproj,
    const float* __restrict__ bias1, const int* __restrict__ Lp,
    const int* __restrict__ maxLp, const int* __restrict__ map,
    ushort* __restrict__ h0b, ushort* __restrict__ h1b,
    float* __restrict__ c0, float* __restrict__ c1, float* __restrict__ hlast,
    const float* __restrict__ fcw, const float* __restrict__ fcb,
    float* __restrict__ out, int* __restrict__ bar)
{
  __shared__ __align__(16) ushort wl0h[16*520];
  __shared__ __align__(16) ushort wl1h[16*1032];
  __shared__ __align__(16) float  hsf[4096];
  const int blk = blockIdx.x;
  const int bh = blk & 3, us = blk >> 2;
  load_weights(threadIdx.x, us, w_hh0, w_ih1, w_hh1, wl0h, wl1h);
  __syncthreads();
  const int maxL = *maxLp;
  for (int t = 0; t <= maxL + 1; ++t) {
    const ushort* h0c = h0b + (size_t)(t & 1)*(B_*H_);
    ushort*       h0n = h0b + (size_t)((t+1) & 1)*(B_*H_);
    const ushort* h1c = h1b + (size_t)(t & 1)*(B_*H_);
    ushort*       h1n = h1b + (size_t)((t+1) & 1)*(B_*H_);
    lstm_iter(t, maxL, bh, us, wl0h, wl1h, hsf, xproj, bias1, map, Lp,
              h0c, h0n, h1c, h1n, c0, c1, hlast);
    grid_barrier(bar, blk, t + 1);
  }
  if (blk == 0) fc_epilogue(threadIdx.x, hlast, fcw, fcb, out);
}

// ---------------- non-cooperative fallback: one iteration per launch ----------------
__global__ __launch_bounds__(256, 2) void k_step(int t,
    const float* __restrict__ w_hh0, const float* __restrict__ w_ih1,
    const float* __restrict__ w_hh1, const float* __restrict__ xproj,
    const float* __restrict__ bias1, const int* __restrict__ Lp,
    const int* __restrict__ maxLp, const int* __restrict__ map,
    ushort* __restrict__ h0b, ushort* __restrict__ h1b,
    float* __restrict__ c0, float* __restrict__ c1, float* __restrict__ hlast)
{
  __shared__ __align__(16) ushort wl0h[16*520];
  __shared__ __align__(16) ushort wl1h[16*1032];
  __shared__ __align__(16) float  hsf[4096];
  const int blk = blockIdx.x;
  const int bh = blk & 3, us = blk >> 2;
  load_weights(threadIdx.x, us, w_hh0, w_ih1, w_hh1, wl0h, wl1h);
  __syncthreads();
  const int maxL = *maxLp;
  if (t > maxL + 1) return;
  const ushort* h0c = h0b + (size_t)(t & 1)*(B_*H_);
  ushort*       h0n = h0b + (size_t)((t+1) & 1)*(B_*H_);
  const ushort* h1c = h1b + (size_t)(t & 1)*(B_*H_);
  ushort*       h1n = h1b + (size_t)((t+1) & 1)*(B_*H_);
  lstm_iter(t, maxL, bh, us, wl0h, wl1h, hsf, xproj, bias1, map, Lp,
            h0c, h0n, h1c, h1n, c0, c1, hlast);
}

__global__ __launch_bounds__(128) void k_fc(
    const float* __restrict__ hlast, const float* __restrict__ fcw,
    const float* __restrict__ fcb, float* __restrict__ out)
{
  fc_epilogue(threadIdx.x, hlast, fcw, fcb, out);
}

// ---------------- host ----------------
extern "C" void kernel_launch(void* const* d_in, const int* in_sizes, int n_in,
                              void* d_out, int out_size, void* d_ws, size_t ws_size,
                              hipStream_t stream)
{
  const float* text  = (const float*)d_in[0];
  const float* ques  = (const float*)d_in[1];
  const float* code  = (const float*)d_in[2];
  const int*   ns    = (const int*)  d_in[3];
  const int*   que   = (const int*)  d_in[4];
  const float* w_ih0 = (const float*)d_in[5];
  const float* w_hh0 = (const float*)d_in[6];
  const float* b_ih0 = (const float*)d_in[7];
  const float* b_hh0 = (const float*)d_in[8];
  const float* w_ih1 = (const float*)d_in[9];
  const float* w_hh1 = (const float*)d_in[10];
  const float* b_ih1 = (const float*)d_in[11];
  const float* b_hh1 = (const float*)d_in[12];
  const float* fcw   = (const float*)d_in[13];
  const float* fcb   = (const float*)d_in[14];
  float* out = (float*)d_out;

  char* ws = (char*)d_ws;
  int*    Lp     = (int*)   (ws + OFF_L);
  int*    maxLp  = (int*)   (ws + OFF_MAXL);
  int*    map    = (int*)   (ws + OFF_MAP);
  float*  bias0  = (float*) (ws + OFF_BIAS0);
  float*  bias1  = (float*) (ws + OFF_BIAS1);
  float*  c0     = (float*) (ws + OFF_C0);
  float*  c1     = (float*) (ws + OFF_C1);
  float*  hlast  = (float*) (ws + OFF_HLAST);
  ushort* h0b    = (ushort*)(ws + OFF_H0B);
  ushort* h1b    = (ushort*)(ws + OFF_H1B);
  float*  wT_ih0 = (float*) (ws + OFF_WTIH0);
  float*  xproj  = (float*) (ws + OFF_XPROJ);
  int*    bar    = (int*)   (ws + OFF_BAR);
  (void)in_sizes; (void)n_in; (void)out_size; (void)ws_size; (void)WS_NEED;

  hipLaunchKernelGGL(k_prep, dim3(1), dim3(256), 0, stream,
                     ns, que, b_ih0, b_hh0, b_ih1, b_hh1,
                     Lp, maxLp, map, bias0, bias1, c0, c1, hlast, h0b, h1b, bar);

  hipLaunchKernelGGL(k_transpose, dim3(64, 24), dim3(32, 8), 0, stream,
                     w_ih0, wT_ih0);

  hipLaunchKernelGGL(k_proj, dim3(81, 16), dim3(128), 0, stream,
                     text, ques, code, wT_ih0, bias0, xproj);

  const float* a_whh0 = w_hh0; const float* a_wih1 = w_ih1; const float* a_whh1 = w_hh1;
  const float* a_xp = xproj;   const float* a_b1 = bias1;
  const int* a_Lp = Lp; const int* a_maxLp = maxLp; const int* a_map = map;
  ushort* a_h0b = h0b; ushort* a_h1b = h1b; float* a_c0 = c0; float* a_c1 = c1;
  float* a_hl = hlast; const float* a_fcw = fcw; const float* a_fcb = fcb;
  float* a_out = out; int* a_bar = bar;
  void* args[] = { &a_whh0, &a_wih1, &a_whh1, &a_xp, &a_b1, &a_Lp, &a_maxLp, &a_map,
                   &a_h0b, &a_h1b, &a_c0, &a_c1, &a_hl, &a_fcw, &a_fcb, &a_out, &a_bar };

  hipError_t err = hipLaunchCooperativeKernel((const void*)k_lstm_coop,
                                              dim3(512), dim3(256), args, 0, stream);
  if (err != hipSuccess) {
    (void)hipGetLastError();  // clear error state
    for (int t = 0; t < S_ + 1; ++t) {
      hipLaunchKernelGGL(k_step, dim3(512), dim3(256), 0, stream, t,
                         w_hh0, w_ih1, w_hh1, xproj, bias1, Lp, maxLp, map,
                         h0b, h1b, c0, c1, hlast);
    }
    hipLaunchKernelGGL(k_fc, dim3(1), dim3(128), 0, stream, hlast, fcw, fcb, out);
  }
}

// Round 8
// 3719.229 us; speedup vs baseline: 4.1817x; 1.4128x over previous
//
#include <hip/hip_runtime.h>
#include <hip/hip_cooperative_groups.h>

namespace cg = cooperative_groups;

#define B_    64
#define Q_    16
#define MAXK_ 32
#define C_    64
#define D_    768
#define H_    512
#define G4_   2048   // 4*H
#define S_    529    // Q*(MAXK+1)+1
#define NR_   81     // 16 questions + 64 code + 1 text

typedef float f32x4_t __attribute__((ext_vector_type(4)));
typedef unsigned int u32x2_t __attribute__((ext_vector_type(2)));
typedef unsigned int u32x4_t __attribute__((ext_vector_type(4)));

// LDS geometry (bytes)
#define WL0_RB 1040   // 16 rows x (512 halves + 8 pad) : W_hh0 slice
#define WL1_RB 2064   // 16 rows x (1024 halves + 8 pad): [W_ih1|W_hh1] slice
#define HS_RB  1024   // 16 rows x 512 halves (one k-chunk)

// ---------------- workspace layout (bytes) ----------------
static constexpr size_t OFF_L     = 0;                      // 64 int
static constexpr size_t OFF_MAXL  = 256;
static constexpr size_t OFF_MAP   = 512;                    // 64*529*4
static constexpr size_t OFF_BIAS0 = OFF_MAP   + 135424;     // 2048 f
static constexpr size_t OFF_BIAS1 = OFF_BIAS0 + 8192;       // 2048 f
static constexpr size_t OFF_C0    = OFF_BIAS1 + 8192;       // 64*512 f
static constexpr size_t OFF_C1    = OFF_C0    + 131072;
static constexpr size_t OFF_HLAST = OFF_C1    + 131072;     // 64*512 f (fp32, real-batch idx)
static constexpr size_t OFF_H0B   = OFF_HLAST + 131072;     // 2 x 64*512 half (sorted idx)
static constexpr size_t OFF_H1B   = OFF_H0B   + 262144;
static constexpr size_t OFF_WTIH0 = OFF_H1B   + 262144;     // 768x2048 f
static constexpr size_t OFF_XPROJ = OFF_WTIH0 + 6291456ULL; // 64*81*2048 f
static constexpr size_t OFF_BAR   = OFF_XPROJ + 42467328ULL; // 4 groups x 256 int
static constexpr size_t OFF_ORD   = OFF_BAR   + 4096;       // 64 int (sorted batch ids)
static constexpr size_t OFF_GMAX  = OFF_ORD   + 256;        // 4 int (per-group max L)
static constexpr size_t WS_NEED   = OFF_GMAX  + 256;

// group g owns sorted ranks [gbase, gbase+16): pair longest(g0) with shortest(g2)
__device__ __forceinline__ int group_base(int g) {
  return (g == 0) ? 0 : (g == 1) ? 16 : (g == 2) ? 48 : 32;
}

// ---------------- coherent (L2-bypass) access helpers ----------------
__device__ __forceinline__ void store_us_cc(ushort* p, unsigned int v) {
  asm volatile("global_store_short %0, %1, off sc0 sc1" :: "v"(p), "v"(v) : "memory");
}
__device__ __forceinline__ unsigned int load_us_cc(const ushort* p) {
  unsigned int v;
  asm volatile("global_load_ushort %0, %1, off sc0 sc1\n\ts_waitcnt vmcnt(0)"
               : "=v"(v) : "v"(p) : "memory");
  return v;
}
__device__ __forceinline__ void store_f_cc(float* p, float v) {
  asm volatile("global_store_dword %0, %1, off sc0 sc1" :: "v"(p), "v"(v) : "memory");
}

__device__ __forceinline__ void dot2(float& acc, unsigned int a, unsigned int b) {
  asm("v_dot2_f32_f16 %0, %1, %2, %0" : "+v"(acc) : "v"(a), "v"(b));
}
__device__ __forceinline__ unsigned int pkrtz(float a, float b) {
  auto r = __builtin_amdgcn_cvt_pkrtz(a, b);   // __fp16 ext_vector_type(2)
  unsigned int u;
  __builtin_memcpy(&u, &r, 4);
  return u;
}
__device__ __forceinline__ unsigned int f2h(float a) {
  return pkrtz(a, 0.f) & 0xffffu;              // low half = RTZ f32->f16 of a
}

// ---------------- prep ----------------
__global__ __launch_bounds__(256) void k_prep(
    const int* __restrict__ ns, const int* __restrict__ que,
    const float* __restrict__ b_ih0, const float* __restrict__ b_hh0,
    const float* __restrict__ b_ih1, const float* __restrict__ b_hh1,
    int* __restrict__ Lp, int* __restrict__ maxLp, int* __restrict__ map,
    float* __restrict__ bias0, float* __restrict__ bias1,
    float* __restrict__ c0, float* __restrict__ c1, float* __restrict__ hlast,
    ushort* __restrict__ h0b, ushort* __restrict__ h1b, int* __restrict__ bar,
    int* __restrict__ ord, int* __restrict__ gmax)
{
  const int tid = threadIdx.x;
  for (int i = tid; i < B_*S_; i += 256) map[i] = -1;
  for (int i = tid; i < G4_; i += 256) {
    bias0[i] = b_ih0[i] + b_hh0[i];
    bias1[i] = b_ih1[i] + b_hh1[i];
  }
  int* h0i = (int*)h0b;
  int* h1i = (int*)h1b;
  for (int i = tid; i < B_*H_; i += 256) {
    c0[i]=0.f; c1[i]=0.f; hlast[i]=0.f;
    h0i[i]=0; h1i[i]=0;
  }
  for (int i = tid; i < 1024; i += 256) bar[i] = 0;
  if (tid == 0) *maxLp = 0;
  __syncthreads();
  if (tid < B_) {
    const int b = tid;
    const int qn = que[b];
    int pos = 0;
    int* m = map + b*S_;
    for (int q = 0; q < qn; ++q) {
      m[pos++] = q;
      const int n = ns[b*Q_ + q];
      for (int k = 0; k < n; ++k) {
        int j = q + k; if (j > C_-1) j = C_-1;
        m[pos++] = 16 + j;
      }
    }
    m[pos] = 80;
    Lp[b] = pos;
    atomicMax(maxLp, pos);
  }
  __syncthreads();
  // rank-sort batches by L descending (tie-break by index) -> ord[rank] = batch
  if (tid < B_) {
    const int myL = Lp[tid];
    int rank = 0;
    for (int j = 0; j < B_; ++j) {
      const int lj = Lp[j];
      rank += (lj > myL) || (lj == myL && j < tid);
    }
    ord[rank] = tid;
  }
  __syncthreads();
  if (tid < 4) {
    const int gb = (tid == 0) ? 0 : (tid == 1) ? 16 : (tid == 2) ? 48 : 32;
    gmax[tid] = Lp[ord[gb]];   // sorted desc -> first rank in slice is the max
  }
}

// ---------------- transpose W_ih0 only: [2048][768] -> [768][2048] ----------------
__global__ __launch_bounds__(256) void k_transpose(
    const float* __restrict__ w, float* __restrict__ wT)
{
  __shared__ float tile[32][33];
  const int n0 = blockIdx.x * 32;
  const int k0 = blockIdx.y * 32;
  const int tx = threadIdx.x, ty = threadIdx.y;
  for (int i = ty; i < 32; i += 8)
    tile[i][tx] = w[(size_t)(n0+i)*D_ + k0 + tx];
  __syncthreads();
  for (int i = ty; i < 32; i += 8)
    wT[(size_t)(k0 + i)*G4_ + n0 + tx] = tile[tx][i];
}

// ---------------- xproj: project 81 distinct source rows per batch (fp32) ----------------
__global__ __launch_bounds__(128, 2) void k_proj(
    const float* __restrict__ text, const float* __restrict__ ques,
    const float* __restrict__ code, const float* __restrict__ wT_ih0,
    const float* __restrict__ bias0, float* __restrict__ xproj)
{
  __shared__ float hsLds[32][64];
  const int mb = blockIdx.x, nb = blockIdx.y;
  const int n0 = nb * 128;
  const int tid = threadIdx.x;
  const int tb = tid >> 4, tn = tid & 15;
  const int b0 = tb * 8;
  const int bb = tid >> 1, hh = tid & 1;

  const int mrow = mb*64 + bb;
  const int sb = mrow / NR_, sr = mrow % NR_;
  const float* srcrow = (sr < 16) ? (ques + ((size_t)sb*Q_ + sr)*D_)
                      : (sr < 80) ? (code + ((size_t)sb*C_ + (sr-16))*D_)
                                  : (text + (size_t)sb*D_);

  float a[8][8];
  #pragma unroll
  for (int i=0;i<8;i++)
    #pragma unroll
    for (int j=0;j<8;j++) a[i][j]=0.f;

  for (int k0 = 0; k0 < D_; k0 += 32) {
    __syncthreads();
    {
      const float* p = srcrow + k0 + hh*16;
      float4 v0 = *(const float4*)(p+0);
      float4 v1 = *(const float4*)(p+4);
      float4 v2 = *(const float4*)(p+8);
      float4 v3 = *(const float4*)(p+12);
      const int kk = hh*16;
      hsLds[kk+ 0][bb]=v0.x; hsLds[kk+ 1][bb]=v0.y; hsLds[kk+ 2][bb]=v0.z; hsLds[kk+ 3][bb]=v0.w;
      hsLds[kk+ 4][bb]=v1.x; hsLds[kk+ 5][bb]=v1.y; hsLds[kk+ 6][bb]=v1.z; hsLds[kk+ 7][bb]=v1.w;
      hsLds[kk+ 8][bb]=v2.x; hsLds[kk+ 9][bb]=v2.y; hsLds[kk+10][bb]=v2.z; hsLds[kk+11][bb]=v2.w;
      hsLds[kk+12][bb]=v3.x; hsLds[kk+13][bb]=v3.y; hsLds[kk+14][bb]=v3.z; hsLds[kk+15][bb]=v3.w;
    }
    __syncthreads();
    const float* wb = wT_ih0 + (size_t)k0*G4_ + n0 + tn*8;
    #pragma unroll 4
    for (int k=0;k<32;k++){
      float4 w0 = *(const float4*)(wb + (size_t)k*G4_);
      float4 w1 = *(const float4*)(wb + (size_t)k*G4_ + 4);
      float4 hA = *(const float4*)(&hsLds[k][b0]);
      float4 hB = *(const float4*)(&hsLds[k][b0+4]);
      float hv[8]={hA.x,hA.y,hA.z,hA.w,hB.x,hB.y,hB.z,hB.w};
      float wv[8]={w0.x,w0.y,w0.z,w0.w,w1.x,w1.y,w1.z,w1.w};
      #pragma unroll
      for (int i=0;i<8;i++)
        #pragma unroll
        for (int j=0;j<8;j++)
          a[i][j] = fmaf(hv[i], wv[j], a[i][j]);
    }
  }
  float bz[8];
  #pragma unroll
  for (int j=0;j<8;j++) bz[j] = bias0[n0 + tn*8 + j];
  #pragma unroll
  for (int i=0;i<8;i++){
    const int m = mb*64 + b0 + i;
    float* pd = xproj + (size_t)m*G4_ + n0 + tn*8;
    *(float4*)(pd+0) = make_float4(a[i][0]+bz[0], a[i][1]+bz[1], a[i][2]+bz[2], a[i][3]+bz[3]);
    *(float4*)(pd+4) = make_float4(a[i][4]+bz[4], a[i][5]+bz[5], a[i][6]+bz[6], a[i][7]+bz[7]);
  }
}

// ---------------- persistent LSTM pieces ----------------
// 512 blocks: g = blk>>7 (sync domain / batch group), us = blk & 127 (4 units).
// Group g owns sorted ranks [group_base(g), +16); h buffers indexed by sorted rank.
__device__ __forceinline__ void load_weights(int tid, int us,
    const float* __restrict__ w_hh0, const float* __restrict__ w_ih1,
    const float* __restrict__ w_hh1, ushort* __restrict__ wl0h, ushort* __restrict__ wl1h)
{
  char* w0b = (char*)wl0h;
  char* w1b = (char*)wl1h;
  #pragma unroll
  for (int p = 0; p < 8; ++p) {
    const int f4 = tid + p*256;           // 0..2047 = 16 rows x 128 float4
    const int r = f4 >> 7, c4 = f4 & 127;
    const int n = (r >> 2)*H_ + us*4 + (r & 3);
    float4 v = *(const float4*)(w_hh0 + (size_t)n*H_ + c4*4);
    u32x2_t o; o.x = pkrtz(v.x, v.y); o.y = pkrtz(v.z, v.w);
    *(u32x2_t*)(w0b + r*WL0_RB + c4*8) = o;
  }
  #pragma unroll
  for (int p = 0; p < 16; ++p) {
    const int f4 = tid + p*256;           // 0..4095 = 16 rows x 256 float4
    const int r = f4 >> 8, c4 = f4 & 255;
    const int n = (r >> 2)*H_ + us*4 + (r & 3);
    float4 v = (c4 < 128) ? *(const float4*)(w_ih1 + (size_t)n*H_ + c4*4)
                          : *(const float4*)(w_hh1 + (size_t)n*H_ + (c4-128)*4);
    u32x2_t o; o.x = pkrtz(v.x, v.y); o.y = pkrtz(v.z, v.w);
    *(u32x2_t*)(w1b + r*WL1_RB + c4*8) = o;
  }
}

__device__ __forceinline__ float sigm(float x) { return 1.f/(1.f + __expf(-x)); }

// issue 4 coherent dwordx4 loads for one 16x512-half chunk (rows = sorted ranks)
__device__ __forceinline__ void stage_issue(const ushort* __restrict__ srcb,
    int gbase, int row, int cq, u32x4_t* vvh)
{
  const ushort* gp = srcb + (size_t)(gbase + row)*H_ + cq*32;
  #pragma unroll
  for (int q = 0; q < 4; ++q)
    asm volatile("global_load_dwordx4 %0, %1, off sc0 sc1"
                 : "=v"(vvh[q]) : "v"(gp + q*8) : "memory");
}
// drain loads, write swizzled LDS chunk [16 rows][512 halves]
__device__ __forceinline__ void stage_write(char* __restrict__ hsb,
    int row, int cq, const u32x4_t* vvh)
{
  asm volatile("s_waitcnt vmcnt(0)" ::: "memory");
  __builtin_amdgcn_sched_barrier(0);   // rule #18
  const int swz = (row & 7) << 4;
  char* hrow = hsb + row*HS_RB;
  #pragma unroll
  for (int q = 0; q < 4; ++q)
    *(u32x4_t*)(hrow + ((cq*64 + q*16) ^ swz)) = vvh[q];
}

__device__ __forceinline__ void lstm_iter(int t, int maxLg, int gbase, int us,
    const ushort* __restrict__ wl0h, const ushort* __restrict__ wl1h,
    float* __restrict__ hsf,
    const float* __restrict__ xproj, const float* __restrict__ bias1,
    const int* __restrict__ map, const int* __restrict__ Lp,
    const int* __restrict__ ord,
    const ushort* __restrict__ h0c, ushort* __restrict__ h0n,
    const ushort* __restrict__ h1c, ushort* __restrict__ h1n,
    float* __restrict__ c0, float* __restrict__ c1, float* __restrict__ hlast)
{
  const int tid  = threadIdx.x;
  const int slot = tid & 15, kg = tid >> 4;      // 16 slots x 16 k-groups
  const int bgrp = slot & 3, ngrp = slot >> 2;
  const int b4   = bgrp * 4;
  const int row  = tid & 15, cq = tid >> 4;      // staging map
  char* hsb = (char*)hsf;
  const char* w0base = (const char*)wl0h + ngrp*WL0_RB;
  const char* w1base = (const char*)wl1h + ngrp*WL1_RB;

  // ---- prefetch this step's xproj gate inputs (L0 gate threads) ----
  float xg0=0.f, xg1=0.f, xg2=0.f, xg3=0.f;
  int rpre = -1, rb0 = 0;
  if (tid < 64) {
    rb0 = ord[gbase + (tid & 15)];
    if (t <= maxLg) rpre = map[rb0*S_ + t];
    const int rr = rpre < 0 ? 0 : rpre;
    const float* xp = xproj + ((size_t)rb0*NR_ + rr)*G4_ + (us*4 + (tid>>4));
    xg0 = xp[0]; xg1 = xp[512]; xg2 = xp[1024]; xg3 = xp[1536];
  }

  float acc0[4][4], acc1[4][4];
  #pragma unroll
  for (int i=0;i<4;i++)
    #pragma unroll
    for (int j=0;j<4;j++){ acc0[i][j]=0.f; acc1[i][j]=0.f; }

  u32x4_t vvh[4];
  stage_issue(h0c, gbase, row, cq, vvh);         // chunk A = h0

  // ---- chunk A: h0 (512 halves) -> acc0 (L0) + acc1 (L1-x) ----
  stage_write(hsb, row, cq, vvh);
  __syncthreads();
  stage_issue(h1c, gbase, row, cq, vvh);         // prefetch chunk B = h1
  #pragma unroll
  for (int k4 = 0; k4 < 8; ++k4) {
    const int rot = (k4 + bgrp) & 7;
    const int kb = kg*64 + rot*8;
    u32x2_t hv[4];
    #pragma unroll
    for (int i = 0; i < 4; ++i)
      hv[i] = *(const u32x2_t*)(hsb + (b4+i)*HS_RB + (kb ^ (((b4+i)&7)<<4)));
    #pragma unroll
    for (int j = 0; j < 4; ++j) {
      const u32x2_t w0 = *(const u32x2_t*)(w0base + j*4*WL0_RB + kb);
      const u32x2_t w1 = *(const u32x2_t*)(w1base + j*4*WL1_RB + kb);
      #pragma unroll
      for (int i = 0; i < 4; ++i) {
        dot2(acc0[i][j], hv[i].x, w0.x);
        dot2(acc0[i][j], hv[i].y, w0.y);
        dot2(acc1[i][j], hv[i].x, w1.x);
        dot2(acc1[i][j], hv[i].y, w1.y);
      }
    }
  }
  __syncthreads();                               // done reading chunk A

  // ---- chunk B: h1 (512 halves) -> acc1 (L1-h) ----
  stage_write(hsb, row, cq, vvh);
  __syncthreads();
  #pragma unroll
  for (int k4 = 0; k4 < 8; ++k4) {
    const int rot = (k4 + bgrp) & 7;
    const int kb = kg*64 + rot*8;
    u32x2_t hv[4];
    #pragma unroll
    for (int i = 0; i < 4; ++i)
      hv[i] = *(const u32x2_t*)(hsb + (b4+i)*HS_RB + (kb ^ (((b4+i)&7)<<4)));
    #pragma unroll
    for (int j = 0; j < 4; ++j) {
      const u32x2_t w1 = *(const u32x2_t*)(w1base + 1024 + j*4*WL1_RB + kb);
      #pragma unroll
      for (int i = 0; i < 4; ++i) {
        dot2(acc1[i][j], hv[i].x, w1.x);
        dot2(acc1[i][j], hv[i].y, w1.y);
      }
    }
  }
  __syncthreads();                               // before reduce reuses hs

  // ---- reduce 16 kg -> 4 wave-partials (shfl) -> LDS ----
  #pragma unroll
  for (int i = 0; i < 4; ++i)
    #pragma unroll
    for (int j = 0; j < 4; ++j) {
      float v0 = acc0[i][j], v1 = acc1[i][j];
      v0 += __shfl_xor(v0, 16); v0 += __shfl_xor(v0, 32);
      v1 += __shfl_xor(v1, 16); v1 += __shfl_xor(v1, 32);
      acc0[i][j] = v0; acc1[i][j] = v1;
    }
  if (((tid >> 4) & 3) == 0) {
    const int base = (tid >> 6)*256 + slot*16;
    #pragma unroll
    for (int i = 0; i < 4; ++i)
      #pragma unroll
      for (int j = 0; j < 4; ++j) {
        hsf[base + i*4 + j]        = acc0[i][j];
        hsf[1024 + base + i*4 + j] = acc1[i][j];
      }
  }
  __syncthreads();

  // ---- gates: L0 threads 0..63, L1 threads 64..127 ----
  if (tid < 64) {
    const int bl = tid & 15, ul = tid >> 4;
    const int pb = gbase + bl, u = us*4 + ul;
    const int idx = pb*H_ + u;
    if (rpre >= 0) {
      const int sbase = (ul*4 + (bl>>2))*16 + (bl&3)*4;
      float g0=xg0, g1=xg1, g2=xg2, g3=xg3;
      #pragma unroll
      for (int wv = 0; wv < 4; ++wv) {
        const int base = wv*256 + sbase;
        g0 += hsf[base+0]; g1 += hsf[base+1]; g2 += hsf[base+2]; g3 += hsf[base+3];
      }
      const float cc = sigm(g1)*c0[idx] + sigm(g0)*tanhf(g2);
      c0[idx] = cc;
      store_us_cc(h0n + idx, f2h(sigm(g3)*tanhf(cc)));
    } else {
      store_us_cc(h0n + idx, load_us_cc(h0c + idx));
    }
  } else if (tid < 128) {
    const int w2 = tid - 64;
    const int bl = w2 & 15, ul = w2 >> 4;
    const int pb = gbase + bl, u = us*4 + ul;
    const int rb = ord[pb];
    const int idx = pb*H_ + u;
    const int s = t - 1;
    const int r = (s >= 0 && s <= maxLg) ? map[rb*S_ + s] : -1;
    if (r >= 0) {
      const int sbase = (ul*4 + (bl>>2))*16 + (bl&3)*4;
      float g0=0.f, g1=0.f, g2=0.f, g3=0.f;
      #pragma unroll
      for (int wv = 0; wv < 4; ++wv) {
        const int base = 1024 + wv*256 + sbase;
        g0 += hsf[base+0]; g1 += hsf[base+1]; g2 += hsf[base+2]; g3 += hsf[base+3];
      }
      g0 += bias1[u]; g1 += bias1[512+u]; g2 += bias1[1024+u]; g3 += bias1[1536+u];
      const float cc = sigm(g1)*c1[idx] + sigm(g0)*tanhf(g2);
      c1[idx] = cc;
      const float hn = sigm(g3)*tanhf(cc);
      store_us_cc(h1n + idx, f2h(hn));
      if (s == Lp[rb]) store_f_cc(hlast + rb*H_ + u, hn);
    } else {
      store_us_cc(h1n + idx, load_us_cc(h1c + idx));
    }
  }
}

// ---------------- per-group barrier: 128 blocks = 8 leaves x 16 ----------------
__device__ __forceinline__ void grid_barrier_g(int* __restrict__ barg, int us, int gen)
{
  asm volatile("s_waitcnt vmcnt(0)" ::: "memory");  // drain this thread's sc stores
  __syncthreads();                                   // all threads' stores drained
  if (threadIdx.x == 0) {
    int* lp = barg + (us >> 4) * 16;
    int* rp = barg + 128;
    int* gp = barg + 144;
    bool last = false;
    if (atomicAdd(lp, 1) == gen*16 - 1) {
      if (atomicAdd(rp, 1) == gen*8 - 1) {
        __hip_atomic_store(gp, gen, __ATOMIC_RELAXED, __HIP_MEMORY_SCOPE_AGENT);
        last = true;
      }
    }
    if (!last) {
      while (__hip_atomic_load(gp, __ATOMIC_RELAXED, __HIP_MEMORY_SCOPE_AGENT) < gen)
        __builtin_amdgcn_s_sleep(1);
    }
  }
  __syncthreads();
}

// ---------------- cooperative persistent kernel ----------------
__global__ __launch_bounds__(256, 2) void k_lstm_coop(
    const float* __restrict__ w_hh0, const float* __restrict__ w_ih1,
    const float* __restrict__ w_hh1, const float* __restrict__ xproj,
    const float* __restrict__ bias1, const int* __restrict__ Lp,
    const int* __restrict__ gmax, const int* __restrict__ map,
    const int* __restrict__ ord,
    ushort* __restrict__ h0b, ushort* __restrict__ h1b,
    float* __restrict__ c0, float* __restrict__ c1, float* __restrict__ hlast,
    const float* __restrict__ fcw, const float* __restrict__ fcb,
    float* __restrict__ out, int* __restrict__ bar)
{
  __shared__ __align__(16) ushort wl0h[16*520];
  __shared__ __align__(16) ushort wl1h[16*1032];
  __shared__ __align__(16) float  hsf[4096];
  const int blk = blockIdx.x;
  const int g = blk >> 7, us = blk & 127;
  const int gbase = group_base(g);
  load_weights(threadIdx.x, us, w_hh0, w_ih1, w_hh1, wl0h, wl1h);
  __syncthreads();
  const int maxLg = gmax[g];
  int* barg = bar + g*256;
  for (int t = 0; t <= maxLg + 1; ++t) {
    const ushort* h0c = h0b + (size_t)(t & 1)*(B_*H_);
    ushort*       h0n = h0b + (size_t)((t+1) & 1)*(B_*H_);
    const ushort* h1c = h1b + (size_t)(t & 1)*(B_*H_);
    ushort*       h1n = h1b + (size_t)((t+1) & 1)*(B_*H_);
    lstm_iter(t, maxLg, gbase, us, wl0h, wl1h, hsf, xproj, bias1, map, Lp, ord,
              h0c, h0n, h1c, h1n, c0, c1, hlast);
    grid_barrier_g(barg, us, t + 1);
  }
  // ---- per-group FC epilogue (us==0 block; 32 threads, 2 per batch) ----
  if (us == 0 && threadIdx.x < 32) {
    const int tid = threadIdx.x;
    const int pb = gbase + (tid >> 1), half = tid & 1;
    const int rb = ord[pb];
    const float* hv = hlast + (size_t)rb*H_ + half*256;
    const float* fw = fcw + half*256;
    float s = 0.f;
    #pragma unroll 8
    for (int u = 0; u < 256; ++u) s = fmaf(hv[u], fw[u], s);
    s += __shfl_xor(s, 1);
    if (half == 0) store_f_cc(out + rb, s + fcb[0]);  // write-through: no cross-XCD line sharing
  }
}

// ---------------- non-cooperative fallback: one iteration per launch ----------------
__global__ __launch_bounds__(256, 2) void k_step(int t,
    const float* __restrict__ w_hh0, const float* __restrict__ w_ih1,
    const float* __restrict__ w_hh1, const float* __restrict__ xproj,
    const float* __restrict__ bias1, const int* __restrict__ Lp,
    const int* __restrict__ gmax, const int* __restrict__ map,
    const int* __restrict__ ord,
    ushort* __restrict__ h0b, ushort* __restrict__ h1b,
    float* __restrict__ c0, float* __restrict__ c1, float* __restrict__ hlast)
{
  __shared__ __align__(16) ushort wl0h[16*520];
  __shared__ __align__(16) ushort wl1h[16*1032];
  __shared__ __align__(16) float  hsf[4096];
  const int blk = blockIdx.x;
  const int g = blk >> 7, us = blk & 127;
  const int gbase = group_base(g);
  const int maxLg = gmax[g];
  if (t > maxLg + 1) return;
  load_weights(threadIdx.x, us, w_hh0, w_ih1, w_hh1, wl0h, wl1h);
  __syncthreads();
  const ushort* h0c = h0b + (size_t)(t & 1)*(B_*H_);
  ushort*       h0n = h0b + (size_t)((t+1) & 1)*(B_*H_);
  const ushort* h1c = h1b + (size_t)(t & 1)*(B_*H_);
  ushort*       h1n = h1b + (size_t)((t+1) & 1)*(B_*H_);
  lstm_iter(t, maxLg, gbase, us, wl0h, wl1h, hsf, xproj, bias1, map, Lp, ord,
            h0c, h0n, h1c, h1n, c0, c1, hlast);
}

__global__ __launch_bounds__(128) void k_fc(
    const float* __restrict__ hlast, const float* __restrict__ fcw,
    const float* __restrict__ fcb, float* __restrict__ out)
{
  const int tid = threadIdx.x;
  if (tid < 128) {
    const int b = tid >> 1, half = tid & 1;
    const float* hv = hlast + (size_t)b*H_ + half*256;
    const float* fw = fcw + half*256;
    float s = 0.f;
    #pragma unroll 8
    for (int u = 0; u < 256; ++u) s = fmaf(hv[u], fw[u], s);
    s += __shfl_xor(s, 1);
    if (half == 0) out[b] = s + fcb[0];
  }
}

// ---------------- host ----------------
extern "C" void kernel_launch(void* const* d_in, const int* in_sizes, int n_in,
                              void* d_out, int out_size, void* d_ws, size_t ws_size,
                              hipStream_t stream)
{
  const float* text  = (const float*)d_in[0];
  const float* ques  = (const float*)d_in[1];
  const float* code  = (const float*)d_in[2];
  const int*   ns    = (const int*)  d_in[3];
  const int*   que   = (const int*)  d_in[4];
  const float* w_ih0 = (const float*)d_in[5];
  const float* w_hh0 = (const float*)d_in[6];
  const float* b_ih0 = (const float*)d_in[7];
  const float* b_hh0 = (const float*)d_in[8];
  const float* w_ih1 = (const float*)d_in[9];
  const float* w_hh1 = (const float*)d_in[10];
  const float* b_ih1 = (const float*)d_in[11];
  const float* b_hh1 = (const float*)d_in[12];
  const float* fcw   = (const float*)d_in[13];
  const float* fcb   = (const float*)d_in[14];
  float* out = (float*)d_out;

  char* ws = (char*)d_ws;
  int*    Lp     = (int*)   (ws + OFF_L);
  int*    maxLp  = (int*)   (ws + OFF_MAXL);
  int*    map    = (int*)   (ws + OFF_MAP);
  float*  bias0  = (float*) (ws + OFF_BIAS0);
  float*  bias1  = (float*) (ws + OFF_BIAS1);
  float*  c0     = (float*) (ws + OFF_C0);
  float*  c1     = (float*) (ws + OFF_C1);
  float*  hlast  = (float*) (ws + OFF_HLAST);
  ushort* h0b    = (ushort*)(ws + OFF_H0B);
  ushort* h1b    = (ushort*)(ws + OFF_H1B);
  float*  wT_ih0 = (float*) (ws + OFF_WTIH0);
  float*  xproj  = (float*) (ws + OFF_XPROJ);
  int*    bar    = (int*)   (ws + OFF_BAR);
  int*    ord    = (int*)   (ws + OFF_ORD);
  int*    gmax   = (int*)   (ws + OFF_GMAX);
  (void)in_sizes; (void)n_in; (void)out_size; (void)ws_size; (void)WS_NEED;

  hipLaunchKernelGGL(k_prep, dim3(1), dim3(256), 0, stream,
                     ns, que, b_ih0, b_hh0, b_ih1, b_hh1,
                     Lp, maxLp, map, bias0, bias1, c0, c1, hlast, h0b, h1b, bar,
                     ord, gmax);

  hipLaunchKernelGGL(k_transpose, dim3(64, 24), dim3(32, 8), 0, stream,
                     w_ih0, wT_ih0);

  hipLaunchKernelGGL(k_proj, dim3(81, 16), dim3(128), 0, stream,
                     text, ques, code, wT_ih0, bias0, xproj);

  const float* a_whh0 = w_hh0; const float* a_wih1 = w_ih1; const float* a_whh1 = w_hh1;
  const float* a_xp = xproj;   const float* a_b1 = bias1;
  const int* a_Lp = Lp; const int* a_gmax = gmax; const int* a_map = map;
  const int* a_ord = ord;
  ushort* a_h0b = h0b; ushort* a_h1b = h1b; float* a_c0 = c0; float* a_c1 = c1;
  float* a_hl = hlast; const float* a_fcw = fcw; const float* a_fcb = fcb;
  float* a_out = out; int* a_bar = bar;
  void* args[] = { &a_whh0, &a_wih1, &a_whh1, &a_xp, &a_b1, &a_Lp, &a_gmax, &a_map,
                   &a_ord, &a_h0b, &a_h1b, &a_c0, &a_c1, &a_hl, &a_fcw, &a_fcb,
                   &a_out, &a_bar };

  hipError_t err = hipLaunchCooperativeKernel((const void*)k_lstm_coop,
                                              dim3(512), dim3(256), args, 0, stream);
  if (err != hipSuccess) {
    (void)hipGetLastError();  // clear error state
    for (int t = 0; t < S_ + 1; ++t) {
      hipLaunchKernelGGL(k_step, dim3(512), dim3(256), 0, stream, t,
                         w_hh0, w_ih1, w_hh1, xproj, bias1, Lp, gmax, map, ord,
                         h0b, h1b, c0, c1, hlast);
    }
    hipLaunchKernelGGL(k_fc, dim3(1), dim3(128), 0, stream, hlast, fcw, fcb, out);
  }
}

// Round 9
// 3639.529 us; speedup vs baseline: 4.2732x; 1.0219x over previous
//
#include <hip/hip_runtime.h>
#include <hip/hip_cooperative_groups.h>

namespace cg = cooperative_groups;

#define B_    64
#define Q_    16
#define MAXK_ 32
#define C_    64
#define D_    768
#define H_    512
#define G4_   2048   // 4*H
#define S_    529    // Q*(MAXK+1)+1
#define NR_   81     // 16 questions + 64 code + 1 text

typedef float f32x4_t __attribute__((ext_vector_type(4)));
typedef unsigned int u32x2_t __attribute__((ext_vector_type(2)));
typedef unsigned int u32x4_t __attribute__((ext_vector_type(4)));

// LDS geometry (bytes)
#define WL0_RB 1040   // 16 rows x (512 halves + 8 pad) : W_hh0 slice
#define WL1_RB 2064   // 16 rows x (1024 halves + 8 pad): [W_ih1|W_hh1] slice
#define HS_RB  1024   // 16 rows x 512 halves (one k-chunk)

// ---------------- workspace layout (bytes) ----------------
static constexpr size_t OFF_L     = 0;                      // 64 int
static constexpr size_t OFF_MAXL  = 256;
static constexpr size_t OFF_MAP   = 512;                    // 64*529*4
static constexpr size_t OFF_BIAS0 = OFF_MAP   + 135424;     // 2048 f
static constexpr size_t OFF_BIAS1 = OFF_BIAS0 + 8192;       // 2048 f
static constexpr size_t OFF_C0    = OFF_BIAS1 + 8192;       // 64*512 f
static constexpr size_t OFF_C1    = OFF_C0    + 131072;
static constexpr size_t OFF_HLAST = OFF_C1    + 131072;     // 64*512 f (fp32, real-batch idx)
static constexpr size_t OFF_H0B   = OFF_HLAST + 131072;     // 2 x 64*512 half (sorted idx)
static constexpr size_t OFF_H1B   = OFF_H0B   + 262144;
static constexpr size_t OFF_WTIH0 = OFF_H1B   + 262144;     // 768x2048 f
static constexpr size_t OFF_XPROJ = OFF_WTIH0 + 6291456ULL; // 64*81*2048 f
static constexpr size_t OFF_BAR   = OFF_XPROJ + 42467328ULL; // 4 groups x 64 int (256B apart)
static constexpr size_t OFF_ORD   = OFF_BAR   + 4096;       // 64 int (sorted batch ids)
static constexpr size_t OFF_GMAX  = OFF_ORD   + 256;        // 4 int (per-group max L)
static constexpr size_t WS_NEED   = OFF_GMAX  + 256;

// group g owns sorted ranks [gbase, gbase+16): pair longest(g0) with shortest(g2)
__device__ __forceinline__ int group_base(int g) {
  return (g == 0) ? 0 : (g == 1) ? 16 : (g == 2) ? 48 : 32;
}

// ---------------- coherent (L2-bypass) access helpers ----------------
__device__ __forceinline__ void store_us_cc(ushort* p, unsigned int v) {
  asm volatile("global_store_short %0, %1, off sc0 sc1" :: "v"(p), "v"(v) : "memory");
}
__device__ __forceinline__ void store_f_cc(float* p, float v) {
  asm volatile("global_store_dword %0, %1, off sc0 sc1" :: "v"(p), "v"(v) : "memory");
}

__device__ __forceinline__ void dot2(float& acc, unsigned int a, unsigned int b) {
  asm("v_dot2_f32_f16 %0, %1, %2, %0" : "+v"(acc) : "v"(a), "v"(b));
}
__device__ __forceinline__ unsigned int pkrtz(float a, float b) {
  auto r = __builtin_amdgcn_cvt_pkrtz(a, b);   // __fp16 ext_vector_type(2)
  unsigned int u;
  __builtin_memcpy(&u, &r, 4);
  return u;
}
__device__ __forceinline__ unsigned int f2h(float a) {
  return pkrtz(a, 0.f) & 0xffffu;              // low half = RTZ f32->f16 of a
}

// ---------------- prep ----------------
__global__ __launch_bounds__(256) void k_prep(
    const int* __restrict__ ns, const int* __restrict__ que,
    const float* __restrict__ b_ih0, const float* __restrict__ b_hh0,
    const float* __restrict__ b_ih1, const float* __restrict__ b_hh1,
    int* __restrict__ Lp, int* __restrict__ maxLp, int* __restrict__ map,
    float* __restrict__ bias0, float* __restrict__ bias1,
    float* __restrict__ c0, float* __restrict__ c1, float* __restrict__ hlast,
    ushort* __restrict__ h0b, ushort* __restrict__ h1b, int* __restrict__ bar,
    int* __restrict__ ord, int* __restrict__ gmax)
{
  const int tid = threadIdx.x;
  for (int i = tid; i < B_*S_; i += 256) map[i] = -1;
  for (int i = tid; i < G4_; i += 256) {
    bias0[i] = b_ih0[i] + b_hh0[i];
    bias1[i] = b_ih1[i] + b_hh1[i];
  }
  int* h0i = (int*)h0b;
  int* h1i = (int*)h1b;
  for (int i = tid; i < B_*H_; i += 256) {
    c0[i]=0.f; c1[i]=0.f; hlast[i]=0.f;
    h0i[i]=0; h1i[i]=0;
  }
  for (int i = tid; i < 1024; i += 256) bar[i] = 0;
  if (tid == 0) *maxLp = 0;
  __syncthreads();
  if (tid < B_) {
    const int b = tid;
    const int qn = que[b];
    int pos = 0;
    int* m = map + b*S_;
    for (int q = 0; q < qn; ++q) {
      m[pos++] = q;
      const int n = ns[b*Q_ + q];
      for (int k = 0; k < n; ++k) {
        int j = q + k; if (j > C_-1) j = C_-1;
        m[pos++] = 16 + j;
      }
    }
    m[pos] = 80;
    Lp[b] = pos;
    atomicMax(maxLp, pos);
  }
  __syncthreads();
  // rank-sort batches by L descending (tie-break by index) -> ord[rank] = batch
  if (tid < B_) {
    const int myL = Lp[tid];
    int rank = 0;
    for (int j = 0; j < B_; ++j) {
      const int lj = Lp[j];
      rank += (lj > myL) || (lj == myL && j < tid);
    }
    ord[rank] = tid;
  }
  __syncthreads();
  if (tid < 4) {
    const int gb = (tid == 0) ? 0 : (tid == 1) ? 16 : (tid == 2) ? 48 : 32;
    gmax[tid] = Lp[ord[gb]];   // sorted desc -> first rank in slice is the max
  }
}

// ---------------- transpose W_ih0 only: [2048][768] -> [768][2048] ----------------
__global__ __launch_bounds__(256) void k_transpose(
    const float* __restrict__ w, float* __restrict__ wT)
{
  __shared__ float tile[32][33];
  const int n0 = blockIdx.x * 32;
  const int k0 = blockIdx.y * 32;
  const int tx = threadIdx.x, ty = threadIdx.y;
  for (int i = ty; i < 32; i += 8)
    tile[i][tx] = w[(size_t)(n0+i)*D_ + k0 + tx];
  __syncthreads();
  for (int i = ty; i < 32; i += 8)
    wT[(size_t)(k0 + i)*G4_ + n0 + tx] = tile[tx][i];
}

// ---------------- xproj: project 81 distinct source rows per batch (fp32) ----------------
__global__ __launch_bounds__(128, 2) void k_proj(
    const float* __restrict__ text, const float* __restrict__ ques,
    const float* __restrict__ code, const float* __restrict__ wT_ih0,
    const float* __restrict__ bias0, float* __restrict__ xproj)
{
  __shared__ float hsLds[32][64];
  const int mb = blockIdx.x, nb = blockIdx.y;
  const int n0 = nb * 128;
  const int tid = threadIdx.x;
  const int tb = tid >> 4, tn = tid & 15;
  const int b0 = tb * 8;
  const int bb = tid >> 1, hh = tid & 1;

  const int mrow = mb*64 + bb;
  const int sb = mrow / NR_, sr = mrow % NR_;
  const float* srcrow = (sr < 16) ? (ques + ((size_t)sb*Q_ + sr)*D_)
                      : (sr < 80) ? (code + ((size_t)sb*C_ + (sr-16))*D_)
                                  : (text + (size_t)sb*D_);

  float a[8][8];
  #pragma unroll
  for (int i=0;i<8;i++)
    #pragma unroll
    for (int j=0;j<8;j++) a[i][j]=0.f;

  for (int k0 = 0; k0 < D_; k0 += 32) {
    __syncthreads();
    {
      const float* p = srcrow + k0 + hh*16;
      float4 v0 = *(const float4*)(p+0);
      float4 v1 = *(const float4*)(p+4);
      float4 v2 = *(const float4*)(p+8);
      float4 v3 = *(const float4*)(p+12);
      const int kk = hh*16;
      hsLds[kk+ 0][bb]=v0.x; hsLds[kk+ 1][bb]=v0.y; hsLds[kk+ 2][bb]=v0.z; hsLds[kk+ 3][bb]=v0.w;
      hsLds[kk+ 4][bb]=v1.x; hsLds[kk+ 5][bb]=v1.y; hsLds[kk+ 6][bb]=v1.z; hsLds[kk+ 7][bb]=v1.w;
      hsLds[kk+ 8][bb]=v2.x; hsLds[kk+ 9][bb]=v2.y; hsLds[kk+10][bb]=v2.z; hsLds[kk+11][bb]=v2.w;
      hsLds[kk+12][bb]=v3.x; hsLds[kk+13][bb]=v3.y; hsLds[kk+14][bb]=v3.z; hsLds[kk+15][bb]=v3.w;
    }
    __syncthreads();
    const float* wb = wT_ih0 + (size_t)k0*G4_ + n0 + tn*8;
    #pragma unroll 4
    for (int k=0;k<32;k++){
      float4 w0 = *(const float4*)(wb + (size_t)k*G4_);
      float4 w1 = *(const float4*)(wb + (size_t)k*G4_ + 4);
      float4 hA = *(const float4*)(&hsLds[k][b0]);
      float4 hB = *(const float4*)(&hsLds[k][b0+4]);
      float hv[8]={hA.x,hA.y,hA.z,hA.w,hB.x,hB.y,hB.z,hB.w};
      float wv[8]={w0.x,w0.y,w0.z,w0.w,w1.x,w1.y,w1.z,w1.w};
      #pragma unroll
      for (int i=0;i<8;i++)
        #pragma unroll
        for (int j=0;j<8;j++)
          a[i][j] = fmaf(hv[i], wv[j], a[i][j]);
    }
  }
  float bz[8];
  #pragma unroll
  for (int j=0;j<8;j++) bz[j] = bias0[n0 + tn*8 + j];
  #pragma unroll
  for (int i=0;i<8;i++){
    const int m = mb*64 + b0 + i;
    float* pd = xproj + (size_t)m*G4_ + n0 + tn*8;
    *(float4*)(pd+0) = make_float4(a[i][0]+bz[0], a[i][1]+bz[1], a[i][2]+bz[2], a[i][3]+bz[3]);
    *(float4*)(pd+4) = make_float4(a[i][4]+bz[4], a[i][5]+bz[5], a[i][6]+bz[6], a[i][7]+bz[7]);
  }
}

// ---------------- persistent LSTM pieces ----------------
// 512 blocks: g = blk>>7 (sync domain / batch group), us = blk & 127 (4 units).
// Group g owns sorted ranks [group_base(g), +16); h buffers indexed by sorted rank.
__device__ __forceinline__ void load_weights(int tid, int us,
    const float* __restrict__ w_hh0, const float* __restrict__ w_ih1,
    const float* __restrict__ w_hh1, ushort* __restrict__ wl0h, ushort* __restrict__ wl1h)
{
  char* w0b = (char*)wl0h;
  char* w1b = (char*)wl1h;
  #pragma unroll
  for (int p = 0; p < 8; ++p) {
    const int f4 = tid + p*256;           // 0..2047 = 16 rows x 128 float4
    const int r = f4 >> 7, c4 = f4 & 127;
    const int n = (r >> 2)*H_ + us*4 + (r & 3);
    float4 v = *(const float4*)(w_hh0 + (size_t)n*H_ + c4*4);
    u32x2_t o; o.x = pkrtz(v.x, v.y); o.y = pkrtz(v.z, v.w);
    *(u32x2_t*)(w0b + r*WL0_RB + c4*8) = o;
  }
  #pragma unroll
  for (int p = 0; p < 16; ++p) {
    const int f4 = tid + p*256;           // 0..4095 = 16 rows x 256 float4
    const int r = f4 >> 8, c4 = f4 & 255;
    const int n = (r >> 2)*H_ + us*4 + (r & 3);
    float4 v = (c4 < 128) ? *(const float4*)(w_ih1 + (size_t)n*H_ + c4*4)
                          : *(const float4*)(w_hh1 + (size_t)n*H_ + (c4-128)*4);
    u32x2_t o; o.x = pkrtz(v.x, v.y); o.y = pkrtz(v.z, v.w);
    *(u32x2_t*)(w1b + r*WL1_RB + c4*8) = o;
  }
}

__device__ __forceinline__ float sigm(float x) { return 1.f/(1.f + __expf(-x)); }

// issue 4 coherent dwordx4 loads for one 16x512-half chunk (rows = sorted ranks)
__device__ __forceinline__ void stage_issue(const ushort* __restrict__ srcb,
    int gbase, int row, int cq, u32x4_t* vvh)
{
  const ushort* gp = srcb + (size_t)(gbase + row)*H_ + cq*32;
  #pragma unroll
  for (int q = 0; q < 4; ++q)
    asm volatile("global_load_dwordx4 %0, %1, off sc0 sc1"
                 : "=v"(vvh[q]) : "v"(gp + q*8) : "memory");
}
// drain loads, write swizzled LDS chunk [16 rows][512 halves]
__device__ __forceinline__ void stage_write(char* __restrict__ hsb,
    int row, int cq, const u32x4_t* vvh)
{
  asm volatile("s_waitcnt vmcnt(0)" ::: "memory");
  __builtin_amdgcn_sched_barrier(0);   // rule #18
  const int swz = (row & 7) << 4;
  char* hrow = hsb + row*HS_RB;
  #pragma unroll
  for (int q = 0; q < 4; ++q)
    *(u32x4_t*)(hrow + ((cq*64 + q*16) ^ swz)) = vvh[q];
}

// gate-context prefetch for L0 threads (tid<64): map value + 4 xproj gathers
__device__ __forceinline__ void xg_prefetch(int t, int maxLg,
    const int* __restrict__ mrow, const float* __restrict__ xbase,
    float& xg0, float& xg1, float& xg2, float& xg3, int& rpre)
{
  rpre = (t <= maxLg) ? mrow[t] : -1;
  const float* xp = xbase + (size_t)(rpre < 0 ? 0 : rpre)*G4_;
  xg0 = xp[0]; xg1 = xp[512]; xg2 = xp[1024]; xg3 = xp[1536];
}

__device__ __forceinline__ void lstm_iter(int t, int maxLg, int gbase, int us,
    const ushort* __restrict__ wl0h, const ushort* __restrict__ wl1h,
    float* __restrict__ hsf,
    const ushort* __restrict__ h0c, ushort* __restrict__ h0n,
    const ushort* __restrict__ h1c, ushort* __restrict__ h1n,
    float* __restrict__ c0, float* __restrict__ c1, float* __restrict__ hlast,
    const int* __restrict__ mrow, const float* __restrict__ xbase,
    float& xg0, float& xg1, float& xg2, float& xg3, int& rpre0, int& rpre1,
    float b1v0, float b1v1, float b1v2, float b1v3, int Lrb, int rb)
{
  const int tid  = threadIdx.x;
  const int slot = tid & 15, kg = tid >> 4;      // 16 slots x 16 k-groups
  const int bgrp = slot & 3, ngrp = slot >> 2;
  const int b4   = bgrp * 4;
  const int row  = tid & 15, cq = tid >> 4;      // staging map
  char* hsb = (char*)hsf;
  const char* w0base = (const char*)wl0h + ngrp*WL0_RB;
  const char* w1base = (const char*)wl1h + ngrp*WL1_RB;

  float acc0[4][4], acc1[4][4];
  #pragma unroll
  for (int i=0;i<4;i++)
    #pragma unroll
    for (int j=0;j<4;j++){ acc0[i][j]=0.f; acc1[i][j]=0.f; }

  // ---- h0 load is THE critical path: issue first thing after the barrier ----
  u32x4_t vvh[4];
  stage_issue(h0c, gbase, row, cq, vvh);         // chunk A = h0

  // ---- chunk A: h0 (512 halves) -> acc0 (L0) + acc1 (L1-x) ----
  stage_write(hsb, row, cq, vvh);
  __syncthreads();
  stage_issue(h1c, gbase, row, cq, vvh);         // prefetch chunk B = h1 (hidden under GEMM A)
  #pragma unroll
  for (int k4 = 0; k4 < 8; ++k4) {
    const int rot = (k4 + bgrp) & 7;
    const int kb = kg*64 + rot*8;
    u32x2_t hv[4];
    #pragma unroll
    for (int i = 0; i < 4; ++i)
      hv[i] = *(const u32x2_t*)(hsb + (b4+i)*HS_RB + (kb ^ (((b4+i)&7)<<4)));
    #pragma unroll
    for (int j = 0; j < 4; ++j) {
      const u32x2_t w0 = *(const u32x2_t*)(w0base + j*4*WL0_RB + kb);
      const u32x2_t w1 = *(const u32x2_t*)(w1base + j*4*WL1_RB + kb);
      #pragma unroll
      for (int i = 0; i < 4; ++i) {
        dot2(acc0[i][j], hv[i].x, w0.x);
        dot2(acc0[i][j], hv[i].y, w0.y);
        dot2(acc1[i][j], hv[i].x, w1.x);
        dot2(acc1[i][j], hv[i].y, w1.y);
      }
    }
  }
  __syncthreads();                               // done reading chunk A

  // ---- chunk B: h1 (512 halves) -> acc1 (L1-h) ----
  stage_write(hsb, row, cq, vvh);
  __syncthreads();

  // ---- prefetch NEXT step's gate context (overlaps GEMM B; consumed next iter) ----
  float nxg0=xg0, nxg1=xg1, nxg2=xg2, nxg3=xg3;
  int nr0 = -1, nr1 = -1;
  if (tid < 64) {
    xg_prefetch(t + 1, maxLg, mrow, xbase, nxg0, nxg1, nxg2, nxg3, nr0);
  } else if (tid < 128) {
    nr1 = (t <= maxLg) ? mrow[t] : -1;           // L1's s at iter t+1 is t
  }

  #pragma unroll
  for (int k4 = 0; k4 < 8; ++k4) {
    const int rot = (k4 + bgrp) & 7;
    const int kb = kg*64 + rot*8;
    u32x2_t hv[4];
    #pragma unroll
    for (int i = 0; i < 4; ++i)
      hv[i] = *(const u32x2_t*)(hsb + (b4+i)*HS_RB + (kb ^ (((b4+i)&7)<<4)));
    #pragma unroll
    for (int j = 0; j < 4; ++j) {
      const u32x2_t w1 = *(const u32x2_t*)(w1base + 1024 + j*4*WL1_RB + kb);
      #pragma unroll
      for (int i = 0; i < 4; ++i) {
        dot2(acc1[i][j], hv[i].x, w1.x);
        dot2(acc1[i][j], hv[i].y, w1.y);
      }
    }
  }
  __syncthreads();                               // before reduce reuses hs

  // ---- reduce 16 kg -> 4 wave-partials (shfl) -> LDS ----
  #pragma unroll
  for (int i = 0; i < 4; ++i)
    #pragma unroll
    for (int j = 0; j < 4; ++j) {
      float v0 = acc0[i][j], v1 = acc1[i][j];
      v0 += __shfl_xor(v0, 16); v0 += __shfl_xor(v0, 32);
      v1 += __shfl_xor(v1, 16); v1 += __shfl_xor(v1, 32);
      acc0[i][j] = v0; acc1[i][j] = v1;
    }
  if (((tid >> 4) & 3) == 0) {
    const int base = (tid >> 6)*256 + slot*16;
    #pragma unroll
    for (int i = 0; i < 4; ++i)
      #pragma unroll
      for (int j = 0; j < 4; ++j) {
        hsf[base + i*4 + j]        = acc0[i][j];
        hsf[1024 + base + i*4 + j] = acc1[i][j];
      }
  }
  __syncthreads();

  // ---- gates: L0 threads 0..63, L1 threads 64..127 ----
  // dead batches (rpre<0): do nothing — stale h is masked forever after.
  if (tid < 64) {
    if (rpre0 >= 0) {
      const int bl = tid & 15, ul = tid >> 4;
      const int pb = gbase + bl, u = us*4 + ul;
      const int idx = pb*H_ + u;
      const int sbase = (ul*4 + (bl>>2))*16 + (bl&3)*4;
      float g0=xg0, g1=xg1, g2=xg2, g3=xg3;
      #pragma unroll
      for (int wv = 0; wv < 4; ++wv) {
        const int base = wv*256 + sbase;
        g0 += hsf[base+0]; g1 += hsf[base+1]; g2 += hsf[base+2]; g3 += hsf[base+3];
      }
      const float cc = sigm(g1)*c0[idx] + sigm(g0)*tanhf(g2);
      c0[idx] = cc;
      store_us_cc(h0n + idx, f2h(sigm(g3)*tanhf(cc)));
    }
  } else if (tid < 128) {
    if (rpre1 >= 0) {
      const int w2 = tid - 64;
      const int bl = w2 & 15, ul = w2 >> 4;
      const int pb = gbase + bl, u = us*4 + ul;
      const int idx = pb*H_ + u;
      const int sbase = (ul*4 + (bl>>2))*16 + (bl&3)*4;
      float g0=b1v0, g1=b1v1, g2=b1v2, g3=b1v3;
      #pragma unroll
      for (int wv = 0; wv < 4; ++wv) {
        const int base = 1024 + wv*256 + sbase;
        g0 += hsf[base+0]; g1 += hsf[base+1]; g2 += hsf[base+2]; g3 += hsf[base+3];
      }
      const float cc = sigm(g1)*c1[idx] + sigm(g0)*tanhf(g2);
      c1[idx] = cc;
      const float hn = sigm(g3)*tanhf(cc);
      store_us_cc(h1n + idx, f2h(hn));
      if (t - 1 == Lrb) store_f_cc(hlast + rb*H_ + u, hn);
    }
  }

  // commit next-step gate context
  xg0 = nxg0; xg1 = nxg1; xg2 = nxg2; xg3 = nxg3;
  rpre0 = nr0; rpre1 = nr1;
}

// ---------------- per-group barrier: single counter, 1 LLC RT on signal path ----------------
__device__ __forceinline__ void grid_barrier_g(int* __restrict__ cnt, int gen)
{
  asm volatile("s_waitcnt vmcnt(0)" ::: "memory");  // drain this thread's sc stores
  __syncthreads();                                   // all threads' stores drained
  if (threadIdx.x == 0) {
    atomicAdd(cnt, 1);                               // device-scope (m20)
    while (__hip_atomic_load(cnt, __ATOMIC_RELAXED, __HIP_MEMORY_SCOPE_AGENT) < gen*128)
      __builtin_amdgcn_s_sleep(1);
  }
  __syncthreads();
}

// ---------------- cooperative persistent kernel ----------------
__global__ __launch_bounds__(256, 2) void k_lstm_coop(
    const float* __restrict__ w_hh0, const float* __restrict__ w_ih1,
    const float* __restrict__ w_hh1, const float* __restrict__ xproj,
    const float* __restrict__ bias1, const int* __restrict__ Lp,
    const int* __restrict__ gmax, const int* __restrict__ map,
    const int* __restrict__ ord,
    ushort* __restrict__ h0b, ushort* __restrict__ h1b,
    float* __restrict__ c0, float* __restrict__ c1, float* __restrict__ hlast,
    const float* __restrict__ fcw, const float* __restrict__ fcb,
    float* __restrict__ out, int* __restrict__ bar)
{
  __shared__ __align__(16) ushort wl0h[16*520];
  __shared__ __align__(16) ushort wl1h[16*1032];
  __shared__ __align__(16) float  hsf[4096];
  const int blk = blockIdx.x;
  const int g = blk >> 7, us = blk & 127;
  const int gbase = group_base(g);
  load_weights(threadIdx.x, us, w_hh0, w_ih1, w_hh1, wl0h, wl1h);
  if (g < 2) __builtin_amdgcn_s_setprio(1);   // long groups win CU arbitration vs short partners
  __syncthreads();
  const int maxLg = gmax[g];
  int* cnt = bar + g*64;

  // ---- per-thread persistent gate context ----
  const int tid = threadIdx.x;
  int rb = 0, Lrb = -2;
  const int* mrow = map;
  const float* xbase = xproj;
  float b1v0=0.f, b1v1=0.f, b1v2=0.f, b1v3=0.f;
  if (tid < 128) {
    rb = ord[gbase + (tid & 15)];
    mrow = map + rb*S_;
    if (tid < 64) {
      xbase = xproj + (size_t)rb*NR_*G4_ + (us*4 + (tid>>4));
    } else {
      const int u = us*4 + ((tid-64)>>4);
      b1v0=bias1[u]; b1v1=bias1[512+u]; b1v2=bias1[1024+u]; b1v3=bias1[1536+u];
      Lrb = Lp[rb];
    }
  }
  float xg0=0.f, xg1=0.f, xg2=0.f, xg3=0.f;
  int rpre0 = -1, rpre1 = -1;
  if (tid < 64) xg_prefetch(0, maxLg, mrow, xbase, xg0, xg1, xg2, xg3, rpre0);

  for (int t = 0; t <= maxLg + 1; ++t) {
    const ushort* h0c = h0b + (size_t)(t & 1)*(B_*H_);
    ushort*       h0n = h0b + (size_t)((t+1) & 1)*(B_*H_);
    const ushort* h1c = h1b + (size_t)(t & 1)*(B_*H_);
    ushort*       h1n = h1b + (size_t)((t+1) & 1)*(B_*H_);
    lstm_iter(t, maxLg, gbase, us, wl0h, wl1h, hsf,
              h0c, h0n, h1c, h1n, c0, c1, hlast,
              mrow, xbase, xg0, xg1, xg2, xg3, rpre0, rpre1,
              b1v0, b1v1, b1v2, b1v3, Lrb, rb);
    grid_barrier_g(cnt, t + 1);
  }
  // ---- per-group FC epilogue (us==0 block; 32 threads, 2 per batch) ----
  if (us == 0 && tid < 32) {
    const int pb = gbase + (tid >> 1), half = tid & 1;
    const int rbf = ord[pb];
    const float* hv = hlast + (size_t)rbf*H_ + half*256;
    const float* fw = fcw + half*256;
    float s = 0.f;
    #pragma unroll 8
    for (int u = 0; u < 256; ++u) s = fmaf(hv[u], fw[u], s);
    s += __shfl_xor(s, 1);
    if (half == 0) store_f_cc(out + rbf, s + fcb[0]);
  }
}

// ---------------- non-cooperative fallback: one iteration per launch ----------------
__global__ __launch_bounds__(256, 2) void k_step(int t,
    const float* __restrict__ w_hh0, const float* __restrict__ w_ih1,
    const float* __restrict__ w_hh1, const float* __restrict__ xproj,
    const float* __restrict__ bias1, const int* __restrict__ Lp,
    const int* __restrict__ gmax, const int* __restrict__ map,
    const int* __restrict__ ord,
    ushort* __restrict__ h0b, ushort* __restrict__ h1b,
    float* __restrict__ c0, float* __restrict__ c1, float* __restrict__ hlast)
{
  __shared__ __align__(16) ushort wl0h[16*520];
  __shared__ __align__(16) ushort wl1h[16*1032];
  __shared__ __align__(16) float  hsf[4096];
  const int blk = blockIdx.x;
  const int g = blk >> 7, us = blk & 127;
  const int gbase = group_base(g);
  const int maxLg = gmax[g];
  if (t > maxLg + 1) return;
  load_weights(threadIdx.x, us, w_hh0, w_ih1, w_hh1, wl0h, wl1h);
  __syncthreads();
  const int tid = threadIdx.x;
  int rb = 0, Lrb = -2;
  const int* mrow = map;
  const float* xbase = xproj;
  float b1v0=0.f, b1v1=0.f, b1v2=0.f, b1v3=0.f;
  if (tid < 128) {
    rb = ord[gbase + (tid & 15)];
    mrow = map + rb*S_;
    if (tid < 64) {
      xbase = xproj + (size_t)rb*NR_*G4_ + (us*4 + (tid>>4));
    } else {
      const int u = us*4 + ((tid-64)>>4);
      b1v0=bias1[u]; b1v1=bias1[512+u]; b1v2=bias1[1024+u]; b1v3=bias1[1536+u];
      Lrb = Lp[rb];
    }
  }
  float xg0=0.f, xg1=0.f, xg2=0.f, xg3=0.f;
  int rpre0 = -1, rpre1 = -1;
  if (tid < 64) xg_prefetch(t, maxLg, mrow, xbase, xg0, xg1, xg2, xg3, rpre0);
  else if (tid < 128) rpre1 = (t-1 >= 0 && t-1 <= maxLg) ? mrow[t-1] : -1;

  const ushort* h0c = h0b + (size_t)(t & 1)*(B_*H_);
  ushort*       h0n = h0b + (size_t)((t+1) & 1)*(B_*H_);
  const ushort* h1c = h1b + (size_t)(t & 1)*(B_*H_);
  ushort*       h1n = h1b + (size_t)((t+1) & 1)*(B_*H_);
  lstm_iter(t, maxLg, gbase, us, wl0h, wl1h, hsf,
            h0c, h0n, h1c, h1n, c0, c1, hlast,
            mrow, xbase, xg0, xg1, xg2, xg3, rpre0, rpre1,
            b1v0, b1v1, b1v2, b1v3, Lrb, rb);
}

__global__ __launch_bounds__(128) void k_fc(
    const float* __restrict__ hlast, const float* __restrict__ fcw,
    const float* __restrict__ fcb, float* __restrict__ out)
{
  const int tid = threadIdx.x;
  if (tid < 128) {
    const int b = tid >> 1, half = tid & 1;
    const float* hv = hlast + (size_t)b*H_ + half*256;
    const float* fw = fcw + half*256;
    float s = 0.f;
    #pragma unroll 8
    for (int u = 0; u < 256; ++u) s = fmaf(hv[u], fw[u], s);
    s += __shfl_xor(s, 1);
    if (half == 0) out[b] = s + fcb[0];
  }
}

// ---------------- host ----------------
extern "C" void kernel_launch(void* const* d_in, const int* in_sizes, int n_in,
                              void* d_out, int out_size, void* d_ws, size_t ws_size,
                              hipStream_t stream)
{
  const float* text  = (const float*)d_in[0];
  const float* ques  = (const float*)d_in[1];
  const float* code  = (const float*)d_in[2];
  const int*   ns    = (const int*)  d_in[3];
  const int*   que   = (const int*)  d_in[4];
  const float* w_ih0 = (const float*)d_in[5];
  const float* w_hh0 = (const float*)d_in[6];
  const float* b_ih0 = (const float*)d_in[7];
  const float* b_hh0 = (const float*)d_in[8];
  const float* w_ih1 = (const float*)d_in[9];
  const float* w_hh1 = (const float*)d_in[10];
  const float* b_ih1 = (const float*)d_in[11];
  const float* b_hh1 = (const float*)d_in[12];
  const float* fcw   = (const float*)d_in[13];
  const float* fcb   = (const float*)d_in[14];
  float* out = (float*)d_out;

  char* ws = (char*)d_ws;
  int*    Lp     = (int*)   (ws + OFF_L);
  int*    maxLp  = (int*)   (ws + OFF_MAXL);
  int*    map    = (int*)   (ws + OFF_MAP);
  float*  bias0  = (float*) (ws + OFF_BIAS0);
  float*  bias1  = (float*) (ws + OFF_BIAS1);
  float*  c0     = (float*) (ws + OFF_C0);
  float*  c1     = (float*) (ws + OFF_C1);
  float*  hlast  = (float*) (ws + OFF_HLAST);
  ushort* h0b    = (ushort*)(ws + OFF_H0B);
  ushort* h1b    = (ushort*)(ws + OFF_H1B);
  float*  wT_ih0 = (float*) (ws + OFF_WTIH0);
  float*  xproj  = (float*) (ws + OFF_XPROJ);
  int*    bar    = (int*)   (ws + OFF_BAR);
  int*    ord    = (int*)   (ws + OFF_ORD);
  int*    gmax   = (int*)   (ws + OFF_GMAX);
  (void)in_sizes; (void)n_in; (void)out_size; (void)ws_size; (void)WS_NEED;

  hipLaunchKernelGGL(k_prep, dim3(1), dim3(256), 0, stream,
                     ns, que, b_ih0, b_hh0, b_ih1, b_hh1,
                     Lp, maxLp, map, bias0, bias1, c0, c1, hlast, h0b, h1b, bar,
                     ord, gmax);

  hipLaunchKernelGGL(k_transpose, dim3(64, 24), dim3(32, 8), 0, stream,
                     w_ih0, wT_ih0);

  hipLaunchKernelGGL(k_proj, dim3(81, 16), dim3(128), 0, stream,
                     text, ques, code, wT_ih0, bias0, xproj);

  const float* a_whh0 = w_hh0; const float* a_wih1 = w_ih1; const float* a_whh1 = w_hh1;
  const float* a_xp = xproj;   const float* a_b1 = bias1;
  const int* a_Lp = Lp; const int* a_gmax = gmax; const int* a_map = map;
  const int* a_ord = ord;
  ushort* a_h0b = h0b; ushort* a_h1b = h1b; float* a_c0 = c0; float* a_c1 = c1;
  float* a_hl = hlast; const float* a_fcw = fcw; const float* a_fcb = fcb;
  float* a_out = out; int* a_bar = bar;
  void* args[] = { &a_whh0, &a_wih1, &a_whh1, &a_xp, &a_b1, &a_Lp, &a_gmax, &a_map,
                   &a_ord, &a_h0b, &a_h1b, &a_c0, &a_c1, &a_hl, &a_fcw, &a_fcb,
                   &a_out, &a_bar };

  hipError_t err = hipLaunchCooperativeKernel((const void*)k_lstm_coop,
                                              dim3(512), dim3(256), args, 0, stream);
  if (err != hipSuccess) {
    (void)hipGetLastError();  // clear error state
    for (int t = 0; t < S_ + 1; ++t) {
      hipLaunchKernelGGL(k_step, dim3(512), dim3(256), 0, stream, t,
                         w_hh0, w_ih1, w_hh1, xproj, bias1, Lp, gmax, map, ord,
                         h0b, h1b, c0, c1, hlast);
    }
    hipLaunchKernelGGL(k_fc, dim3(1), dim3(128), 0, stream, hlast, fcw, fcb, out);
  }
}

// Round 10
// 2744.220 us; speedup vs baseline: 5.6674x; 1.3263x over previous
//
#include <hip/hip_runtime.h>
#include <hip/hip_cooperative_groups.h>

namespace cg = cooperative_groups;

#define B_    64
#define Q_    16
#define MAXK_ 32
#define C_    64
#define D_    768
#define H_    512
#define G4_   2048   // 4*H
#define S_    529    // Q*(MAXK+1)+1
#define NR_   81     // 16 questions + 64 code + 1 text

typedef float f32x4_t __attribute__((ext_vector_type(4)));
typedef unsigned int u32x2_t __attribute__((ext_vector_type(2)));
typedef unsigned int u32x4_t __attribute__((ext_vector_type(4)));
typedef _Float16 f16x8_t __attribute__((ext_vector_type(8)));

// ---------------- workspace layout (bytes) ----------------
static constexpr size_t OFF_L     = 0;                      // 64 int
static constexpr size_t OFF_MAXL  = 256;
static constexpr size_t OFF_MAP   = 512;                    // 64*529*4
static constexpr size_t OFF_BIAS0 = OFF_MAP   + 135424;     // 2048 f
static constexpr size_t OFF_BIAS1 = OFF_BIAS0 + 8192;       // 2048 f
static constexpr size_t OFF_C0    = OFF_BIAS1 + 8192;       // 64*512 f
static constexpr size_t OFF_C1    = OFF_C0    + 131072;
static constexpr size_t OFF_HLAST = OFF_C1    + 131072;     // 64*512 f (fp32, real-batch idx)
static constexpr size_t OFF_H0B   = OFF_HLAST + 131072;     // 2 x 64*512 half (sorted idx)
static constexpr size_t OFF_H1B   = OFF_H0B   + 262144;
static constexpr size_t OFF_WTIH0 = OFF_H1B   + 262144;     // 768x2048 f
static constexpr size_t OFF_XPROJ = OFF_WTIH0 + 6291456ULL; // 64*81*2048 f
static constexpr size_t OFF_BAR   = OFF_XPROJ + 42467328ULL; // 4 groups x 64 int
static constexpr size_t OFF_ORD   = OFF_BAR   + 4096;       // 64 int (sorted batch ids)
static constexpr size_t OFF_GMAX  = OFF_ORD   + 256;        // 4 int (per-group max L)
static constexpr size_t WS_NEED   = OFF_GMAX  + 256;

// group g owns sorted ranks [gbase, gbase+16): pair longest(g0) with shortest(g2)
__device__ __forceinline__ int group_base(int g) {
  return (g == 0) ? 0 : (g == 1) ? 16 : (g == 2) ? 48 : 32;
}

// ---------------- coherent (L2-bypass) access helpers ----------------
__device__ __forceinline__ void store_us_cc(ushort* p, unsigned int v) {
  asm volatile("global_store_short %0, %1, off sc0 sc1" :: "v"(p), "v"(v) : "memory");
}
__device__ __forceinline__ void store_f_cc(float* p, float v) {
  asm volatile("global_store_dword %0, %1, off sc0 sc1" :: "v"(p), "v"(v) : "memory");
}
__device__ __forceinline__ void load_a_cc(u32x4_t& v, const ushort* p) {
  asm volatile("global_load_dwordx4 %0, %1, off sc0 sc1" : "=v"(v) : "v"(p) : "memory");
}

__device__ __forceinline__ unsigned int pkrtz(float a, float b) {
  auto r = __builtin_amdgcn_cvt_pkrtz(a, b);
  unsigned int u;
  __builtin_memcpy(&u, &r, 4);
  return u;
}
__device__ __forceinline__ unsigned int f2h(float a) {
  return pkrtz(a, 0.f) & 0xffffu;
}
__device__ __forceinline__ f32x4_t mfma16(u32x4_t a, u32x4_t b, f32x4_t c) {
  f16x8_t av, bv;
  __builtin_memcpy(&av, &a, 16);
  __builtin_memcpy(&bv, &b, 16);
  return __builtin_amdgcn_mfma_f32_16x16x32_f16(av, bv, c, 0, 0, 0);
}

__device__ __forceinline__ float sigm(float x) { return 1.f/(1.f + __expf(-x)); }

// ---------------- prep ----------------
__global__ __launch_bounds__(256) void k_prep(
    const int* __restrict__ ns, const int* __restrict__ que,
    const float* __restrict__ b_ih0, const float* __restrict__ b_hh0,
    const float* __restrict__ b_ih1, const float* __restrict__ b_hh1,
    int* __restrict__ Lp, int* __restrict__ maxLp, int* __restrict__ map,
    float* __restrict__ bias0, float* __restrict__ bias1,
    float* __restrict__ c0, float* __restrict__ c1, float* __restrict__ hlast,
    ushort* __restrict__ h0b, ushort* __restrict__ h1b, int* __restrict__ bar,
    int* __restrict__ ord, int* __restrict__ gmax)
{
  const int tid = threadIdx.x;
  for (int i = tid; i < B_*S_; i += 256) map[i] = -1;
  for (int i = tid; i < G4_; i += 256) {
    bias0[i] = b_ih0[i] + b_hh0[i];
    bias1[i] = b_ih1[i] + b_hh1[i];
  }
  int* h0i = (int*)h0b;
  int* h1i = (int*)h1b;
  for (int i = tid; i < B_*H_; i += 256) {
    c0[i]=0.f; c1[i]=0.f; hlast[i]=0.f;
    h0i[i]=0; h1i[i]=0;
  }
  for (int i = tid; i < 1024; i += 256) bar[i] = 0;
  if (tid == 0) *maxLp = 0;
  __syncthreads();
  if (tid < B_) {
    const int b = tid;
    const int qn = que[b];
    int pos = 0;
    int* m = map + b*S_;
    for (int q = 0; q < qn; ++q) {
      m[pos++] = q;
      const int n = ns[b*Q_ + q];
      for (int k = 0; k < n; ++k) {
        int j = q + k; if (j > C_-1) j = C_-1;
        m[pos++] = 16 + j;
      }
    }
    m[pos] = 80;
    Lp[b] = pos;
    atomicMax(maxLp, pos);
  }
  __syncthreads();
  // rank-sort batches by L descending -> ord[rank] = batch
  if (tid < B_) {
    const int myL = Lp[tid];
    int rank = 0;
    for (int j = 0; j < B_; ++j) {
      const int lj = Lp[j];
      rank += (lj > myL) || (lj == myL && j < tid);
    }
    ord[rank] = tid;
  }
  __syncthreads();
  if (tid < 4) {
    const int gb = (tid == 0) ? 0 : (tid == 1) ? 16 : (tid == 2) ? 48 : 32;
    gmax[tid] = Lp[ord[gb]];
  }
}

// ---------------- transpose W_ih0 only: [2048][768] -> [768][2048] ----------------
__global__ __launch_bounds__(256) void k_transpose(
    const float* __restrict__ w, float* __restrict__ wT)
{
  __shared__ float tile[32][33];
  const int n0 = blockIdx.x * 32;
  const int k0 = blockIdx.y * 32;
  const int tx = threadIdx.x, ty = threadIdx.y;
  for (int i = ty; i < 32; i += 8)
    tile[i][tx] = w[(size_t)(n0+i)*D_ + k0 + tx];
  __syncthreads();
  for (int i = ty; i < 32; i += 8)
    wT[(size_t)(k0 + i)*G4_ + n0 + tx] = tile[tx][i];
}

// ---------------- xproj: project 81 distinct source rows per batch (fp32) ----------------
__global__ __launch_bounds__(128, 2) void k_proj(
    const float* __restrict__ text, const float* __restrict__ ques,
    const float* __restrict__ code, const float* __restrict__ wT_ih0,
    const float* __restrict__ bias0, float* __restrict__ xproj)
{
  __shared__ float hsLds[32][64];
  const int mb = blockIdx.x, nb = blockIdx.y;
  const int n0 = nb * 128;
  const int tid = threadIdx.x;
  const int tb = tid >> 4, tn = tid & 15;
  const int b0 = tb * 8;
  const int bb = tid >> 1, hh = tid & 1;

  const int mrow = mb*64 + bb;
  const int sb = mrow / NR_, sr = mrow % NR_;
  const float* srcrow = (sr < 16) ? (ques + ((size_t)sb*Q_ + sr)*D_)
                      : (sr < 80) ? (code + ((size_t)sb*C_ + (sr-16))*D_)
                                  : (text + (size_t)sb*D_);

  float a[8][8];
  #pragma unroll
  for (int i=0;i<8;i++)
    #pragma unroll
    for (int j=0;j<8;j++) a[i][j]=0.f;

  for (int k0 = 0; k0 < D_; k0 += 32) {
    __syncthreads();
    {
      const float* p = srcrow + k0 + hh*16;
      float4 v0 = *(const float4*)(p+0);
      float4 v1 = *(const float4*)(p+4);
      float4 v2 = *(const float4*)(p+8);
      float4 v3 = *(const float4*)(p+12);
      const int kk = hh*16;
      hsLds[kk+ 0][bb]=v0.x; hsLds[kk+ 1][bb]=v0.y; hsLds[kk+ 2][bb]=v0.z; hsLds[kk+ 3][bb]=v0.w;
      hsLds[kk+ 4][bb]=v1.x; hsLds[kk+ 5][bb]=v1.y; hsLds[kk+ 6][bb]=v1.z; hsLds[kk+ 7][bb]=v1.w;
      hsLds[kk+ 8][bb]=v2.x; hsLds[kk+ 9][bb]=v2.y; hsLds[kk+10][bb]=v2.z; hsLds[kk+11][bb]=v2.w;
      hsLds[kk+12][bb]=v3.x; hsLds[kk+13][bb]=v3.y; hsLds[kk+14][bb]=v3.z; hsLds[kk+15][bb]=v3.w;
    }
    __syncthreads();
    const float* wb = wT_ih0 + (size_t)k0*G4_ + n0 + tn*8;
    #pragma unroll 4
    for (int k=0;k<32;k++){
      float4 w0 = *(const float4*)(wb + (size_t)k*G4_);
      float4 w1 = *(const float4*)(wb + (size_t)k*G4_ + 4);
      float4 hA = *(const float4*)(&hsLds[k][b0]);
      float4 hB = *(const float4*)(&hsLds[k][b0+4]);
      float hv[8]={hA.x,hA.y,hA.z,hA.w,hB.x,hB.y,hB.z,hB.w};
      float wv[8]={w0.x,w0.y,w0.z,w0.w,w1.x,w1.y,w1.z,w1.w};
      #pragma unroll
      for (int i=0;i<8;i++)
        #pragma unroll
        for (int j=0;j<8;j++)
          a[i][j] = fmaf(hv[i], wv[j], a[i][j]);
    }
  }
  float bz[8];
  #pragma unroll
  for (int j=0;j<8;j++) bz[j] = bias0[n0 + tn*8 + j];
  #pragma unroll
  for (int i=0;i<8;i++){
    const int m = mb*64 + b0 + i;
    float* pd = xproj + (size_t)m*G4_ + n0 + tn*8;
    *(float4*)(pd+0) = make_float4(a[i][0]+bz[0], a[i][1]+bz[1], a[i][2]+bz[2], a[i][3]+bz[3]);
    *(float4*)(pd+4) = make_float4(a[i][4]+bz[4], a[i][5]+bz[5], a[i][6]+bz[6], a[i][7]+bz[7]);
  }
}

// ---------------- persistent LSTM (MFMA core) ----------------
// 512 blocks: g = blk>>7 (sync domain / 16 sorted batches), us = blk&127 (4 units).
// Per block: D[16 batches][16 n] per layer; n(idx) = (idx>>2)*512 + us*4 + (idx&3).
// Wave wv: L0 K-slice [wv*128,+128) of W_hh0 (4 MFMA); L1 K-slice 256:
// waves 0,1 -> W_ih1 (A=h0), waves 2,3 -> W_hh1 (A=h1). 12 MFMA/wave/iter.
// Weights live in VGPRs (48/lane); cross-wave K-reduce via LDS partials.

// load this thread's 12 weight B-fragments (f16 packed)
__device__ __forceinline__ void load_wfrags(int tid, int us,
    const float* __restrict__ w_hh0, const float* __restrict__ w_ih1,
    const float* __restrict__ w_hh1, u32x4_t* wf0, u32x4_t* wf1)
{
  const int wv = tid >> 6, lane = tid & 63;
  const int nidx = lane & 15, kgrp = lane >> 4;
  const int ngl = (nidx >> 2)*H_ + us*4 + (nidx & 3);
  const float* r0 = w_hh0 + (size_t)ngl*H_ + wv*128 + kgrp*8;
  #pragma unroll
  for (int f = 0; f < 4; ++f) {
    float4 lo = *(const float4*)(r0 + f*32);
    float4 hi = *(const float4*)(r0 + f*32 + 4);
    wf0[f] = (u32x4_t){pkrtz(lo.x,lo.y), pkrtz(lo.z,lo.w), pkrtz(hi.x,hi.y), pkrtz(hi.z,hi.w)};
  }
  const float* w1 = (wv < 2) ? w_ih1 : w_hh1;
  const float* r1 = w1 + (size_t)ngl*H_ + (wv & 1)*256 + kgrp*8;
  #pragma unroll
  for (int f = 0; f < 8; ++f) {
    float4 lo = *(const float4*)(r1 + f*32);
    float4 hi = *(const float4*)(r1 + f*32 + 4);
    wf1[f] = (u32x4_t){pkrtz(lo.x,lo.y), pkrtz(lo.z,lo.w), pkrtz(hi.x,hi.y), pkrtz(hi.z,hi.w)};
  }
}

// gate-context prefetch for L0 threads (tid<64)
__device__ __forceinline__ void xg_prefetch(int t, int maxLg,
    const int* __restrict__ mrow, const float* __restrict__ xbase,
    float& xg0, float& xg1, float& xg2, float& xg3, int& rpre)
{
  rpre = (t <= maxLg) ? mrow[t] : -1;
  const float* xp = xbase + (size_t)(rpre < 0 ? 0 : rpre)*G4_;
  xg0 = xp[0]; xg1 = xp[512]; xg2 = xp[1024]; xg3 = xp[1536];
}

__device__ __forceinline__ void lstm_iter(int t, int maxLg, int gbase, int us,
    const u32x4_t* wf0, const u32x4_t* wf1, float* __restrict__ P,
    const ushort* __restrict__ h0c, ushort* __restrict__ h0n,
    const ushort* __restrict__ h1c, ushort* __restrict__ h1n,
    float* __restrict__ c0, float* __restrict__ c1, float* __restrict__ hlast,
    const int* __restrict__ mrow, const float* __restrict__ xbase,
    float& xg0, float& xg1, float& xg2, float& xg3, int& rpre0, int& rpre1,
    float b1v0, float b1v1, float b1v2, float b1v3, int Lrb, int rb)
{
  const int tid = threadIdx.x;
  const int wv = tid >> 6, lane = tid & 63;
  const int nidx = lane & 15, kgrp = lane >> 4;

  // ---- A-fragment loads (h through LLC), first thing after the barrier ----
  u32x4_t a0[4], a1[8];
  {
    const ushort* h0r = h0c + (size_t)(gbase + nidx)*H_ + wv*128 + kgrp*8;
    #pragma unroll
    for (int f = 0; f < 4; ++f) load_a_cc(a0[f], h0r + f*32);
    const ushort* hs1 = (wv < 2) ? h0c : h1c;
    const ushort* h1r = hs1 + (size_t)(gbase + nidx)*H_ + (wv & 1)*256 + kgrp*8;
    #pragma unroll
    for (int f = 0; f < 8; ++f) load_a_cc(a1[f], h1r + f*32);
  }
  asm volatile("s_waitcnt vmcnt(0)" ::: "memory");
  __builtin_amdgcn_sched_barrier(0);   // rule #18: keep MFMAs below the wait

  f32x4_t acc0 = {0.f,0.f,0.f,0.f};
  f32x4_t acc1 = {0.f,0.f,0.f,0.f};
  #pragma unroll
  for (int f = 0; f < 4; ++f) acc0 = mfma16(a0[f], wf0[f], acc0);
  #pragma unroll
  for (int f = 0; f < 8; ++f) acc1 = mfma16(a1[f], wf1[f], acc1);

  // ---- stash per-wave partials: P[(wv*2+layer)*16 + m][17] + n ----
  #pragma unroll
  for (int r = 0; r < 4; ++r) {
    P[((wv*2+0)*16 + kgrp*4 + r)*17 + nidx] = acc0[r];
    P[((wv*2+1)*16 + kgrp*4 + r)*17 + nidx] = acc1[r];
  }

  // ---- prefetch NEXT step's gate context (drained by arrive's vmcnt) ----
  float nxg0=xg0, nxg1=xg1, nxg2=xg2, nxg3=xg3;
  int nr0 = -1, nr1 = -1;
  if (tid < 64) {
    xg_prefetch(t + 1, maxLg, mrow, xbase, nxg0, nxg1, nxg2, nxg3, nr0);
  } else if (tid < 128) {
    nr1 = (t <= maxLg) ? mrow[t] : -1;
  }
  __syncthreads();

  // ---- gates: L0 threads 0..63, L1 threads 64..127 ----
  if (tid < 64) {
    if (rpre0 >= 0) {
      const int bl = tid & 15, ul = tid >> 4;
      const int pb = gbase + bl, u = us*4 + ul;
      const int idx = pb*H_ + u;
      float g0=xg0, g1=xg1, g2=xg2, g3=xg3;
      #pragma unroll
      for (int w = 0; w < 4; ++w) {
        const float* Pr = P + ((w*2+0)*16 + bl)*17 + ul;
        g0 += Pr[0]; g1 += Pr[4]; g2 += Pr[8]; g3 += Pr[12];
      }
      const float cc = sigm(g1)*c0[idx] + sigm(g0)*tanhf(g2);
      c0[idx] = cc;
      store_us_cc(h0n + idx, f2h(sigm(g3)*tanhf(cc)));
    }
  } else if (tid < 128) {
    if (rpre1 >= 0) {
      const int w2 = tid - 64;
      const int bl = w2 & 15, ul = w2 >> 4;
      const int pb = gbase + bl, u = us*4 + ul;
      const int idx = pb*H_ + u;
      float g0=b1v0, g1=b1v1, g2=b1v2, g3=b1v3;
      #pragma unroll
      for (int w = 0; w < 4; ++w) {
        const float* Pr = P + ((w*2+1)*16 + bl)*17 + ul;
        g0 += Pr[0]; g1 += Pr[4]; g2 += Pr[8]; g3 += Pr[12];
      }
      const float cc = sigm(g1)*c1[idx] + sigm(g0)*tanhf(g2);
      c1[idx] = cc;
      const float hn = sigm(g3)*tanhf(cc);
      store_us_cc(h1n + idx, f2h(hn));
      if (t - 1 == Lrb) store_f_cc(hlast + rb*H_ + u, hn);
    }
  }

  xg0 = nxg0; xg1 = nxg1; xg2 = nxg2; xg3 = nxg3;
  rpre0 = nr0; rpre1 = nr1;
}

// ---------------- per-group barrier: single counter ----------------
__device__ __forceinline__ void grid_barrier_g(int* __restrict__ cnt, int gen)
{
  asm volatile("s_waitcnt vmcnt(0)" ::: "memory");
  __syncthreads();
  if (threadIdx.x == 0) {
    atomicAdd(cnt, 1);
    while (__hip_atomic_load(cnt, __ATOMIC_RELAXED, __HIP_MEMORY_SCOPE_AGENT) < gen*128)
      __builtin_amdgcn_s_sleep(1);
  }
  __syncthreads();
}

// ---------------- cooperative persistent kernel ----------------
__global__ __launch_bounds__(256, 2) void k_lstm_coop(
    const float* __restrict__ w_hh0, const float* __restrict__ w_ih1,
    const float* __restrict__ w_hh1, const float* __restrict__ xproj,
    const float* __restrict__ bias1, const int* __restrict__ Lp,
    const int* __restrict__ gmax, const int* __restrict__ map,
    const int* __restrict__ ord,
    ushort* __restrict__ h0b, ushort* __restrict__ h1b,
    float* __restrict__ c0, float* __restrict__ c1, float* __restrict__ hlast,
    const float* __restrict__ fcw, const float* __restrict__ fcb,
    float* __restrict__ out, int* __restrict__ bar)
{
  __shared__ __align__(16) float P[8*16*17];
  const int blk = blockIdx.x;
  const int g = blk >> 7, us = blk & 127;
  const int gbase = group_base(g);
  const int tid = threadIdx.x;

  u32x4_t wf0[4], wf1[8];
  load_wfrags(tid, us, w_hh0, w_ih1, w_hh1, wf0, wf1);
  if (g < 2) __builtin_amdgcn_s_setprio(1);
  const int maxLg = gmax[g];
  int* cnt = bar + g*64;

  // ---- per-thread persistent gate context ----
  int rb = 0, Lrb = -2;
  const int* mrow = map;
  const float* xbase = xproj;
  float b1v0=0.f, b1v1=0.f, b1v2=0.f, b1v3=0.f;
  if (tid < 128) {
    rb = ord[gbase + (tid & 15)];
    mrow = map + rb*S_;
    if (tid < 64) {
      xbase = xproj + (size_t)rb*NR_*G4_ + (us*4 + (tid>>4));
    } else {
      const int u = us*4 + ((tid-64)>>4);
      b1v0=bias1[u]; b1v1=bias1[512+u]; b1v2=bias1[1024+u]; b1v3=bias1[1536+u];
      Lrb = Lp[rb];
    }
  }
  float xg0=0.f, xg1=0.f, xg2=0.f, xg3=0.f;
  int rpre0 = -1, rpre1 = -1;
  if (tid < 64) xg_prefetch(0, maxLg, mrow, xbase, xg0, xg1, xg2, xg3, rpre0);
  __syncthreads();

  for (int t = 0; t <= maxLg + 1; ++t) {
    const ushort* h0c = h0b + (size_t)(t & 1)*(B_*H_);
    ushort*       h0n = h0b + (size_t)((t+1) & 1)*(B_*H_);
    const ushort* h1c = h1b + (size_t)(t & 1)*(B_*H_);
    ushort*       h1n = h1b + (size_t)((t+1) & 1)*(B_*H_);
    lstm_iter(t, maxLg, gbase, us, wf0, wf1, P,
              h0c, h0n, h1c, h1n, c0, c1, hlast,
              mrow, xbase, xg0, xg1, xg2, xg3, rpre0, rpre1,
              b1v0, b1v1, b1v2, b1v3, Lrb, rb);
    grid_barrier_g(cnt, t + 1);
  }
  // ---- per-group FC epilogue ----
  if (us == 0 && tid < 32) {
    const int pb = gbase + (tid >> 1), half = tid & 1;
    const int rbf = ord[pb];
    const float* hv = hlast + (size_t)rbf*H_ + half*256;
    const float* fw = fcw + half*256;
    float s = 0.f;
    #pragma unroll 8
    for (int u = 0; u < 256; ++u) s = fmaf(hv[u], fw[u], s);
    s += __shfl_xor(s, 1);
    if (half == 0) store_f_cc(out + rbf, s + fcb[0]);
  }
}

// ---------------- non-cooperative fallback: one iteration per launch ----------------
__global__ __launch_bounds__(256, 2) void k_step(int t,
    const float* __restrict__ w_hh0, const float* __restrict__ w_ih1,
    const float* __restrict__ w_hh1, const float* __restrict__ xproj,
    const float* __restrict__ bias1, const int* __restrict__ Lp,
    const int* __restrict__ gmax, const int* __restrict__ map,
    const int* __restrict__ ord,
    ushort* __restrict__ h0b, ushort* __restrict__ h1b,
    float* __restrict__ c0, float* __restrict__ c1, float* __restrict__ hlast)
{
  __shared__ __align__(16) float P[8*16*17];
  const int blk = blockIdx.x;
  const int g = blk >> 7, us = blk & 127;
  const int gbase = group_base(g);
  const int maxLg = gmax[g];
  if (t > maxLg + 1) return;
  const int tid = threadIdx.x;
  u32x4_t wf0[4], wf1[8];
  load_wfrags(tid, us, w_hh0, w_ih1, w_hh1, wf0, wf1);

  int rb = 0, Lrb = -2;
  const int* mrow = map;
  const float* xbase = xproj;
  float b1v0=0.f, b1v1=0.f, b1v2=0.f, b1v3=0.f;
  if (tid < 128) {
    rb = ord[gbase + (tid & 15)];
    mrow = map + rb*S_;
    if (tid < 64) {
      xbase = xproj + (size_t)rb*NR_*G4_ + (us*4 + (tid>>4));
    } else {
      const int u = us*4 + ((tid-64)>>4);
      b1v0=bias1[u]; b1v1=bias1[512+u]; b1v2=bias1[1024+u]; b1v3=bias1[1536+u];
      Lrb = Lp[rb];
    }
  }
  float xg0=0.f, xg1=0.f, xg2=0.f, xg3=0.f;
  int rpre0 = -1, rpre1 = -1;
  if (tid < 64) xg_prefetch(t, maxLg, mrow, xbase, xg0, xg1, xg2, xg3, rpre0);
  else if (tid < 128) rpre1 = (t-1 >= 0 && t-1 <= maxLg) ? mrow[t-1] : -1;
  __syncthreads();

  const ushort* h0c = h0b + (size_t)(t & 1)*(B_*H_);
  ushort*       h0n = h0b + (size_t)((t+1) & 1)*(B_*H_);
  const ushort* h1c = h1b + (size_t)(t & 1)*(B_*H_);
  ushort*       h1n = h1b + (size_t)((t+1) & 1)*(B_*H_);
  lstm_iter(t, maxLg, gbase, us, wf0, wf1, P,
            h0c, h0n, h1c, h1n, c0, c1, hlast,
            mrow, xbase, xg0, xg1, xg2, xg3, rpre0, rpre1,
            b1v0, b1v1, b1v2, b1v3, Lrb, rb);
}

__global__ __launch_bounds__(128) void k_fc(
    const float* __restrict__ hlast, const float* __restrict__ fcw,
    const float* __restrict__ fcb, float* __restrict__ out)
{
  const int tid = threadIdx.x;
  if (tid < 128) {
    const int b = tid >> 1, half = tid & 1;
    const float* hv = hlast + (size_t)b*H_ + half*256;
    const float* fw = fcw + half*256;
    float s = 0.f;
    #pragma unroll 8
    for (int u = 0; u < 256; ++u) s = fmaf(hv[u], fw[u], s);
    s += __shfl_xor(s, 1);
    if (half == 0) out[b] = s + fcb[0];
  }
}

// ---------------- host ----------------
extern "C" void kernel_launch(void* const* d_in, const int* in_sizes, int n_in,
                              void* d_out, int out_size, void* d_ws, size_t ws_size,
                              hipStream_t stream)
{
  const float* text  = (const float*)d_in[0];
  const float* ques  = (const float*)d_in[1];
  const float* code  = (const float*)d_in[2];
  const int*   ns    = (const int*)  d_in[3];
  const int*   que   = (const int*)  d_in[4];
  const float* w_ih0 = (const float*)d_in[5];
  const float* w_hh0 = (const float*)d_in[6];
  const float* b_ih0 = (const float*)d_in[7];
  const float* b_hh0 = (const float*)d_in[8];
  const float* w_ih1 = (const float*)d_in[9];
  const float* w_hh1 = (const float*)d_in[10];
  const float* b_ih1 = (const float*)d_in[11];
  const float* b_hh1 = (const float*)d_in[12];
  const float* fcw   = (const float*)d_in[13];
  const float* fcb   = (const float*)d_in[14];
  float* out = (float*)d_out;

  char* ws = (char*)d_ws;
  int*    Lp     = (int*)   (ws + OFF_L);
  int*    maxLp  = (int*)   (ws + OFF_MAXL);
  int*    map    = (int*)   (ws + OFF_MAP);
  float*  bias0  = (float*) (ws + OFF_BIAS0);
  float*  bias1  = (float*) (ws + OFF_BIAS1);
  float*  c0     = (float*) (ws + OFF_C0);
  float*  c1     = (float*) (ws + OFF_C1);
  float*  hlast  = (float*) (ws + OFF_HLAST);
  ushort* h0b    = (ushort*)(ws + OFF_H0B);
  ushort* h1b    = (ushort*)(ws + OFF_H1B);
  float*  wT_ih0 = (float*) (ws + OFF_WTIH0);
  float*  xproj  = (float*) (ws + OFF_XPROJ);
  int*    bar    = (int*)   (ws + OFF_BAR);
  int*    ord    = (int*)   (ws + OFF_ORD);
  int*    gmax   = (int*)   (ws + OFF_GMAX);
  (void)in_sizes; (void)n_in; (void)out_size; (void)ws_size; (void)WS_NEED;

  hipLaunchKernelGGL(k_prep, dim3(1), dim3(256), 0, stream,
                     ns, que, b_ih0, b_hh0, b_ih1, b_hh1,
                     Lp, maxLp, map, bias0, bias1, c0, c1, hlast, h0b, h1b, bar,
                     ord, gmax);

  hipLaunchKernelGGL(k_transpose, dim3(64, 24), dim3(32, 8), 0, stream,
                     w_ih0, wT_ih0);

  hipLaunchKernelGGL(k_proj, dim3(81, 16), dim3(128), 0, stream,
                     text, ques, code, wT_ih0, bias0, xproj);

  const float* a_whh0 = w_hh0; const float* a_wih1 = w_ih1; const float* a_whh1 = w_hh1;
  const float* a_xp = xproj;   const float* a_b1 = bias1;
  const int* a_Lp = Lp; const int* a_gmax = gmax; const int* a_map = map;
  const int* a_ord = ord;
  ushort* a_h0b = h0b; ushort* a_h1b = h1b; float* a_c0 = c0; float* a_c1 = c1;
  float* a_hl = hlast; const float* a_fcw = fcw; const float* a_fcb = fcb;
  float* a_out = out; int* a_bar = bar;
  void* args[] = { &a_whh0, &a_wih1, &a_whh1, &a_xp, &a_b1, &a_Lp, &a_gmax, &a_map,
                   &a_ord, &a_h0b, &a_h1b, &a_c0, &a_c1, &a_hl, &a_fcw, &a_fcb,
                   &a_out, &a_bar };

  hipError_t err = hipLaunchCooperativeKernel((const void*)k_lstm_coop,
                                              dim3(512), dim3(256), args, 0, stream);
  if (err != hipSuccess) {
    (void)hipGetLastError();  // clear error state
    for (int t = 0; t < S_ + 1; ++t) {
      hipLaunchKernelGGL(k_step, dim3(512), dim3(256), 0, stream, t,
                         w_hh0, w_ih1, w_hh1, xproj, bias1, Lp, gmax, map, ord,
                         h0b, h1b, c0, c1, hlast);
    }
    hipLaunchKernelGGL(k_fc, dim3(1), dim3(128), 0, stream, hlast, fcw, fcb, out);
  }
}

// Round 11
// 2255.476 us; speedup vs baseline: 6.8955x; 1.2167x over previous
//
#include <hip/hip_runtime.h>
#include <hip/hip_cooperative_groups.h>

namespace cg = cooperative_groups;

#define B_    64
#define Q_    16
#define MAXK_ 32
#define C_    64
#define D_    768
#define H_    512
#define G4_   2048   // 4*H
#define S_    529    // Q*(MAXK+1)+1
#define NR_   81     // 16 questions + 64 code + 1 text

typedef float f32x4_t __attribute__((ext_vector_type(4)));
typedef unsigned int u32x2_t __attribute__((ext_vector_type(2)));
typedef unsigned int u32x4_t __attribute__((ext_vector_type(4)));
typedef _Float16 f16x8_t __attribute__((ext_vector_type(8)));

// ---------------- workspace layout (bytes) ----------------
static constexpr size_t OFF_L     = 0;                      // 64 int
static constexpr size_t OFF_MAXL  = 256;
static constexpr size_t OFF_MAP   = 512;                    // 64*529*4
static constexpr size_t OFF_BIAS0 = OFF_MAP   + 135424;     // 2048 f
static constexpr size_t OFF_BIAS1 = OFF_BIAS0 + 8192;       // 2048 f
static constexpr size_t OFF_C0    = OFF_BIAS1 + 8192;       // 64*512 f
static constexpr size_t OFF_C1    = OFF_C0    + 131072;
static constexpr size_t OFF_HLAST = OFF_C1    + 131072;     // 64*512 f (fp32, real-batch idx)
static constexpr size_t OFF_H0B   = OFF_HLAST + 131072;     // 2 x 64*512 half (sorted idx)
static constexpr size_t OFF_H1B   = OFF_H0B   + 262144;
static constexpr size_t OFF_WTIH0 = OFF_H1B   + 262144;     // 768x2048 f
static constexpr size_t OFF_XPROJ = OFF_WTIH0 + 6291456ULL; // 64*81*2048 f
static constexpr size_t OFF_BAR   = OFF_XPROJ + 42467328ULL; // 4 groups x 64 int
static constexpr size_t OFF_ORD   = OFF_BAR   + 4096;       // 64 int (sorted batch ids)
static constexpr size_t OFF_GMAX  = OFF_ORD   + 256;        // 4 int (per-group max L)
static constexpr size_t WS_NEED   = OFF_GMAX  + 256;

// group g owns sorted ranks [gbase, gbase+16)
__device__ __forceinline__ int group_base(int g) {
  return (g == 0) ? 0 : (g == 1) ? 16 : (g == 2) ? 48 : 32;
}

// ---------------- coherent (L2-bypass) access helpers ----------------
__device__ __forceinline__ void store_us_cc(ushort* p, unsigned int v) {
  asm volatile("global_store_short %0, %1, off sc0 sc1" :: "v"(p), "v"(v) : "memory");
}
__device__ __forceinline__ void store_f_cc(float* p, float v) {
  asm volatile("global_store_dword %0, %1, off sc0 sc1" :: "v"(p), "v"(v) : "memory");
}
__device__ __forceinline__ void load_a_cc(u32x4_t& v, const ushort* p) {
  asm volatile("global_load_dwordx4 %0, %1, off sc0 sc1" : "=v"(v) : "v"(p) : "memory");
}

__device__ __forceinline__ unsigned int pkrtz(float a, float b) {
  auto r = __builtin_amdgcn_cvt_pkrtz(a, b);
  unsigned int u;
  __builtin_memcpy(&u, &r, 4);
  return u;
}
__device__ __forceinline__ unsigned int f2h(float a) {
  return pkrtz(a, 0.f) & 0xffffu;
}
__device__ __forceinline__ f32x4_t mfma16(u32x4_t a, u32x4_t b, f32x4_t c) {
  f16x8_t av, bv;
  __builtin_memcpy(&av, &a, 16);
  __builtin_memcpy(&bv, &b, 16);
  return __builtin_amdgcn_mfma_f32_16x16x32_f16(av, bv, c, 0, 0, 0);
}

__device__ __forceinline__ float sigm(float x) { return 1.f/(1.f + __expf(-x)); }

// P-partials LDS geometry: P[wl=wv*2+layer][col=64][m=16] with col stride 20
#define PSEG 1280              // 64*20 floats per wl
#define PCOL 20

// ---------------- prep ----------------
__global__ __launch_bounds__(256) void k_prep(
    const int* __restrict__ ns, const int* __restrict__ que,
    const float* __restrict__ b_ih0, const float* __restrict__ b_hh0,
    const float* __restrict__ b_ih1, const float* __restrict__ b_hh1,
    int* __restrict__ Lp, int* __restrict__ maxLp, int* __restrict__ map,
    float* __restrict__ bias0, float* __restrict__ bias1,
    float* __restrict__ c0, float* __restrict__ c1, float* __restrict__ hlast,
    ushort* __restrict__ h0b, ushort* __restrict__ h1b, int* __restrict__ bar,
    int* __restrict__ ord, int* __restrict__ gmax)
{
  const int tid = threadIdx.x;
  for (int i = tid; i < B_*S_; i += 256) map[i] = -1;
  for (int i = tid; i < G4_; i += 256) {
    bias0[i] = b_ih0[i] + b_hh0[i];
    bias1[i] = b_ih1[i] + b_hh1[i];
  }
  int* h0i = (int*)h0b;
  int* h1i = (int*)h1b;
  for (int i = tid; i < B_*H_; i += 256) {
    c0[i]=0.f; c1[i]=0.f; hlast[i]=0.f;
    h0i[i]=0; h1i[i]=0;
  }
  for (int i = tid; i < 1024; i += 256) bar[i] = 0;
  if (tid == 0) *maxLp = 0;
  __syncthreads();
  if (tid < B_) {
    const int b = tid;
    const int qn = que[b];
    int pos = 0;
    int* m = map + b*S_;
    for (int q = 0; q < qn; ++q) {
      m[pos++] = q;
      const int n = ns[b*Q_ + q];
      for (int k = 0; k < n; ++k) {
        int j = q + k; if (j > C_-1) j = C_-1;
        m[pos++] = 16 + j;
      }
    }
    m[pos] = 80;
    Lp[b] = pos;
    atomicMax(maxLp, pos);
  }
  __syncthreads();
  if (tid < B_) {
    const int myL = Lp[tid];
    int rank = 0;
    for (int j = 0; j < B_; ++j) {
      const int lj = Lp[j];
      rank += (lj > myL) || (lj == myL && j < tid);
    }
    ord[rank] = tid;
  }
  __syncthreads();
  if (tid < 4) {
    const int gb = (tid == 0) ? 0 : (tid == 1) ? 16 : (tid == 2) ? 48 : 32;
    gmax[tid] = Lp[ord[gb]];
  }
}

// ---------------- transpose W_ih0 only ----------------
__global__ __launch_bounds__(256) void k_transpose(
    const float* __restrict__ w, float* __restrict__ wT)
{
  __shared__ float tile[32][33];
  const int n0 = blockIdx.x * 32;
  const int k0 = blockIdx.y * 32;
  const int tx = threadIdx.x, ty = threadIdx.y;
  for (int i = ty; i < 32; i += 8)
    tile[i][tx] = w[(size_t)(n0+i)*D_ + k0 + tx];
  __syncthreads();
  for (int i = ty; i < 32; i += 8)
    wT[(size_t)(k0 + i)*G4_ + n0 + tx] = tile[tx][i];
}

// ---------------- xproj ----------------
__global__ __launch_bounds__(128, 2) void k_proj(
    const float* __restrict__ text, const float* __restrict__ ques,
    const float* __restrict__ code, const float* __restrict__ wT_ih0,
    const float* __restrict__ bias0, float* __restrict__ xproj)
{
  __shared__ float hsLds[32][64];
  const int mb = blockIdx.x, nb = blockIdx.y;
  const int n0 = nb * 128;
  const int tid = threadIdx.x;
  const int tb = tid >> 4, tn = tid & 15;
  const int b0 = tb * 8;
  const int bb = tid >> 1, hh = tid & 1;

  const int mrow = mb*64 + bb;
  const int sb = mrow / NR_, sr = mrow % NR_;
  const float* srcrow = (sr < 16) ? (ques + ((size_t)sb*Q_ + sr)*D_)
                      : (sr < 80) ? (code + ((size_t)sb*C_ + (sr-16))*D_)
                                  : (text + (size_t)sb*D_);

  float a[8][8];
  #pragma unroll
  for (int i=0;i<8;i++)
    #pragma unroll
    for (int j=0;j<8;j++) a[i][j]=0.f;

  for (int k0 = 0; k0 < D_; k0 += 32) {
    __syncthreads();
    {
      const float* p = srcrow + k0 + hh*16;
      float4 v0 = *(const float4*)(p+0);
      float4 v1 = *(const float4*)(p+4);
      float4 v2 = *(const float4*)(p+8);
      float4 v3 = *(const float4*)(p+12);
      const int kk = hh*16;
      hsLds[kk+ 0][bb]=v0.x; hsLds[kk+ 1][bb]=v0.y; hsLds[kk+ 2][bb]=v0.z; hsLds[kk+ 3][bb]=v0.w;
      hsLds[kk+ 4][bb]=v1.x; hsLds[kk+ 5][bb]=v1.y; hsLds[kk+ 6][bb]=v1.z; hsLds[kk+ 7][bb]=v1.w;
      hsLds[kk+ 8][bb]=v2.x; hsLds[kk+ 9][bb]=v2.y; hsLds[kk+10][bb]=v2.z; hsLds[kk+11][bb]=v2.w;
      hsLds[kk+12][bb]=v3.x; hsLds[kk+13][bb]=v3.y; hsLds[kk+14][bb]=v3.z; hsLds[kk+15][bb]=v3.w;
    }
    __syncthreads();
    const float* wb = wT_ih0 + (size_t)k0*G4_ + n0 + tn*8;
    #pragma unroll 4
    for (int k=0;k<32;k++){
      float4 w0 = *(const float4*)(wb + (size_t)k*G4_);
      float4 w1 = *(const float4*)(wb + (size_t)k*G4_ + 4);
      float4 hA = *(const float4*)(&hsLds[k][b0]);
      float4 hB = *(const float4*)(&hsLds[k][b0+4]);
      float hv[8]={hA.x,hA.y,hA.z,hA.w,hB.x,hB.y,hB.z,hB.w};
      float wv[8]={w0.x,w0.y,w0.z,w0.w,w1.x,w1.y,w1.z,w1.w};
      #pragma unroll
      for (int i=0;i<8;i++)
        #pragma unroll
        for (int j=0;j<8;j++)
          a[i][j] = fmaf(hv[i], wv[j], a[i][j]);
    }
  }
  float bz[8];
  #pragma unroll
  for (int j=0;j<8;j++) bz[j] = bias0[n0 + tn*8 + j];
  #pragma unroll
  for (int i=0;i<8;i++){
    const int m = mb*64 + b0 + i;
    float* pd = xproj + (size_t)m*G4_ + n0 + tn*8;
    *(float4*)(pd+0) = make_float4(a[i][0]+bz[0], a[i][1]+bz[1], a[i][2]+bz[2], a[i][3]+bz[3]);
    *(float4*)(pd+4) = make_float4(a[i][4]+bz[4], a[i][5]+bz[5], a[i][6]+bz[6], a[i][7]+bz[7]);
  }
}

// ---------------- persistent LSTM (MFMA core, fat blocks) ----------------
// 128 blocks: g = blk>>5 (sync domain / 16 sorted batches), us = blk&31 (16 units).
// Block owns units us*16..+15 -> N=64 gate-cols/layer (4 N-tiles of 16).
// n(tile nt, idx) = (idx>>2)*512 + us*16 + nt*4 + (idx&3).
// Wave wv: L0 K-slice [wv*128,+128) (16 MFMA); L1: wv<2 -> W_ih1 slice
// (wv&1)*256 (A=h0), wv>=2 -> W_hh1 slice (A=h1) (32 MFMA). 48 MFMA/wave.
// Weights in VGPRs (48 frags = 192 regs); cross-wave K-reduce via LDS P.

__device__ __forceinline__ void load_wfrags(int tid, int us,
    const float* __restrict__ w_hh0, const float* __restrict__ w_ih1,
    const float* __restrict__ w_hh1, u32x4_t* wf0, u32x4_t* wf1)
{
  const int wv = tid >> 6, lane = tid & 63;
  const int nidx = lane & 15, kgrp = lane >> 4;
  #pragma unroll
  for (int nt = 0; nt < 4; ++nt) {
    const int ngl = (nidx >> 2)*H_ + us*16 + nt*4 + (nidx & 3);
    const float* r0 = w_hh0 + (size_t)ngl*H_ + wv*128 + kgrp*8;
    #pragma unroll
    for (int f = 0; f < 4; ++f) {
      float4 lo = *(const float4*)(r0 + f*32);
      float4 hi = *(const float4*)(r0 + f*32 + 4);
      wf0[nt*4+f] = (u32x4_t){pkrtz(lo.x,lo.y), pkrtz(lo.z,lo.w), pkrtz(hi.x,hi.y), pkrtz(hi.z,hi.w)};
    }
    const float* w1 = (wv < 2) ? w_ih1 : w_hh1;
    const float* r1 = w1 + (size_t)ngl*H_ + (wv & 1)*256 + kgrp*8;
    #pragma unroll
    for (int f = 0; f < 8; ++f) {
      float4 lo = *(const float4*)(r1 + f*32);
      float4 hi = *(const float4*)(r1 + f*32 + 4);
      wf1[nt*8+f] = (u32x4_t){pkrtz(lo.x,lo.y), pkrtz(lo.z,lo.w), pkrtz(hi.x,hi.y), pkrtz(hi.z,hi.w)};
    }
  }
}

// gate-context prefetch (all 256 threads have an L0 cell)
__device__ __forceinline__ void xg_prefetch(int t, int maxLg,
    const int* __restrict__ mrow, const float* __restrict__ xbase,
    float& xg0, float& xg1, float& xg2, float& xg3, int& rpre)
{
  rpre = (t <= maxLg) ? mrow[t] : -1;
  const float* xp = xbase + (size_t)(rpre < 0 ? 0 : rpre)*G4_;
  xg0 = xp[0]; xg1 = xp[512]; xg2 = xp[1024]; xg3 = xp[1536];
}

__device__ __forceinline__ void lstm_iter(int t, int maxLg, int gbase, int us,
    const u32x4_t* wf0, const u32x4_t* wf1, float* __restrict__ P,
    const ushort* __restrict__ h0c, ushort* __restrict__ h0n,
    const ushort* __restrict__ h1c, ushort* __restrict__ h1n,
    float* __restrict__ c0, float* __restrict__ c1, float* __restrict__ hlast,
    const int* __restrict__ mrow, const float* __restrict__ xbase,
    float& xg0, float& xg1, float& xg2, float& xg3, int& rpre0, int& rpre1,
    float b1v0, float b1v1, float b1v2, float b1v3, int Lrb, int rb)
{
  const int tid = threadIdx.x;
  const int wv = tid >> 6, lane = tid & 63;
  const int nidx = lane & 15, kgrp = lane >> 4;

  // ---- A-fragment loads (h through LLC), first thing after the barrier ----
  u32x4_t a0[4], a1[8];
  {
    const ushort* h0r = h0c + (size_t)(gbase + nidx)*H_ + wv*128 + kgrp*8;
    #pragma unroll
    for (int f = 0; f < 4; ++f) load_a_cc(a0[f], h0r + f*32);
    const ushort* hs1 = (wv < 2) ? h0c : h1c;
    const ushort* h1r = hs1 + (size_t)(gbase + nidx)*H_ + (wv & 1)*256 + kgrp*8;
    #pragma unroll
    for (int f = 0; f < 8; ++f) load_a_cc(a1[f], h1r + f*32);
  }
  asm volatile("s_waitcnt vmcnt(0)" ::: "memory");
  __builtin_amdgcn_sched_barrier(0);   // rule #18: keep MFMAs below the wait

  f32x4_t acc0[4], acc1[4];
  #pragma unroll
  for (int nt = 0; nt < 4; ++nt) { acc0[nt] = (f32x4_t){0.f,0.f,0.f,0.f}; acc1[nt] = (f32x4_t){0.f,0.f,0.f,0.f}; }
  #pragma unroll
  for (int nt = 0; nt < 4; ++nt)
    #pragma unroll
    for (int f = 0; f < 4; ++f) acc0[nt] = mfma16(a0[f], wf0[nt*4+f], acc0[nt]);
  #pragma unroll
  for (int nt = 0; nt < 4; ++nt)
    #pragma unroll
    for (int f = 0; f < 8; ++f) acc1[nt] = mfma16(a1[f], wf1[nt*8+f], acc1[nt]);

  // ---- stash per-wave partials: P[wl][col][m], col stride PCOL, b128 stores ----
  #pragma unroll
  for (int nt = 0; nt < 4; ++nt) {
    *(f32x4_t*)(P + (wv*2+0)*PSEG + (nt*16 + nidx)*PCOL + kgrp*4) = acc0[nt];
    *(f32x4_t*)(P + (wv*2+1)*PSEG + (nt*16 + nidx)*PCOL + kgrp*4) = acc1[nt];
  }

  // ---- prefetch NEXT step's gate context (overlaps; drained later) ----
  float nxg0=xg0, nxg1=xg1, nxg2=xg2, nxg3=xg3;
  int nr0 = -1;
  const int nr1 = rpre0;                 // L1's map value at iter t+1 is L0's at t
  xg_prefetch(t + 1, maxLg, mrow, xbase, nxg0, nxg1, nxg2, nxg3, nr0);
  __syncthreads();

  // ---- gates: every thread does one L0 cell and one L1 cell ----
  const int bl = tid & 15, ul = tid >> 4;
  const int pb = gbase + bl;
  const int u = us*16 + ul;
  const int idx = pb*H_ + u;
  const int clb = (ul >> 2)*16 + (ul & 3);   // col base for gate g: clb + g*4
  if (rpre0 >= 0) {
    float g0=xg0, g1=xg1, g2=xg2, g3=xg3;
    #pragma unroll
    for (int w = 0; w < 4; ++w) {
      const float* Pr = P + (w*2+0)*PSEG + bl;
      g0 += Pr[(clb+ 0)*PCOL]; g1 += Pr[(clb+ 4)*PCOL];
      g2 += Pr[(clb+ 8)*PCOL]; g3 += Pr[(clb+12)*PCOL];
    }
    const float cc = sigm(g1)*c0[idx] + sigm(g0)*tanhf(g2);
    c0[idx] = cc;
    store_us_cc(h0n + idx, f2h(sigm(g3)*tanhf(cc)));
  }
  if (rpre1 >= 0) {
    float g0=b1v0, g1=b1v1, g2=b1v2, g3=b1v3;
    #pragma unroll
    for (int w = 0; w < 4; ++w) {
      const float* Pr = P + (w*2+1)*PSEG + bl;
      g0 += Pr[(clb+ 0)*PCOL]; g1 += Pr[(clb+ 4)*PCOL];
      g2 += Pr[(clb+ 8)*PCOL]; g3 += Pr[(clb+12)*PCOL];
    }
    const float cc = sigm(g1)*c1[idx] + sigm(g0)*tanhf(g2);
    c1[idx] = cc;
    const float hn = sigm(g3)*tanhf(cc);
    store_us_cc(h1n + idx, f2h(hn));
    if (t - 1 == Lrb) store_f_cc(hlast + rb*H_ + u, hn);
  }

  xg0 = nxg0; xg1 = nxg1; xg2 = nxg2; xg3 = nxg3;
  rpre0 = nr0; rpre1 = nr1;
}

// ---------------- per-group barrier: single counter, 32 arrivals ----------------
__device__ __forceinline__ void grid_barrier_g(int* __restrict__ cnt, int gen)
{
  asm volatile("s_waitcnt vmcnt(0)" ::: "memory");
  __syncthreads();
  if (threadIdx.x == 0) {
    atomicAdd(cnt, 1);
    while (__hip_atomic_load(cnt, __ATOMIC_RELAXED, __HIP_MEMORY_SCOPE_AGENT) < gen*32)
      __builtin_amdgcn_s_sleep(1);
  }
  __syncthreads();
}

// ---------------- cooperative persistent kernel ----------------
__global__ __launch_bounds__(256, 1) void k_lstm_coop(
    const float* __restrict__ w_hh0, const float* __restrict__ w_ih1,
    const float* __restrict__ w_hh1, const float* __restrict__ xproj,
    const float* __restrict__ bias1, const int* __restrict__ Lp,
    const int* __restrict__ gmax, const int* __restrict__ map,
    const int* __restrict__ ord,
    ushort* __restrict__ h0b, ushort* __restrict__ h1b,
    float* __restrict__ c0, float* __restrict__ c1, float* __restrict__ hlast,
    const float* __restrict__ fcw, const float* __restrict__ fcb,
    float* __restrict__ out, int* __restrict__ bar)
{
  __shared__ __align__(16) float P[8*PSEG];
  const int blk = blockIdx.x;
  const int g = blk >> 5, us = blk & 31;
  const int gbase = group_base(g);
  const int tid = threadIdx.x;

  u32x4_t wf0[16], wf1[32];
  load_wfrags(tid, us, w_hh0, w_ih1, w_hh1, wf0, wf1);
  const int maxLg = gmax[g];
  int* cnt = bar + g*64;

  // ---- per-thread persistent gate context (all 256 threads have cells) ----
  const int rb = ord[gbase + (tid & 15)];
  const int* mrow = map + rb*S_;
  const int u = us*16 + (tid >> 4);
  const float* xbase = xproj + (size_t)rb*NR_*G4_ + u;
  const float b1v0 = bias1[u], b1v1 = bias1[512+u], b1v2 = bias1[1024+u], b1v3 = bias1[1536+u];
  const int Lrb = Lp[rb];

  float xg0=0.f, xg1=0.f, xg2=0.f, xg3=0.f;
  int rpre0 = -1, rpre1 = -1;
  xg_prefetch(0, maxLg, mrow, xbase, xg0, xg1, xg2, xg3, rpre0);
  __syncthreads();

  for (int t = 0; t <= maxLg + 1; ++t) {
    const ushort* h0c = h0b + (size_t)(t & 1)*(B_*H_);
    ushort*       h0n = h0b + (size_t)((t+1) & 1)*(B_*H_);
    const ushort* h1c = h1b + (size_t)(t & 1)*(B_*H_);
    ushort*       h1n = h1b + (size_t)((t+1) & 1)*(B_*H_);
    lstm_iter(t, maxLg, gbase, us, wf0, wf1, P,
              h0c, h0n, h1c, h1n, c0, c1, hlast,
              mrow, xbase, xg0, xg1, xg2, xg3, rpre0, rpre1,
              b1v0, b1v1, b1v2, b1v3, Lrb, rb);
    grid_barrier_g(cnt, t + 1);
  }
  // ---- per-group FC epilogue ----
  if (us == 0 && tid < 32) {
    const int pb = gbase + (tid >> 1), half = tid & 1;
    const int rbf = ord[pb];
    const float* hv = hlast + (size_t)rbf*H_ + half*256;
    const float* fw = fcw + half*256;
    float s = 0.f;
    #pragma unroll 8
    for (int uu = 0; uu < 256; ++uu) s = fmaf(hv[uu], fw[uu], s);
    s += __shfl_xor(s, 1);
    if (half == 0) store_f_cc(out + rbf, s + fcb[0]);
  }
}

// ---------------- non-cooperative fallback: one iteration per launch ----------------
__global__ __launch_bounds__(256, 1) void k_step(int t,
    const float* __restrict__ w_hh0, const float* __restrict__ w_ih1,
    const float* __restrict__ w_hh1, const float* __restrict__ xproj,
    const float* __restrict__ bias1, const int* __restrict__ Lp,
    const int* __restrict__ gmax, const int* __restrict__ map,
    const int* __restrict__ ord,
    ushort* __restrict__ h0b, ushort* __restrict__ h1b,
    float* __restrict__ c0, float* __restrict__ c1, float* __restrict__ hlast)
{
  __shared__ __align__(16) float P[8*PSEG];
  const int blk = blockIdx.x;
  const int g = blk >> 5, us = blk & 31;
  const int gbase = group_base(g);
  const int maxLg = gmax[g];
  if (t > maxLg + 1) return;
  const int tid = threadIdx.x;
  u32x4_t wf0[16], wf1[32];
  load_wfrags(tid, us, w_hh0, w_ih1, w_hh1, wf0, wf1);

  const int rb = ord[gbase + (tid & 15)];
  const int* mrow = map + rb*S_;
  const int u = us*16 + (tid >> 4);
  const float* xbase = xproj + (size_t)rb*NR_*G4_ + u;
  const float b1v0 = bias1[u], b1v1 = bias1[512+u], b1v2 = bias1[1024+u], b1v3 = bias1[1536+u];
  const int Lrb = Lp[rb];

  float xg0=0.f, xg1=0.f, xg2=0.f, xg3=0.f;
  int rpre0 = -1, rpre1 = -1;
  xg_prefetch(t, maxLg, mrow, xbase, xg0, xg1, xg2, xg3, rpre0);
  rpre1 = (t-1 >= 0 && t-1 <= maxLg) ? mrow[t-1] : -1;
  __syncthreads();

  const ushort* h0c = h0b + (size_t)(t & 1)*(B_*H_);
  ushort*       h0n = h0b + (size_t)((t+1) & 1)*(B_*H_);
  const ushort* h1c = h1b + (size_t)(t & 1)*(B_*H_);
  ushort*       h1n = h1b + (size_t)((t+1) & 1)*(B_*H_);
  lstm_iter(t, maxLg, gbase, us, wf0, wf1, P,
            h0c, h0n, h1c, h1n, c0, c1, hlast,
            mrow, xbase, xg0, xg1, xg2, xg3, rpre0, rpre1,
            b1v0, b1v1, b1v2, b1v3, Lrb, rb);
}

__global__ __launch_bounds__(128) void k_fc(
    const float* __restrict__ hlast, const float* __restrict__ fcw,
    const float* __restrict__ fcb, float* __restrict__ out)
{
  const int tid = threadIdx.x;
  if (tid < 128) {
    const int b = tid >> 1, half = tid & 1;
    const float* hv = hlast + (size_t)b*H_ + half*256;
    const float* fw = fcw + half*256;
    float s = 0.f;
    #pragma unroll 8
    for (int u = 0; u < 256; ++u) s = fmaf(hv[u], fw[u], s);
    s += __shfl_xor(s, 1);
    if (half == 0) out[b] = s + fcb[0];
  }
}

// ---------------- host ----------------
extern "C" void kernel_launch(void* const* d_in, const int* in_sizes, int n_in,
                              void* d_out, int out_size, void* d_ws, size_t ws_size,
                              hipStream_t stream)
{
  const float* text  = (const float*)d_in[0];
  const float* ques  = (const float*)d_in[1];
  const float* code  = (const float*)d_in[2];
  const int*   ns    = (const int*)  d_in[3];
  const int*   que   = (const int*)  d_in[4];
  const float* w_ih0 = (const float*)d_in[5];
  const float* w_hh0 = (const float*)d_in[6];
  const float* b_ih0 = (const float*)d_in[7];
  const float* b_hh0 = (const float*)d_in[8];
  const float* w_ih1 = (const float*)d_in[9];
  const float* w_hh1 = (const float*)d_in[10];
  const float* b_ih1 = (const float*)d_in[11];
  const float* b_hh1 = (const float*)d_in[12];
  const float* fcw   = (const float*)d_in[13];
  const float* fcb   = (const float*)d_in[14];
  float* out = (float*)d_out;

  char* ws = (char*)d_ws;
  int*    Lp     = (int*)   (ws + OFF_L);
  int*    maxLp  = (int*)   (ws + OFF_MAXL);
  int*    map    = (int*)   (ws + OFF_MAP);
  float*  bias0  = (float*) (ws + OFF_BIAS0);
  float*  bias1  = (float*) (ws + OFF_BIAS1);
  float*  c0     = (float*) (ws + OFF_C0);
  float*  c1     = (float*) (ws + OFF_C1);
  float*  hlast  = (float*) (ws + OFF_HLAST);
  ushort* h0b    = (ushort*)(ws + OFF_H0B);
  ushort* h1b    = (ushort*)(ws + OFF_H1B);
  float*  wT_ih0 = (float*) (ws + OFF_WTIH0);
  float*  xproj  = (float*) (ws + OFF_XPROJ);
  int*    bar    = (int*)   (ws + OFF_BAR);
  int*    ord    = (int*)   (ws + OFF_ORD);
  int*    gmax   = (int*)   (ws + OFF_GMAX);
  (void)in_sizes; (void)n_in; (void)out_size; (void)ws_size; (void)WS_NEED;

  hipLaunchKernelGGL(k_prep, dim3(1), dim3(256), 0, stream,
                     ns, que, b_ih0, b_hh0, b_ih1, b_hh1,
                     Lp, maxLp, map, bias0, bias1, c0, c1, hlast, h0b, h1b, bar,
                     ord, gmax);

  hipLaunchKernelGGL(k_transpose, dim3(64, 24), dim3(32, 8), 0, stream,
                     w_ih0, wT_ih0);

  hipLaunchKernelGGL(k_proj, dim3(81, 16), dim3(128), 0, stream,
                     text, ques, code, wT_ih0, bias0, xproj);

  const float* a_whh0 = w_hh0; const float* a_wih1 = w_ih1; const float* a_whh1 = w_hh1;
  const float* a_xp = xproj;   const float* a_b1 = bias1;
  const int* a_Lp = Lp; const int* a_gmax = gmax; const int* a_map = map;
  const int* a_ord = ord;
  ushort* a_h0b = h0b; ushort* a_h1b = h1b; float* a_c0 = c0; float* a_c1 = c1;
  float* a_hl = hlast; const float* a_fcw = fcw; const float* a_fcb = fcb;
  float* a_out = out; int* a_bar = bar;
  void* args[] = { &a_whh0, &a_wih1, &a_whh1, &a_xp, &a_b1, &a_Lp, &a_gmax, &a_map,
                   &a_ord, &a_h0b, &a_h1b, &a_c0, &a_c1, &a_hl, &a_fcw, &a_fcb,
                   &a_out, &a_bar };

  hipError_t err = hipLaunchCooperativeKernel((const void*)k_lstm_coop,
                                              dim3(128), dim3(256), args, 0, stream);
  if (err != hipSuccess) {
    (void)hipGetLastError();  // clear error state
    for (int t = 0; t < S_ + 1; ++t) {
      hipLaunchKernelGGL(k_step, dim3(128), dim3(256), 0, stream, t,
                         w_hh0, w_ih1, w_hh1, xproj, bias1, Lp, gmax, map, ord,
                         h0b, h1b, c0, c1, hlast);
    }
    hipLaunchKernelGGL(k_fc, dim3(1), dim3(128), 0, stream, hlast, fcw, fcb, out);
  }
}